// Round 1
// baseline (4819.352 us; speedup 1.0000x reference)
//
#include <hip/hip_runtime.h>
#include <hip/hip_bf16.h>
#include <stdint.h>

// ChebNet: 4x ChebConv(K=10) + BN + FC head. fp32 baseline, CSR-by-dst gather
// for L_hat (no fp32 atomics on hot path), tiled fp32 GEMM w/ accumulate.

#define N_NODES 20000
#define N_EDGES 320000
#define FDIM_IN 128
#define DD1 256
#define DD2 128
#define DD3 64
#define K_CHEB 10
#define EPSBN 1e-5f

// ---------------- graph setup ----------------

// edge_index may arrive as int32 or int64 depending on harness/jax x64 config.
// Detect: if the high 32-bit words of the first 64 "int64" entries are all 0,
// it's int64 (values < 2^31 and nonnegative). For int32 those words are random
// src indices -> essentially never all zero.
__global__ void detect_idx_kernel(const void* ei, int* flag) {
  int t = threadIdx.x;
  const int* p = (const int*)ei;
  int v = p[2 * t + 1];
  unsigned long long b = __ballot(v == 0);
  if (t == 0) *flag = (b == ~0ULL) ? 1 : 0;
}

__device__ __forceinline__ int load_edge(const void* ei, int mode64, long long pos) {
  return mode64 ? (int)((const long long*)ei)[pos] : ((const int*)ei)[pos];
}

__global__ void deg_kernel(const void* ei, const int* __restrict__ flag, int* __restrict__ ideg) {
  int e = blockIdx.x * blockDim.x + threadIdx.x;
  if (e < N_EDGES) {
    int d = load_edge(ei, *flag, (long long)N_EDGES + e);
    atomicAdd(&ideg[d], 1);
  }
}

__global__ void dinv_kernel(const int* __restrict__ ideg, float* __restrict__ dinv) {
  int n = blockIdx.x * blockDim.x + threadIdx.x;
  if (n < N_NODES) {
    int d = ideg[n];
    dinv[n] = d > 0 ? rsqrtf((float)d) : 0.f;
  }
}

__global__ __launch_bounds__(1024) void scan_kernel(const int* __restrict__ ideg, int* __restrict__ rowptr) {
  __shared__ int part[1024];
  int tid = threadIdx.x;
  const int CH = (N_NODES + 1023) / 1024;  // 20 elems / thread
  int base = tid * CH;
  int s = 0;
  for (int i = 0; i < CH; i++) { int idx = base + i; if (idx < N_NODES) s += ideg[idx]; }
  part[tid] = s;
  __syncthreads();
  for (int off = 1; off < 1024; off <<= 1) {
    int v = (tid >= off) ? part[tid - off] : 0;
    __syncthreads();
    part[tid] += v;
    __syncthreads();
  }
  int run = (tid == 0) ? 0 : part[tid - 1];
  for (int i = 0; i < CH; i++) { int idx = base + i; if (idx < N_NODES) { rowptr[idx] = run; run += ideg[idx]; } }
  if (tid == 1023) rowptr[N_NODES] = run;
}

__global__ void fill_csr_kernel(const void* ei, const int* __restrict__ flag,
                                const float* __restrict__ dinv, const int* __restrict__ rowptr,
                                int* __restrict__ cnt, int* __restrict__ col, float* __restrict__ wcsr) {
  int e = blockIdx.x * blockDim.x + threadIdx.x;
  if (e < N_EDGES) {
    int m = *flag;
    int s = load_edge(ei, m, e);
    int d = load_edge(ei, m, (long long)N_EDGES + e);
    int pos = rowptr[d] + atomicAdd(&cnt[d], 1);
    col[pos] = s;
    wcsr[pos] = -dinv[s] * dinv[d];  // L_hat off-diagonal weight
  }
}

// ---------------- L_hat: out[n,:] = scale * sum_e w[e]*in[col[e],:]  (- tx0[n,:]) ----------------
template <int F>
__global__ void lhat_kernel(const float* __restrict__ in, float* __restrict__ out,
                            const int* __restrict__ rowptr, const int* __restrict__ col,
                            const float* __restrict__ w, const float* __restrict__ tx0,
                            float scale) {
  int n = blockIdx.x;
  int f = threadIdx.x;  // blockDim == F
  int beg = rowptr[n], end = rowptr[n + 1];
  float acc = 0.f;
  for (int e = beg; e < end; e++) {
    acc += w[e] * in[(size_t)col[e] * F + f];
  }
  float r = scale * acc;
  if (tx0) r -= tx0[(size_t)n * F + f];
  out[(size_t)n * F + f] = r;
}

// ---------------- fp32 GEMM: C[M,Nd] (+)= A[M,Kd] @ B[Kd,Nd], tile 64x64, 4x4/thread ----------------
__global__ __launch_bounds__(256) void gemm64_kernel(const float* __restrict__ A, const float* __restrict__ B,
                                                     float* __restrict__ C, int M, int Kd, int Nd,
                                                     int accumulate) {
  __shared__ float As[16][68];  // [k][m], padded
  __shared__ float Bs[16][68];  // [k][n], padded
  int bm = blockIdx.x * 64;
  int bn = blockIdx.y * 64;
  int t = threadIdx.x;
  int tm = t >> 4, tn = t & 15;
  float acc[4][4] = {};
  for (int k0 = 0; k0 < Kd; k0 += 16) {
#pragma unroll
    for (int i = 0; i < 4; i++) {
      int idx = t + i * 256;
      int m = idx >> 4;      // 0..63
      int kk = idx & 15;     // 0..15
      int gm = bm + m;
      As[kk][m] = (gm < M) ? A[(size_t)gm * Kd + k0 + kk] : 0.f;
    }
#pragma unroll
    for (int i = 0; i < 4; i++) {
      int idx = t + i * 256;
      int kk = idx >> 6;     // 0..15
      int n = idx & 63;      // 0..63
      Bs[kk][n] = B[(size_t)(k0 + kk) * Nd + bn + n];
    }
    __syncthreads();
#pragma unroll
    for (int kk = 0; kk < 16; kk++) {
      float a0 = As[kk][tm * 4 + 0], a1 = As[kk][tm * 4 + 1];
      float a2 = As[kk][tm * 4 + 2], a3 = As[kk][tm * 4 + 3];
      float b0 = Bs[kk][tn * 4 + 0], b1 = Bs[kk][tn * 4 + 1];
      float b2 = Bs[kk][tn * 4 + 2], b3 = Bs[kk][tn * 4 + 3];
      acc[0][0] += a0 * b0; acc[0][1] += a0 * b1; acc[0][2] += a0 * b2; acc[0][3] += a0 * b3;
      acc[1][0] += a1 * b0; acc[1][1] += a1 * b1; acc[1][2] += a1 * b2; acc[1][3] += a1 * b3;
      acc[2][0] += a2 * b0; acc[2][1] += a2 * b1; acc[2][2] += a2 * b2; acc[2][3] += a2 * b3;
      acc[3][0] += a3 * b0; acc[3][1] += a3 * b1; acc[3][2] += a3 * b2; acc[3][3] += a3 * b3;
    }
    __syncthreads();
  }
#pragma unroll
  for (int i = 0; i < 4; i++) {
    int gm = bm + tm * 4 + i;
    if (gm < M) {
      float* cp = C + (size_t)gm * Nd + bn + tn * 4;
      if (accumulate) {
        cp[0] += acc[i][0]; cp[1] += acc[i][1]; cp[2] += acc[i][2]; cp[3] += acc[i][3];
      } else {
        cp[0] = acc[i][0]; cp[1] = acc[i][1]; cp[2] = acc[i][2]; cp[3] = acc[i][3];
      }
    }
  }
}

// ---------------- elementwise / BN / head ----------------
__global__ void bias_act_kernel(float* __restrict__ h, const float* __restrict__ bias,
                                int total, int mask, int relu) {
  int i = blockIdx.x * blockDim.x + threadIdx.x;
  if (i < total) {
    float v = h[i];
    if (bias) v += bias[i & mask];
    if (relu) v = fmaxf(v, 0.f);
    h[i] = v;
  }
}

__global__ __launch_bounds__(256) void bn_stats_kernel(const float* __restrict__ h, float* __restrict__ acc,
                                                       int rows, int D) {
  int f = threadIdx.x;
  if (f >= D) return;
  float s = 0.f, q = 0.f;
  for (int r = blockIdx.x; r < rows; r += gridDim.x) {
    float v = h[(size_t)r * D + f];
    s += v;
    q += v * v;
  }
  atomicAdd(&acc[f], s);
  atomicAdd(&acc[256 + f], q);
}

__global__ void bn_apply_kernel(float* __restrict__ h, const float* __restrict__ acc,
                                const float* __restrict__ g, const float* __restrict__ b,
                                int total, int mask, int relu, float invRows) {
  int i = blockIdx.x * blockDim.x + threadIdx.x;
  if (i < total) {
    int f = i & mask;
    float m = acc[f] * invRows;
    float var = acc[256 + f] * invRows - m * m;
    float r = (h[i] - m) * rsqrtf(var + EPSBN) * g[f] + b[f];
    if (relu) r = fmaxf(r, 0.f);
    h[i] = r;
  }
}

__global__ void fc3_kernel(const float* __restrict__ h, const float* __restrict__ w,
                           const float* __restrict__ b, float* __restrict__ out) {
  int node = blockIdx.x * 4 + (threadIdx.x >> 6);
  int lane = threadIdx.x & 63;
  if (node >= N_NODES) return;
  float v = h[(size_t)node * DD3 + lane] * w[lane];
#pragma unroll
  for (int off = 32; off > 0; off >>= 1) v += __shfl_down(v, off);
  if (lane == 0) out[node] = v + b[0];
}

// ---------------- host ----------------
extern "C" void kernel_launch(void* const* d_in, const int* in_sizes, int n_in,
                              void* d_out, int out_size, void* d_ws, size_t ws_size,
                              hipStream_t stream) {
  const float* x = (const float*)d_in[0];
  const void* ei = d_in[1];
  const float* conv1_w = (const float*)d_in[2];
  const float* convs_w = (const float*)d_in[3];
  const float* convs_b = (const float*)d_in[4];
  const float* bn1_g = (const float*)d_in[5];
  const float* bn1_b = (const float*)d_in[6];
  const float* fc1_w = (const float*)d_in[7];
  const float* fc1_b = (const float*)d_in[8];
  const float* bn2_g = (const float*)d_in[9];
  const float* bn2_b = (const float*)d_in[10];
  const float* fc2_w = (const float*)d_in[11];
  const float* fc2_b = (const float*)d_in[12];
  const float* bn3_g = (const float*)d_in[13];
  const float* bn3_b = (const float*)d_in[14];
  const float* fc3_w = (const float*)d_in[15];
  const float* fc3_b = (const float*)d_in[16];
  float* out = (float*)d_out;

  // workspace carve-up (~105 MB)
  char* ws = (char*)d_ws;
  size_t off = 0;
  auto alloc = [&](size_t bytes) -> void* {
    off = (off + 255) & ~(size_t)255;
    void* p = ws + off;
    off += bytes;
    return p;
  };
  float* tb[3];
  for (int i = 0; i < 3; i++) tb[i] = (float*)alloc((size_t)N_NODES * DD1 * 4);
  float* bufA = (float*)alloc((size_t)N_NODES * DD1 * 4);
  float* bufB = (float*)alloc((size_t)N_NODES * DD1 * 4);
  int* ideg = (int*)alloc(N_NODES * 4);
  int* rowptr = (int*)alloc((N_NODES + 1) * 4);
  int* cnt = (int*)alloc(N_NODES * 4);
  int* col = (int*)alloc(N_EDGES * 4);
  float* wcsr = (float*)alloc(N_EDGES * 4);
  float* dinv = (float*)alloc(N_NODES * 4);
  float* bnacc = (float*)alloc(512 * 4);
  int* flag = (int*)alloc(4);
  if (off > ws_size) return;  // insufficient workspace -> visible failure

  auto gemm = [&](const float* A, const float* B, float* C, int M, int Kd, int Nd, int acc) {
    dim3 grid((M + 63) / 64, Nd / 64);
    gemm64_kernel<<<grid, dim3(256), 0, stream>>>(A, B, C, M, Kd, Nd, acc);
  };
  auto lhat = [&](int F, const float* in, float* o, const float* tx0, float scale) {
    if (F == 128)
      lhat_kernel<128><<<N_NODES, 128, 0, stream>>>(in, o, rowptr, col, wcsr, tx0, scale);
    else
      lhat_kernel<256><<<N_NODES, 256, 0, stream>>>(in, o, rowptr, col, wcsr, tx0, scale);
  };
  // out = sum_k T_k @ W[k];  T0=h, T1=Lhat h, Tk = 2 Lhat T_{k-1} - T_{k-2}
  auto cheb = [&](const float* h, int F, const float* W, float* o) {
    gemm(h, W, o, N_NODES, F, DD1, 0);
    lhat(F, h, tb[0], nullptr, 1.f);
    gemm(tb[0], W + (size_t)F * DD1, o, N_NODES, F, DD1, 1);
    const float* Tm2 = h;
    const float* Tm1 = tb[0];
    int nxt = 1;
    for (int k = 2; k < K_CHEB; k++) {
      float* tgt = tb[nxt];
      lhat(F, Tm1, tgt, Tm2, 2.f);
      gemm(tgt, W + (size_t)k * F * DD1, o, N_NODES, F, DD1, 1);
      Tm2 = Tm1;
      Tm1 = tgt;
      nxt = (nxt + 1) % 3;
    }
  };

  // ---- graph structures ----
  hipMemsetAsync(ideg, 0, N_NODES * 4, stream);
  hipMemsetAsync(cnt, 0, N_NODES * 4, stream);
  detect_idx_kernel<<<1, 64, 0, stream>>>(ei, flag);
  deg_kernel<<<(N_EDGES + 255) / 256, 256, 0, stream>>>(ei, flag, ideg);
  dinv_kernel<<<(N_NODES + 255) / 256, 256, 0, stream>>>(ideg, dinv);
  scan_kernel<<<1, 1024, 0, stream>>>(ideg, rowptr);
  fill_csr_kernel<<<(N_EDGES + 255) / 256, 256, 0, stream>>>(ei, flag, dinv, rowptr, cnt, col, wcsr);

  // ---- conv1: cheb(128->256), relu ----
  cheb(x, FDIM_IN, conv1_w, bufA);
  bias_act_kernel<<<(N_NODES * DD1 + 255) / 256, 256, 0, stream>>>(bufA, nullptr, N_NODES * DD1, DD1 - 1, 1);

  // ---- convs 2..4: cheb(256->256)+bias, relu, bn1 ----
  float* h = bufA;
  float* o = bufB;
  for (int l = 0; l < 3; l++) {
    cheb(h, DD1, convs_w + (size_t)l * K_CHEB * DD1 * DD1, o);
    bias_act_kernel<<<(N_NODES * DD1 + 255) / 256, 256, 0, stream>>>(o, convs_b + (size_t)l * DD1,
                                                                     N_NODES * DD1, DD1 - 1, 1);
    hipMemsetAsync(bnacc, 0, 512 * 4, stream);
    bn_stats_kernel<<<128, 256, 0, stream>>>(o, bnacc, N_NODES, DD1);
    bn_apply_kernel<<<(N_NODES * DD1 + 255) / 256, 256, 0, stream>>>(o, bnacc, bn1_g, bn1_b,
                                                                     N_NODES * DD1, DD1 - 1, 0,
                                                                     1.f / N_NODES);
    float* t = h; h = o; o = t;
  }

  // ---- fc1 (256->128) + bias, bn2, relu ----
  float* f1 = tb[0];
  gemm(h, fc1_w, f1, N_NODES, DD1, DD2, 0);
  bias_act_kernel<<<(N_NODES * DD2 + 255) / 256, 256, 0, stream>>>(f1, fc1_b, N_NODES * DD2, DD2 - 1, 0);
  hipMemsetAsync(bnacc, 0, 512 * 4, stream);
  bn_stats_kernel<<<128, 256, 0, stream>>>(f1, bnacc, N_NODES, DD2);
  bn_apply_kernel<<<(N_NODES * DD2 + 255) / 256, 256, 0, stream>>>(f1, bnacc, bn2_g, bn2_b,
                                                                   N_NODES * DD2, DD2 - 1, 1,
                                                                   1.f / N_NODES);

  // ---- fc2 (128->64) + bias, bn3 ----
  float* f2 = tb[1];
  gemm(f1, fc2_w, f2, N_NODES, DD2, DD3, 0);
  bias_act_kernel<<<(N_NODES * DD3 + 255) / 256, 256, 0, stream>>>(f2, fc2_b, N_NODES * DD3, DD3 - 1, 0);
  hipMemsetAsync(bnacc, 0, 512 * 4, stream);
  bn_stats_kernel<<<128, 256, 0, stream>>>(f2, bnacc, N_NODES, DD3);
  bn_apply_kernel<<<(N_NODES * DD3 + 255) / 256, 256, 0, stream>>>(f2, bnacc, bn3_g, bn3_b,
                                                                   N_NODES * DD3, DD3 - 1, 0,
                                                                   1.f / N_NODES);

  // ---- fc3 (64->1) ----
  fc3_kernel<<<(N_NODES + 3) / 4, 256, 0, stream>>>(f2, fc3_w, fc3_b, out);
}

// Round 3
// 2519.074 us; speedup vs baseline: 1.9131x; 1.9131x over previous
//
#include <hip/hip_runtime.h>
#include <hip/hip_bf16.h>
#include <stdint.h>

// ChebNet: fp32 Chebyshev recurrence (gather CSR), bf16 concat-T MFMA GEMM
// per layer (2 chunks of 5 orders), fp32 head.
// R3 fix: lhat2<128> grid was N/2 (needs N/8, 8 nodes/block) -> OOB fault.

#define N_NODES 20000
#define N_EDGES 320000
#define FDIM_IN 128
#define DD1 256
#define DD2 128
#define DD3 64
#define K_CHEB 10
#define EPSBN 1e-5f

typedef unsigned short u16;
typedef __attribute__((ext_vector_type(8))) short short8;
typedef __attribute__((ext_vector_type(4))) float floatx4;

__device__ __forceinline__ u16 f2bf(float v) {
  __hip_bfloat16 b = __float2bfloat16(v);
  return *reinterpret_cast<u16*>(&b);
}

// ---------------- graph setup ----------------
__global__ void detect_idx_kernel(const void* ei, int* flag) {
  int t = threadIdx.x;
  const int* p = (const int*)ei;
  int v = p[2 * t + 1];
  unsigned long long b = __ballot(v == 0);
  if (t == 0) *flag = (b == ~0ULL) ? 1 : 0;
}

__device__ __forceinline__ int load_edge(const void* ei, int mode64, long long pos) {
  return mode64 ? (int)((const long long*)ei)[pos] : ((const int*)ei)[pos];
}

__global__ void deg_kernel(const void* ei, const int* __restrict__ flag, int* __restrict__ ideg) {
  int e = blockIdx.x * blockDim.x + threadIdx.x;
  if (e < N_EDGES) {
    int d = load_edge(ei, *flag, (long long)N_EDGES + e);
    atomicAdd(&ideg[d], 1);
  }
}

__global__ void dinv_kernel(const int* __restrict__ ideg, float* __restrict__ dinv) {
  int n = blockIdx.x * blockDim.x + threadIdx.x;
  if (n < N_NODES) {
    int d = ideg[n];
    dinv[n] = d > 0 ? rsqrtf((float)d) : 0.f;
  }
}

__global__ __launch_bounds__(1024) void scan_kernel(const int* __restrict__ ideg, int* __restrict__ rowptr) {
  __shared__ int part[1024];
  int tid = threadIdx.x;
  const int CH = (N_NODES + 1023) / 1024;
  int base = tid * CH;
  int s = 0;
  for (int i = 0; i < CH; i++) { int idx = base + i; if (idx < N_NODES) s += ideg[idx]; }
  part[tid] = s;
  __syncthreads();
  for (int off = 1; off < 1024; off <<= 1) {
    int v = (tid >= off) ? part[tid - off] : 0;
    __syncthreads();
    part[tid] += v;
    __syncthreads();
  }
  int run = (tid == 0) ? 0 : part[tid - 1];
  for (int i = 0; i < CH; i++) { int idx = base + i; if (idx < N_NODES) { rowptr[idx] = run; run += ideg[idx]; } }
  if (tid == 1023) rowptr[N_NODES] = run;
}

__global__ void fill_csr_kernel(const void* ei, const int* __restrict__ flag,
                                const float* __restrict__ dinv, const int* __restrict__ rowptr,
                                int* __restrict__ cnt, int* __restrict__ col, float* __restrict__ wcsr) {
  int e = blockIdx.x * blockDim.x + threadIdx.x;
  if (e < N_EDGES) {
    int m = *flag;
    int s = load_edge(ei, m, e);
    int d = load_edge(ei, m, (long long)N_EDGES + e);
    int pos = rowptr[d] + atomicAdd(&cnt[d], 1);
    col[pos] = s;
    wcsr[pos] = -dinv[s] * dinv[d];
  }
}

// ---------------- weight transpose-convert: W[KF][256] fp32 -> Wt[256][KF] bf16 ----------------
__global__ __launch_bounds__(256) void wt_kernel(const float* __restrict__ W, u16* __restrict__ Wt, int KF) {
  __shared__ float sm[32][36];
  int kf0 = blockIdx.x * 32, n0 = blockIdx.y * 32;
  int r = threadIdx.x >> 3, c4 = (threadIdx.x & 7) * 4;
  float4 v = *(const float4*)(W + (size_t)(kf0 + r) * 256 + n0 + c4);
  sm[r][c4 + 0] = v.x; sm[r][c4 + 1] = v.y; sm[r][c4 + 2] = v.z; sm[r][c4 + 3] = v.w;
  __syncthreads();
  int on = threadIdx.x >> 3, okf4 = (threadIdx.x & 7) * 4;
  ushort4 u;
  u.x = f2bf(sm[okf4 + 0][on]);
  u.y = f2bf(sm[okf4 + 1][on]);
  u.z = f2bf(sm[okf4 + 2][on]);
  u.w = f2bf(sm[okf4 + 3][on]);
  *(ushort4*)(Wt + (size_t)(n0 + on) * KF + kf0 + okf4) = u;
}

// ---------------- convert h fp32 -> bf16 into concat slot 0 ----------------
template <int F>
__global__ void convert_cat_kernel(const float* __restrict__ in, u16* __restrict__ cat) {
  constexpr int F4 = F / 4;
  int i = blockIdx.x * blockDim.x + threadIdx.x;  // over N*F4
  int n = i / F4, f4 = i % F4;
  float4 v = ((const float4*)in)[i];
  ushort4 u;
  u.x = f2bf(v.x); u.y = f2bf(v.y); u.z = f2bf(v.z); u.w = f2bf(v.w);
  *(ushort4*)(cat + (size_t)n * (5 * F) + f4 * 4) = u;
}

// ---------------- L_hat: out = scale*gather - tx0 ; also bf16 copy into concat slot ----------------
template <int F>
__global__ void lhat2_kernel(const float* __restrict__ in, float* __restrict__ out,
                             const float* __restrict__ tx0,
                             const int* __restrict__ rowptr, const int* __restrict__ col,
                             const float* __restrict__ w, float scale,
                             u16* __restrict__ cat, int slotOff) {
  constexpr int L = F / 4;        // lanes per node
  constexpr int NPB = 256 / L;    // nodes per block
  int node = blockIdx.x * NPB + threadIdx.x / L;
  int ln = threadIdx.x % L;
  if (node >= N_NODES) return;
  const float4* in4 = (const float4*)in;
  int beg = rowptr[node], end = rowptr[node + 1];
  float ax = 0, ay = 0, az = 0, aw = 0;
  float bx = 0, by = 0, bz = 0, bw = 0;
  int e = beg;
  for (; e + 1 < end; e += 2) {
    int c0 = col[e], c1 = col[e + 1];
    float w0 = w[e], w1 = w[e + 1];
    float4 v0 = in4[(size_t)c0 * L + ln];
    float4 v1 = in4[(size_t)c1 * L + ln];
    ax += w0 * v0.x; ay += w0 * v0.y; az += w0 * v0.z; aw += w0 * v0.w;
    bx += w1 * v1.x; by += w1 * v1.y; bz += w1 * v1.z; bw += w1 * v1.w;
  }
  if (e < end) {
    int c0 = col[e];
    float w0 = w[e];
    float4 v0 = in4[(size_t)c0 * L + ln];
    ax += w0 * v0.x; ay += w0 * v0.y; az += w0 * v0.z; aw += w0 * v0.w;
  }
  float4 r;
  r.x = scale * (ax + bx); r.y = scale * (ay + by);
  r.z = scale * (az + bz); r.w = scale * (aw + bw);
  if (tx0) {
    float4 t = ((const float4*)tx0)[(size_t)node * L + ln];
    r.x -= t.x; r.y -= t.y; r.z -= t.z; r.w -= t.w;
  }
  ((float4*)out)[(size_t)node * L + ln] = r;
  ushort4 u;
  u.x = f2bf(r.x); u.y = f2bf(r.y); u.z = f2bf(r.z); u.w = f2bf(r.w);
  *(ushort4*)(cat + (size_t)node * (5 * F) + slotOff + 4 * ln) = u;
}

// ---------------- bf16 MFMA GEMM: C[M][256] (+)= A[M][Kc]bf16 @ Wt[256][ldB]^T ----------------
// Tile 64(M) x 128(N) x 64(K); 4 waves, each 32x64 (Mrep=2, Nrep=4). XOR-swizzled LDS.
__global__ __launch_bounds__(256) void gemm_cat_kernel(
    const u16* __restrict__ A, int ldA, const u16* __restrict__ B, int ldB, int kBase,
    int Kc, float* __restrict__ C, const float* __restrict__ bias, int M,
    int accFlag, int epiFlag, int reluFlag) {
  __shared__ __align__(16) u16 As[64 * 64];
  __shared__ __align__(16) u16 Bs[128 * 64];
  int tid = threadIdx.x;
  int lane = tid & 63, wave = tid >> 6;
  int wr = wave >> 1, wc = wave & 1;
  int l15 = lane & 15, l16 = lane >> 4;
  int m0 = blockIdx.x * 64, n0 = blockIdx.y * 128;
  floatx4 acc[2][4];
#pragma unroll
  for (int m = 0; m < 2; m++)
#pragma unroll
    for (int n = 0; n < 4; n++) acc[m][n] = (floatx4){0.f, 0.f, 0.f, 0.f};
  int srow = tid >> 3;            // 0..31
  int skc = (tid & 7) * 8;        // element offset, 16B chunks

  for (int k0 = 0; k0 < Kc; k0 += 64) {
    uint4 av[2], bv[4];
#pragma unroll
    for (int p = 0; p < 2; p++) {
      int row = srow + p * 32;
      int gm = m0 + row;
      av[p] = (gm < M) ? *(const uint4*)(A + (size_t)gm * ldA + k0 + skc)
                       : (uint4){0u, 0u, 0u, 0u};
    }
#pragma unroll
    for (int p = 0; p < 4; p++) {
      int row = srow + p * 32;
      bv[p] = *(const uint4*)(B + (size_t)(n0 + row) * ldB + kBase + k0 + skc);
    }
    __syncthreads();  // protect previous iteration's LDS reads
#pragma unroll
    for (int p = 0; p < 2; p++) {
      int row = srow + p * 32;
      *(uint4*)((char*)As + row * 128 + ((skc * 2) ^ ((row & 7) << 4))) = av[p];
    }
#pragma unroll
    for (int p = 0; p < 4; p++) {
      int row = srow + p * 32;
      *(uint4*)((char*)Bs + row * 128 + ((skc * 2) ^ ((row & 7) << 4))) = bv[p];
    }
    __syncthreads();
#pragma unroll
    for (int kk = 0; kk < 2; kk++) {
      int kb = kk * 64 + l16 * 16;  // byte offset of 16B chunk within row
      short8 a[2];
#pragma unroll
      for (int m = 0; m < 2; m++) {
        int r = wr * 32 + m * 16 + l15;
        a[m] = *(short8*)((char*)As + r * 128 + (kb ^ ((r & 7) << 4)));
      }
#pragma unroll
      for (int n = 0; n < 4; n++) {
        int r = wc * 64 + n * 16 + l15;
        short8 b = *(short8*)((char*)Bs + r * 128 + (kb ^ ((r & 7) << 4)));
        acc[0][n] = __builtin_amdgcn_mfma_f32_16x16x32_bf16(a[0], b, acc[0][n], 0, 0, 0);
        acc[1][n] = __builtin_amdgcn_mfma_f32_16x16x32_bf16(a[1], b, acc[1][n], 0, 0, 0);
      }
    }
  }
#pragma unroll
  for (int m = 0; m < 2; m++)
#pragma unroll
    for (int n = 0; n < 4; n++)
#pragma unroll
      for (int j = 0; j < 4; j++) {
        int row = m0 + wr * 32 + m * 16 + l16 * 4 + j;
        int colI = n0 + wc * 64 + n * 16 + l15;
        if (row < M) {
          size_t idx = (size_t)row * 256 + colI;
          float v = acc[m][n][j];
          if (accFlag) v += C[idx];
          if (epiFlag) {
            if (bias) v += bias[colI];
            if (reluFlag) v = fmaxf(v, 0.f);
          }
          C[idx] = v;
        }
      }
}

// ---------------- fp32 GEMM for head ----------------
__global__ __launch_bounds__(256) void gemm64_kernel(const float* __restrict__ A, const float* __restrict__ B,
                                                     float* __restrict__ C, int M, int Kd, int Nd,
                                                     int accumulate) {
  __shared__ float As[16][68];
  __shared__ float Bs[16][68];
  int bm = blockIdx.x * 64;
  int bn = blockIdx.y * 64;
  int t = threadIdx.x;
  int tm = t >> 4, tn = t & 15;
  float acc[4][4] = {};
  for (int k0 = 0; k0 < Kd; k0 += 16) {
#pragma unroll
    for (int i = 0; i < 4; i++) {
      int idx = t + i * 256;
      int m = idx >> 4, kk = idx & 15;
      int gm = bm + m;
      As[kk][m] = (gm < M) ? A[(size_t)gm * Kd + k0 + kk] : 0.f;
    }
#pragma unroll
    for (int i = 0; i < 4; i++) {
      int idx = t + i * 256;
      int kk = idx >> 6, n = idx & 63;
      Bs[kk][n] = B[(size_t)(k0 + kk) * Nd + bn + n];
    }
    __syncthreads();
#pragma unroll
    for (int kk = 0; kk < 16; kk++) {
      float a0 = As[kk][tm * 4 + 0], a1 = As[kk][tm * 4 + 1];
      float a2 = As[kk][tm * 4 + 2], a3 = As[kk][tm * 4 + 3];
      float b0 = Bs[kk][tn * 4 + 0], b1 = Bs[kk][tn * 4 + 1];
      float b2 = Bs[kk][tn * 4 + 2], b3 = Bs[kk][tn * 4 + 3];
      acc[0][0] += a0 * b0; acc[0][1] += a0 * b1; acc[0][2] += a0 * b2; acc[0][3] += a0 * b3;
      acc[1][0] += a1 * b0; acc[1][1] += a1 * b1; acc[1][2] += a1 * b2; acc[1][3] += a1 * b3;
      acc[2][0] += a2 * b0; acc[2][1] += a2 * b1; acc[2][2] += a2 * b2; acc[2][3] += a2 * b3;
      acc[3][0] += a3 * b0; acc[3][1] += a3 * b1; acc[3][2] += a3 * b2; acc[3][3] += a3 * b3;
    }
    __syncthreads();
  }
#pragma unroll
  for (int i = 0; i < 4; i++) {
    int gm = bm + tm * 4 + i;
    if (gm < M) {
      float* cp = C + (size_t)gm * Nd + bn + tn * 4;
      if (accumulate) {
        cp[0] += acc[i][0]; cp[1] += acc[i][1]; cp[2] += acc[i][2]; cp[3] += acc[i][3];
      } else {
        cp[0] = acc[i][0]; cp[1] = acc[i][1]; cp[2] = acc[i][2]; cp[3] = acc[i][3];
      }
    }
  }
}

// ---------------- elementwise / BN / head ----------------
__global__ void bias_act_kernel(float* __restrict__ h, const float* __restrict__ bias,
                                int total, int mask, int relu) {
  int i = blockIdx.x * blockDim.x + threadIdx.x;
  if (i < total) {
    float v = h[i];
    if (bias) v += bias[i & mask];
    if (relu) v = fmaxf(v, 0.f);
    h[i] = v;
  }
}

__global__ __launch_bounds__(256) void bn_stats_kernel(const float* __restrict__ h, float* __restrict__ acc,
                                                       int rows, int D) {
  int f = threadIdx.x;
  if (f >= D) return;
  float s = 0.f, q = 0.f;
  for (int r = blockIdx.x; r < rows; r += gridDim.x) {
    float v = h[(size_t)r * D + f];
    s += v;
    q += v * v;
  }
  atomicAdd(&acc[f], s);
  atomicAdd(&acc[256 + f], q);
}

__global__ void bn_apply_kernel(float* __restrict__ h, const float* __restrict__ acc,
                                const float* __restrict__ g, const float* __restrict__ b,
                                int total, int mask, int relu, float invRows) {
  int i = blockIdx.x * blockDim.x + threadIdx.x;
  if (i < total) {
    int f = i & mask;
    float m = acc[f] * invRows;
    float var = acc[256 + f] * invRows - m * m;
    float r = (h[i] - m) * rsqrtf(var + EPSBN) * g[f] + b[f];
    if (relu) r = fmaxf(r, 0.f);
    h[i] = r;
  }
}

__global__ void fc3_kernel(const float* __restrict__ h, const float* __restrict__ w,
                           const float* __restrict__ b, float* __restrict__ out) {
  int node = blockIdx.x * 4 + (threadIdx.x >> 6);
  int lane = threadIdx.x & 63;
  if (node >= N_NODES) return;
  float v = h[(size_t)node * DD3 + lane] * w[lane];
#pragma unroll
  for (int off = 32; off > 0; off >>= 1) v += __shfl_down(v, off);
  if (lane == 0) out[node] = v + b[0];
}

// ---------------- host ----------------
extern "C" void kernel_launch(void* const* d_in, const int* in_sizes, int n_in,
                              void* d_out, int out_size, void* d_ws, size_t ws_size,
                              hipStream_t stream) {
  const float* x = (const float*)d_in[0];
  const void* ei = d_in[1];
  const float* conv1_w = (const float*)d_in[2];
  const float* convs_w = (const float*)d_in[3];
  const float* convs_b = (const float*)d_in[4];
  const float* bn1_g = (const float*)d_in[5];
  const float* bn1_b = (const float*)d_in[6];
  const float* fc1_w = (const float*)d_in[7];
  const float* fc1_b = (const float*)d_in[8];
  const float* bn2_g = (const float*)d_in[9];
  const float* bn2_b = (const float*)d_in[10];
  const float* fc2_w = (const float*)d_in[11];
  const float* fc2_b = (const float*)d_in[12];
  const float* bn3_g = (const float*)d_in[13];
  const float* bn3_b = (const float*)d_in[14];
  const float* fc3_w = (const float*)d_in[15];
  const float* fc3_b = (const float*)d_in[16];
  float* out = (float*)d_out;

  char* ws = (char*)d_ws;
  size_t off = 0;
  auto alloc = [&](size_t bytes) -> void* {
    off = (off + 255) & ~(size_t)255;
    void* p = ws + off;
    off += bytes;
    return p;
  };
  float* tb[3];
  for (int i = 0; i < 3; i++) tb[i] = (float*)alloc((size_t)N_NODES * DD1 * 4);
  float* bufA = (float*)alloc((size_t)N_NODES * DD1 * 4);
  float* bufB = (float*)alloc((size_t)N_NODES * DD1 * 4);
  u16* Tcat = (u16*)alloc((size_t)N_NODES * 5 * DD1 * 2);   // 5 slots (chunked)
  u16* Wt = (u16*)alloc((size_t)(1280 * 256 + 3 * 2560 * 256) * 2);
  int* ideg = (int*)alloc(N_NODES * 4);
  int* rowptr = (int*)alloc((N_NODES + 1) * 4);
  int* cnt = (int*)alloc(N_NODES * 4);
  int* col = (int*)alloc(N_EDGES * 4);
  float* wcsr = (float*)alloc(N_EDGES * 4);
  float* dinv = (float*)alloc(N_NODES * 4);
  float* bnacc = (float*)alloc(512 * 4);
  int* flag = (int*)alloc(4);
  if (off > ws_size) return;

  // ---- one-time weight transpose to bf16 [256][KF] ----
  wt_kernel<<<dim3(1280 / 32, 8), 256, 0, stream>>>(conv1_w, Wt, 1280);
  for (int l = 0; l < 3; l++)
    wt_kernel<<<dim3(2560 / 32, 8), 256, 0, stream>>>(convs_w + (size_t)l * 655360,
                                                      Wt + 327680 + (size_t)l * 655360, 2560);

  // ---- graph structures ----
  hipMemsetAsync(ideg, 0, N_NODES * 4, stream);
  hipMemsetAsync(cnt, 0, N_NODES * 4, stream);
  detect_idx_kernel<<<1, 64, 0, stream>>>(ei, flag);
  deg_kernel<<<(N_EDGES + 255) / 256, 256, 0, stream>>>(ei, flag, ideg);
  dinv_kernel<<<(N_NODES + 255) / 256, 256, 0, stream>>>(ideg, dinv);
  scan_kernel<<<1, 1024, 0, stream>>>(ideg, rowptr);
  fill_csr_kernel<<<(N_EDGES + 255) / 256, 256, 0, stream>>>(ei, flag, dinv, rowptr, cnt, col, wcsr);

  auto lhat = [&](int F, const float* in, float* o, const float* tx0, float scale, int slot) {
    if (F == 128)
      lhat2_kernel<128><<<(N_NODES + 7) / 8, 256, 0, stream>>>(in, o, tx0, rowptr, col, wcsr,
                                                               scale, Tcat, slot * 128);
    else
      lhat2_kernel<256><<<(N_NODES + 3) / 4, 256, 0, stream>>>(in, o, tx0, rowptr, col, wcsr,
                                                               scale, Tcat, slot * 256);
  };
  auto gemm_cat = [&](int F, const u16* WtL, float* C, const float* bias, int chunk, int relu) {
    int Kc = 5 * F, KF = 10 * F;
    gemm_cat_kernel<<<dim3((N_NODES + 63) / 64, 2), 256, 0, stream>>>(
        Tcat, Kc, WtL, KF, chunk * Kc, Kc, C, bias, N_NODES, chunk, chunk, relu);
  };
  // per layer: T0..T4 -> GEMM chunk0 ; T5..T9 -> GEMM chunk1 (+bias/relu)
  auto cheb = [&](const float* hin, int F, const u16* WtL, const float* bias, float* hout, int relu) {
    int F4 = F / 4;
    if (F == 128)
      convert_cat_kernel<128><<<N_NODES * F4 / 256, 256, 0, stream>>>(hin, Tcat);
    else
      convert_cat_kernel<256><<<N_NODES * F4 / 256, 256, 0, stream>>>(hin, Tcat);
    lhat(F, hin, tb[0], nullptr, 1.f, 1);    // T1
    lhat(F, tb[0], tb[1], hin, 2.f, 2);      // T2
    lhat(F, tb[1], tb[2], tb[0], 2.f, 3);    // T3
    lhat(F, tb[2], tb[0], tb[1], 2.f, 4);    // T4
    gemm_cat(F, WtL, hout, bias, 0, relu);
    lhat(F, tb[0], tb[1], tb[2], 2.f, 0);    // T5
    lhat(F, tb[1], tb[2], tb[0], 2.f, 1);    // T6
    lhat(F, tb[2], tb[0], tb[1], 2.f, 2);    // T7
    lhat(F, tb[0], tb[1], tb[2], 2.f, 3);    // T8
    lhat(F, tb[1], tb[2], tb[0], 2.f, 4);    // T9
    gemm_cat(F, WtL, hout, bias, 1, relu);
  };

  // ---- conv1: cheb(128->256) + relu ----
  cheb(x, FDIM_IN, Wt, nullptr, bufA, 1);

  // ---- convs 2..4: cheb(256->256)+bias+relu, bn1 ----
  float* h = bufA;
  float* o = bufB;
  for (int l = 0; l < 3; l++) {
    const u16* WtL = Wt + 327680 + (size_t)l * 655360;
    cheb(h, DD1, WtL, convs_b + (size_t)l * DD1, o, 1);
    hipMemsetAsync(bnacc, 0, 512 * 4, stream);
    bn_stats_kernel<<<128, 256, 0, stream>>>(o, bnacc, N_NODES, DD1);
    bn_apply_kernel<<<(N_NODES * DD1 + 255) / 256, 256, 0, stream>>>(o, bnacc, bn1_g, bn1_b,
                                                                     N_NODES * DD1, DD1 - 1, 0,
                                                                     1.f / N_NODES);
    float* t = h; h = o; o = t;
  }

  // ---- fc1 (256->128) + bias, bn2, relu ----
  float* f1 = tb[0];
  gemm64_kernel<<<dim3((N_NODES + 63) / 64, DD2 / 64), 256, 0, stream>>>(h, fc1_w, f1, N_NODES, DD1, DD2, 0);
  bias_act_kernel<<<(N_NODES * DD2 + 255) / 256, 256, 0, stream>>>(f1, fc1_b, N_NODES * DD2, DD2 - 1, 0);
  hipMemsetAsync(bnacc, 0, 512 * 4, stream);
  bn_stats_kernel<<<128, 256, 0, stream>>>(f1, bnacc, N_NODES, DD2);
  bn_apply_kernel<<<(N_NODES * DD2 + 255) / 256, 256, 0, stream>>>(f1, bnacc, bn2_g, bn2_b,
                                                                   N_NODES * DD2, DD2 - 1, 1,
                                                                   1.f / N_NODES);

  // ---- fc2 (128->64) + bias, bn3 ----
  float* f2 = tb[1];
  gemm64_kernel<<<dim3((N_NODES + 63) / 64, 1), 256, 0, stream>>>(f1, fc2_w, f2, N_NODES, DD2, DD3, 0);
  bias_act_kernel<<<(N_NODES * DD3 + 255) / 256, 256, 0, stream>>>(f2, fc2_b, N_NODES * DD3, DD3 - 1, 0);
  hipMemsetAsync(bnacc, 0, 512 * 4, stream);
  bn_stats_kernel<<<128, 256, 0, stream>>>(f2, bnacc, N_NODES, DD3);
  bn_apply_kernel<<<(N_NODES * DD3 + 255) / 256, 256, 0, stream>>>(f2, bnacc, bn3_g, bn3_b,
                                                                   N_NODES * DD3, DD3 - 1, 0,
                                                                   1.f / N_NODES);

  // ---- fc3 (64->1) ----
  fc3_kernel<<<(N_NODES + 3) / 4, 256, 0, stream>>>(f2, fc3_w, fc3_b, out);
}

// Round 4
// 2169.640 us; speedup vs baseline: 2.2213x; 1.1611x over previous
//
#include <hip/hip_runtime.h>
#include <hip/hip_bf16.h>
#include <stdint.h>

// ChebNet: fp32 Chebyshev recurrence (gather CSR), bf16 concat-T MFMA GEMM
// per layer (2 chunks of 5 orders), fp32 head.
// R4: gemm_cat staging -> global_load_lds (width 16), linear LDS dest +
// inverse-swizzled global source; ds_read side unchanged (bit-identical math).

#define N_NODES 20000
#define N_EDGES 320000
#define FDIM_IN 128
#define DD1 256
#define DD2 128
#define DD3 64
#define K_CHEB 10
#define EPSBN 1e-5f

typedef unsigned short u16;
typedef unsigned int u32;
typedef __attribute__((ext_vector_type(8))) short short8;
typedef __attribute__((ext_vector_type(4))) float floatx4;

__device__ __forceinline__ u16 f2bf(float v) {
  __hip_bfloat16 b = __float2bfloat16(v);
  return *reinterpret_cast<u16*>(&b);
}

__device__ __forceinline__ void gld16(const void* g, void* l) {
  __builtin_amdgcn_global_load_lds((const __attribute__((address_space(1))) u32*)g,
                                   (__attribute__((address_space(3))) u32*)l, 16, 0, 0);
}

// ---------------- graph setup ----------------
__global__ void detect_idx_kernel(const void* ei, int* flag) {
  int t = threadIdx.x;
  const int* p = (const int*)ei;
  int v = p[2 * t + 1];
  unsigned long long b = __ballot(v == 0);
  if (t == 0) *flag = (b == ~0ULL) ? 1 : 0;
}

__device__ __forceinline__ int load_edge(const void* ei, int mode64, long long pos) {
  return mode64 ? (int)((const long long*)ei)[pos] : ((const int*)ei)[pos];
}

__global__ void deg_kernel(const void* ei, const int* __restrict__ flag, int* __restrict__ ideg) {
  int e = blockIdx.x * blockDim.x + threadIdx.x;
  if (e < N_EDGES) {
    int d = load_edge(ei, *flag, (long long)N_EDGES + e);
    atomicAdd(&ideg[d], 1);
  }
}

__global__ void dinv_kernel(const int* __restrict__ ideg, float* __restrict__ dinv) {
  int n = blockIdx.x * blockDim.x + threadIdx.x;
  if (n < N_NODES) {
    int d = ideg[n];
    dinv[n] = d > 0 ? rsqrtf((float)d) : 0.f;
  }
}

__global__ __launch_bounds__(1024) void scan_kernel(const int* __restrict__ ideg, int* __restrict__ rowptr) {
  __shared__ int part[1024];
  int tid = threadIdx.x;
  const int CH = (N_NODES + 1023) / 1024;
  int base = tid * CH;
  int s = 0;
  for (int i = 0; i < CH; i++) { int idx = base + i; if (idx < N_NODES) s += ideg[idx]; }
  part[tid] = s;
  __syncthreads();
  for (int off = 1; off < 1024; off <<= 1) {
    int v = (tid >= off) ? part[tid - off] : 0;
    __syncthreads();
    part[tid] += v;
    __syncthreads();
  }
  int run = (tid == 0) ? 0 : part[tid - 1];
  for (int i = 0; i < CH; i++) { int idx = base + i; if (idx < N_NODES) { rowptr[idx] = run; run += ideg[idx]; } }
  if (tid == 1023) rowptr[N_NODES] = run;
}

__global__ void fill_csr_kernel(const void* ei, const int* __restrict__ flag,
                                const float* __restrict__ dinv, const int* __restrict__ rowptr,
                                int* __restrict__ cnt, int* __restrict__ col, float* __restrict__ wcsr) {
  int e = blockIdx.x * blockDim.x + threadIdx.x;
  if (e < N_EDGES) {
    int m = *flag;
    int s = load_edge(ei, m, e);
    int d = load_edge(ei, m, (long long)N_EDGES + e);
    int pos = rowptr[d] + atomicAdd(&cnt[d], 1);
    col[pos] = s;
    wcsr[pos] = -dinv[s] * dinv[d];
  }
}

// ---------------- weight transpose-convert: W[KF][256] fp32 -> Wt[256][KF] bf16 ----------------
__global__ __launch_bounds__(256) void wt_kernel(const float* __restrict__ W, u16* __restrict__ Wt, int KF) {
  __shared__ float sm[32][36];
  int kf0 = blockIdx.x * 32, n0 = blockIdx.y * 32;
  int r = threadIdx.x >> 3, c4 = (threadIdx.x & 7) * 4;
  float4 v = *(const float4*)(W + (size_t)(kf0 + r) * 256 + n0 + c4);
  sm[r][c4 + 0] = v.x; sm[r][c4 + 1] = v.y; sm[r][c4 + 2] = v.z; sm[r][c4 + 3] = v.w;
  __syncthreads();
  int on = threadIdx.x >> 3, okf4 = (threadIdx.x & 7) * 4;
  ushort4 u;
  u.x = f2bf(sm[okf4 + 0][on]);
  u.y = f2bf(sm[okf4 + 1][on]);
  u.z = f2bf(sm[okf4 + 2][on]);
  u.w = f2bf(sm[okf4 + 3][on]);
  *(ushort4*)(Wt + (size_t)(n0 + on) * KF + kf0 + okf4) = u;
}

// ---------------- convert h fp32 -> bf16 into concat slot 0 ----------------
template <int F>
__global__ void convert_cat_kernel(const float* __restrict__ in, u16* __restrict__ cat) {
  constexpr int F4 = F / 4;
  int i = blockIdx.x * blockDim.x + threadIdx.x;  // over N*F4
  int n = i / F4, f4 = i % F4;
  float4 v = ((const float4*)in)[i];
  ushort4 u;
  u.x = f2bf(v.x); u.y = f2bf(v.y); u.z = f2bf(v.z); u.w = f2bf(v.w);
  *(ushort4*)(cat + (size_t)n * (5 * F) + f4 * 4) = u;
}

// ---------------- L_hat: out = scale*gather - tx0 ; also bf16 copy into concat slot ----------------
template <int F>
__global__ void lhat2_kernel(const float* __restrict__ in, float* __restrict__ out,
                             const float* __restrict__ tx0,
                             const int* __restrict__ rowptr, const int* __restrict__ col,
                             const float* __restrict__ w, float scale,
                             u16* __restrict__ cat, int slotOff) {
  constexpr int L = F / 4;        // lanes per node
  constexpr int NPB = 256 / L;    // nodes per block
  int node = blockIdx.x * NPB + threadIdx.x / L;
  int ln = threadIdx.x % L;
  if (node >= N_NODES) return;
  const float4* in4 = (const float4*)in;
  int beg = rowptr[node], end = rowptr[node + 1];
  float ax = 0, ay = 0, az = 0, aw = 0;
  float bx = 0, by = 0, bz = 0, bw = 0;
  int e = beg;
  for (; e + 1 < end; e += 2) {
    int c0 = col[e], c1 = col[e + 1];
    float w0 = w[e], w1 = w[e + 1];
    float4 v0 = in4[(size_t)c0 * L + ln];
    float4 v1 = in4[(size_t)c1 * L + ln];
    ax += w0 * v0.x; ay += w0 * v0.y; az += w0 * v0.z; aw += w0 * v0.w;
    bx += w1 * v1.x; by += w1 * v1.y; bz += w1 * v1.z; bw += w1 * v1.w;
  }
  if (e < end) {
    int c0 = col[e];
    float w0 = w[e];
    float4 v0 = in4[(size_t)c0 * L + ln];
    ax += w0 * v0.x; ay += w0 * v0.y; az += w0 * v0.z; aw += w0 * v0.w;
  }
  float4 r;
  r.x = scale * (ax + bx); r.y = scale * (ay + by);
  r.z = scale * (az + bz); r.w = scale * (aw + bw);
  if (tx0) {
    float4 t = ((const float4*)tx0)[(size_t)node * L + ln];
    r.x -= t.x; r.y -= t.y; r.z -= t.z; r.w -= t.w;
  }
  ((float4*)out)[(size_t)node * L + ln] = r;
  ushort4 u;
  u.x = f2bf(r.x); u.y = f2bf(r.y); u.z = f2bf(r.z); u.w = f2bf(r.w);
  *(ushort4*)(cat + (size_t)node * (5 * F) + slotOff + 4 * ln) = u;
}

// ---------------- bf16 MFMA GEMM: C[M][256] (+)= A[M][Kc]bf16 @ Wt[256][ldB]^T ----------------
// Tile 64(M) x 128(N) x 64(K); 4 waves, each 32x64 (Mrep=2, Nrep=4).
// Staging: global_load_lds w16, linear LDS dest, inverse-swizzled global src.
// Read side: XOR-swizzled ds_read (unchanged from R3 -> bit-identical results).
__global__ __launch_bounds__(256) void gemm_cat_kernel(
    const u16* __restrict__ A, int ldA, const u16* __restrict__ B, int ldB, int kBase,
    int Kc, float* __restrict__ C, const float* __restrict__ bias, int M,
    int accFlag, int epiFlag, int reluFlag) {
  __shared__ __align__(16) u16 As[64 * 64];    // 8 KB
  __shared__ __align__(16) u16 Bs[128 * 64];   // 16 KB
  int tid = threadIdx.x;
  int lane = tid & 63, wave = tid >> 6;
  int wr = wave >> 1, wc = wave & 1;
  int l15 = lane & 15, l16 = lane >> 4;
  int m0 = blockIdx.x * 64, n0 = blockIdx.y * 128;
  floatx4 acc[2][4];
#pragma unroll
  for (int m = 0; m < 2; m++)
#pragma unroll
    for (int n = 0; n < 4; n++) acc[m][n] = (floatx4){0.f, 0.f, 0.f, 0.f};

  int subrow = lane >> 3;          // 0..7
  int bcol = (lane & 7) * 16;      // byte col within 128B row

  for (int k0 = 0; k0 < Kc; k0 += 64) {
    __syncthreads();  // previous iteration's ds_reads done before overwrite
#pragma unroll
    for (int i = 0; i < 6; i++) {
      int c = wave * 6 + i;        // 0..23 chunk id, 1KB each
      if (c < 8) {
        int row = c * 8 + subrow;
        const char* src = (const char*)A + ((size_t)(m0 + row) * ldA + k0) * 2 +
                          (bcol ^ ((row & 7) << 4));
        gld16(src, (char*)As + c * 1024);
      } else {
        int row = (c - 8) * 8 + subrow;
        const char* src = (const char*)B + ((size_t)(n0 + row) * ldB + kBase + k0) * 2 +
                          (bcol ^ ((row & 7) << 4));
        gld16(src, (char*)Bs + (c - 8) * 1024);
      }
    }
    __syncthreads();  // compiler drains vmcnt before barrier -> LDS valid
#pragma unroll
    for (int kk = 0; kk < 2; kk++) {
      int kb = kk * 64 + l16 * 16;  // byte offset of 16B chunk within row
      short8 a[2];
#pragma unroll
      for (int m = 0; m < 2; m++) {
        int r = wr * 32 + m * 16 + l15;
        a[m] = *(short8*)((char*)As + r * 128 + (kb ^ ((r & 7) << 4)));
      }
#pragma unroll
      for (int n = 0; n < 4; n++) {
        int r = wc * 64 + n * 16 + l15;
        short8 b = *(short8*)((char*)Bs + r * 128 + (kb ^ ((r & 7) << 4)));
        acc[0][n] = __builtin_amdgcn_mfma_f32_16x16x32_bf16(a[0], b, acc[0][n], 0, 0, 0);
        acc[1][n] = __builtin_amdgcn_mfma_f32_16x16x32_bf16(a[1], b, acc[1][n], 0, 0, 0);
      }
    }
  }
#pragma unroll
  for (int m = 0; m < 2; m++)
#pragma unroll
    for (int n = 0; n < 4; n++)
#pragma unroll
      for (int j = 0; j < 4; j++) {
        int row = m0 + wr * 32 + m * 16 + l16 * 4 + j;
        int colI = n0 + wc * 64 + n * 16 + l15;
        if (row < M) {
          size_t idx = (size_t)row * 256 + colI;
          float v = acc[m][n][j];
          if (accFlag) v += C[idx];
          if (epiFlag) {
            if (bias) v += bias[colI];
            if (reluFlag) v = fmaxf(v, 0.f);
          }
          C[idx] = v;
        }
      }
}

// ---------------- fp32 GEMM for head ----------------
__global__ __launch_bounds__(256) void gemm64_kernel(const float* __restrict__ A, const float* __restrict__ B,
                                                     float* __restrict__ C, int M, int Kd, int Nd,
                                                     int accumulate) {
  __shared__ float As[16][68];
  __shared__ float Bs[16][68];
  int bm = blockIdx.x * 64;
  int bn = blockIdx.y * 64;
  int t = threadIdx.x;
  int tm = t >> 4, tn = t & 15;
  float acc[4][4] = {};
  for (int k0 = 0; k0 < Kd; k0 += 16) {
#pragma unroll
    for (int i = 0; i < 4; i++) {
      int idx = t + i * 256;
      int m = idx >> 4, kk = idx & 15;
      int gm = bm + m;
      As[kk][m] = (gm < M) ? A[(size_t)gm * Kd + k0 + kk] : 0.f;
    }
#pragma unroll
    for (int i = 0; i < 4; i++) {
      int idx = t + i * 256;
      int kk = idx >> 6, n = idx & 63;
      Bs[kk][n] = B[(size_t)(k0 + kk) * Nd + bn + n];
    }
    __syncthreads();
#pragma unroll
    for (int kk = 0; kk < 16; kk++) {
      float a0 = As[kk][tm * 4 + 0], a1 = As[kk][tm * 4 + 1];
      float a2 = As[kk][tm * 4 + 2], a3 = As[kk][tm * 4 + 3];
      float b0 = Bs[kk][tn * 4 + 0], b1 = Bs[kk][tn * 4 + 1];
      float b2 = Bs[kk][tn * 4 + 2], b3 = Bs[kk][tn * 4 + 3];
      acc[0][0] += a0 * b0; acc[0][1] += a0 * b1; acc[0][2] += a0 * b2; acc[0][3] += a0 * b3;
      acc[1][0] += a1 * b0; acc[1][1] += a1 * b1; acc[1][2] += a1 * b2; acc[1][3] += a1 * b3;
      acc[2][0] += a2 * b0; acc[2][1] += a2 * b1; acc[2][2] += a2 * b2; acc[2][3] += a2 * b3;
      acc[3][0] += a3 * b0; acc[3][1] += a3 * b1; acc[3][2] += a3 * b2; acc[3][3] += a3 * b3;
    }
    __syncthreads();
  }
#pragma unroll
  for (int i = 0; i < 4; i++) {
    int gm = bm + tm * 4 + i;
    if (gm < M) {
      float* cp = C + (size_t)gm * Nd + bn + tn * 4;
      if (accumulate) {
        cp[0] += acc[i][0]; cp[1] += acc[i][1]; cp[2] += acc[i][2]; cp[3] += acc[i][3];
      } else {
        cp[0] = acc[i][0]; cp[1] = acc[i][1]; cp[2] = acc[i][2]; cp[3] = acc[i][3];
      }
    }
  }
}

// ---------------- elementwise / BN / head ----------------
__global__ void bias_act_kernel(float* __restrict__ h, const float* __restrict__ bias,
                                int total, int mask, int relu) {
  int i = blockIdx.x * blockDim.x + threadIdx.x;
  if (i < total) {
    float v = h[i];
    if (bias) v += bias[i & mask];
    if (relu) v = fmaxf(v, 0.f);
    h[i] = v;
  }
}

__global__ __launch_bounds__(256) void bn_stats_kernel(const float* __restrict__ h, float* __restrict__ acc,
                                                       int rows, int D) {
  int f = threadIdx.x;
  if (f >= D) return;
  float s = 0.f, q = 0.f;
  for (int r = blockIdx.x; r < rows; r += gridDim.x) {
    float v = h[(size_t)r * D + f];
    s += v;
    q += v * v;
  }
  atomicAdd(&acc[f], s);
  atomicAdd(&acc[256 + f], q);
}

__global__ void bn_apply_kernel(float* __restrict__ h, const float* __restrict__ acc,
                                const float* __restrict__ g, const float* __restrict__ b,
                                int total, int mask, int relu, float invRows) {
  int i = blockIdx.x * blockDim.x + threadIdx.x;
  if (i < total) {
    int f = i & mask;
    float m = acc[f] * invRows;
    float var = acc[256 + f] * invRows - m * m;
    float r = (h[i] - m) * rsqrtf(var + EPSBN) * g[f] + b[f];
    if (relu) r = fmaxf(r, 0.f);
    h[i] = r;
  }
}

__global__ void fc3_kernel(const float* __restrict__ h, const float* __restrict__ w,
                           const float* __restrict__ b, float* __restrict__ out) {
  int node = blockIdx.x * 4 + (threadIdx.x >> 6);
  int lane = threadIdx.x & 63;
  if (node >= N_NODES) return;
  float v = h[(size_t)node * DD3 + lane] * w[lane];
#pragma unroll
  for (int off = 32; off > 0; off >>= 1) v += __shfl_down(v, off);
  if (lane == 0) out[node] = v + b[0];
}

// ---------------- host ----------------
extern "C" void kernel_launch(void* const* d_in, const int* in_sizes, int n_in,
                              void* d_out, int out_size, void* d_ws, size_t ws_size,
                              hipStream_t stream) {
  const float* x = (const float*)d_in[0];
  const void* ei = d_in[1];
  const float* conv1_w = (const float*)d_in[2];
  const float* convs_w = (const float*)d_in[3];
  const float* convs_b = (const float*)d_in[4];
  const float* bn1_g = (const float*)d_in[5];
  const float* bn1_b = (const float*)d_in[6];
  const float* fc1_w = (const float*)d_in[7];
  const float* fc1_b = (const float*)d_in[8];
  const float* bn2_g = (const float*)d_in[9];
  const float* bn2_b = (const float*)d_in[10];
  const float* fc2_w = (const float*)d_in[11];
  const float* fc2_b = (const float*)d_in[12];
  const float* bn3_g = (const float*)d_in[13];
  const float* bn3_b = (const float*)d_in[14];
  const float* fc3_w = (const float*)d_in[15];
  const float* fc3_b = (const float*)d_in[16];
  float* out = (float*)d_out;

  char* ws = (char*)d_ws;
  size_t off = 0;
  auto alloc = [&](size_t bytes) -> void* {
    off = (off + 255) & ~(size_t)255;
    void* p = ws + off;
    off += bytes;
    return p;
  };
  float* tb[3];
  for (int i = 0; i < 3; i++) tb[i] = (float*)alloc((size_t)N_NODES * DD1 * 4);
  float* bufA = (float*)alloc((size_t)N_NODES * DD1 * 4);
  float* bufB = (float*)alloc((size_t)N_NODES * DD1 * 4);
  u16* Tcat = (u16*)alloc((size_t)N_NODES * 5 * DD1 * 2);   // 5 slots (chunked)
  u16* Wt = (u16*)alloc((size_t)(1280 * 256 + 3 * 2560 * 256) * 2);
  int* ideg = (int*)alloc(N_NODES * 4);
  int* rowptr = (int*)alloc((N_NODES + 1) * 4);
  int* cnt = (int*)alloc(N_NODES * 4);
  int* col = (int*)alloc(N_EDGES * 4);
  float* wcsr = (float*)alloc(N_EDGES * 4);
  float* dinv = (float*)alloc(N_NODES * 4);
  float* bnacc = (float*)alloc(512 * 4);
  int* flag = (int*)alloc(4);
  if (off > ws_size) return;

  // ---- one-time weight transpose to bf16 [256][KF] ----
  wt_kernel<<<dim3(1280 / 32, 8), 256, 0, stream>>>(conv1_w, Wt, 1280);
  for (int l = 0; l < 3; l++)
    wt_kernel<<<dim3(2560 / 32, 8), 256, 0, stream>>>(convs_w + (size_t)l * 655360,
                                                      Wt + 327680 + (size_t)l * 655360, 2560);

  // ---- graph structures ----
  hipMemsetAsync(ideg, 0, N_NODES * 4, stream);
  hipMemsetAsync(cnt, 0, N_NODES * 4, stream);
  detect_idx_kernel<<<1, 64, 0, stream>>>(ei, flag);
  deg_kernel<<<(N_EDGES + 255) / 256, 256, 0, stream>>>(ei, flag, ideg);
  dinv_kernel<<<(N_NODES + 255) / 256, 256, 0, stream>>>(ideg, dinv);
  scan_kernel<<<1, 1024, 0, stream>>>(ideg, rowptr);
  fill_csr_kernel<<<(N_EDGES + 255) / 256, 256, 0, stream>>>(ei, flag, dinv, rowptr, cnt, col, wcsr);

  auto lhat = [&](int F, const float* in, float* o, const float* tx0, float scale, int slot) {
    if (F == 128)
      lhat2_kernel<128><<<(N_NODES + 7) / 8, 256, 0, stream>>>(in, o, tx0, rowptr, col, wcsr,
                                                               scale, Tcat, slot * 128);
    else
      lhat2_kernel<256><<<(N_NODES + 3) / 4, 256, 0, stream>>>(in, o, tx0, rowptr, col, wcsr,
                                                               scale, Tcat, slot * 256);
  };
  auto gemm_cat = [&](int F, const u16* WtL, float* C, const float* bias, int chunk, int relu) {
    int Kc = 5 * F, KF = 10 * F;
    gemm_cat_kernel<<<dim3((N_NODES + 63) / 64, 2), 256, 0, stream>>>(
        Tcat, Kc, WtL, KF, chunk * Kc, Kc, C, bias, N_NODES, chunk, chunk, relu);
  };
  // per layer: T0..T4 -> GEMM chunk0 ; T5..T9 -> GEMM chunk1 (+bias/relu)
  auto cheb = [&](const float* hin, int F, const u16* WtL, const float* bias, float* hout, int relu) {
    int F4 = F / 4;
    if (F == 128)
      convert_cat_kernel<128><<<N_NODES * F4 / 256, 256, 0, stream>>>(hin, Tcat);
    else
      convert_cat_kernel<256><<<N_NODES * F4 / 256, 256, 0, stream>>>(hin, Tcat);
    lhat(F, hin, tb[0], nullptr, 1.f, 1);    // T1
    lhat(F, tb[0], tb[1], hin, 2.f, 2);      // T2
    lhat(F, tb[1], tb[2], tb[0], 2.f, 3);    // T3
    lhat(F, tb[2], tb[0], tb[1], 2.f, 4);    // T4
    gemm_cat(F, WtL, hout, bias, 0, relu);
    lhat(F, tb[0], tb[1], tb[2], 2.f, 0);    // T5
    lhat(F, tb[1], tb[2], tb[0], 2.f, 1);    // T6
    lhat(F, tb[2], tb[0], tb[1], 2.f, 2);    // T7
    lhat(F, tb[0], tb[1], tb[2], 2.f, 3);    // T8
    lhat(F, tb[1], tb[2], tb[0], 2.f, 4);    // T9
    gemm_cat(F, WtL, hout, bias, 1, relu);
  };

  // ---- conv1: cheb(128->256) + relu ----
  cheb(x, FDIM_IN, Wt, nullptr, bufA, 1);

  // ---- convs 2..4: cheb(256->256)+bias+relu, bn1 ----
  float* h = bufA;
  float* o = bufB;
  for (int l = 0; l < 3; l++) {
    const u16* WtL = Wt + 327680 + (size_t)l * 655360;
    cheb(h, DD1, WtL, convs_b + (size_t)l * DD1, o, 1);
    hipMemsetAsync(bnacc, 0, 512 * 4, stream);
    bn_stats_kernel<<<128, 256, 0, stream>>>(o, bnacc, N_NODES, DD1);
    bn_apply_kernel<<<(N_NODES * DD1 + 255) / 256, 256, 0, stream>>>(o, bnacc, bn1_g, bn1_b,
                                                                     N_NODES * DD1, DD1 - 1, 0,
                                                                     1.f / N_NODES);
    float* t = h; h = o; o = t;
  }

  // ---- fc1 (256->128) + bias, bn2, relu ----
  float* f1 = tb[0];
  gemm64_kernel<<<dim3((N_NODES + 63) / 64, DD2 / 64), 256, 0, stream>>>(h, fc1_w, f1, N_NODES, DD1, DD2, 0);
  bias_act_kernel<<<(N_NODES * DD2 + 255) / 256, 256, 0, stream>>>(f1, fc1_b, N_NODES * DD2, DD2 - 1, 0);
  hipMemsetAsync(bnacc, 0, 512 * 4, stream);
  bn_stats_kernel<<<128, 256, 0, stream>>>(f1, bnacc, N_NODES, DD2);
  bn_apply_kernel<<<(N_NODES * DD2 + 255) / 256, 256, 0, stream>>>(f1, bnacc, bn2_g, bn2_b,
                                                                   N_NODES * DD2, DD2 - 1, 1,
                                                                   1.f / N_NODES);

  // ---- fc2 (128->64) + bias, bn3 ----
  float* f2 = tb[1];
  gemm64_kernel<<<dim3((N_NODES + 63) / 64, 1), 256, 0, stream>>>(f1, fc2_w, f2, N_NODES, DD2, DD3, 0);
  bias_act_kernel<<<(N_NODES * DD3 + 255) / 256, 256, 0, stream>>>(f2, fc2_b, N_NODES * DD3, DD3 - 1, 0);
  hipMemsetAsync(bnacc, 0, 512 * 4, stream);
  bn_stats_kernel<<<128, 256, 0, stream>>>(f2, bnacc, N_NODES, DD3);
  bn_apply_kernel<<<(N_NODES * DD3 + 255) / 256, 256, 0, stream>>>(f2, bnacc, bn3_g, bn3_b,
                                                                   N_NODES * DD3, DD3 - 1, 0,
                                                                   1.f / N_NODES);

  // ---- fc3 (64->1) ----
  fc3_kernel<<<(N_NODES + 3) / 4, 256, 0, stream>>>(f2, fc3_w, fc3_b, out);
}

// Round 5
// 1484.270 us; speedup vs baseline: 3.2470x; 1.4618x over previous
//
#include <hip/hip_runtime.h>
#include <hip/hip_bf16.h>
#include <stdint.h>

// ChebNet: fp16 Chebyshev T-storage living directly in the concat GEMM buffer
// (gather CSR, fp32 accumulate), f16 MFMA GEMM (2 chunks of 5 orders), fp32 head.
// R5: T-storage fp32->fp16, cat buffer IS the T storage (lhat write traffic 30->10MB,
// gather fetch halves), GEMM bf16->f16 (8x finer input rounding).

#define N_NODES 20000
#define N_EDGES 320000
#define FDIM_IN 128
#define DD1 256
#define DD2 128
#define DD3 64
#define K_CHEB 10
#define EPSBN 1e-5f

typedef unsigned short u16;
typedef unsigned int u32;
typedef _Float16 half8 __attribute__((ext_vector_type(8)));
typedef __attribute__((ext_vector_type(4))) float floatx4;

__device__ __forceinline__ u16 f2h(float v) {
  _Float16 h = (_Float16)v;
  return *reinterpret_cast<u16*>(&h);
}

__device__ __forceinline__ void gld16(const void* g, void* l) {
  __builtin_amdgcn_global_load_lds((const __attribute__((address_space(1))) u32*)g,
                                   (__attribute__((address_space(3))) u32*)l, 16, 0, 0);
}

// ---------------- graph setup ----------------
__global__ void detect_idx_kernel(const void* ei, int* flag) {
  int t = threadIdx.x;
  const int* p = (const int*)ei;
  int v = p[2 * t + 1];
  unsigned long long b = __ballot(v == 0);
  if (t == 0) *flag = (b == ~0ULL) ? 1 : 0;
}

__device__ __forceinline__ int load_edge(const void* ei, int mode64, long long pos) {
  return mode64 ? (int)((const long long*)ei)[pos] : ((const int*)ei)[pos];
}

__global__ void deg_kernel(const void* ei, const int* __restrict__ flag, int* __restrict__ ideg) {
  int e = blockIdx.x * blockDim.x + threadIdx.x;
  if (e < N_EDGES) {
    int d = load_edge(ei, *flag, (long long)N_EDGES + e);
    atomicAdd(&ideg[d], 1);
  }
}

__global__ void dinv_kernel(const int* __restrict__ ideg, float* __restrict__ dinv) {
  int n = blockIdx.x * blockDim.x + threadIdx.x;
  if (n < N_NODES) {
    int d = ideg[n];
    dinv[n] = d > 0 ? rsqrtf((float)d) : 0.f;
  }
}

__global__ __launch_bounds__(1024) void scan_kernel(const int* __restrict__ ideg, int* __restrict__ rowptr) {
  __shared__ int part[1024];
  int tid = threadIdx.x;
  const int CH = (N_NODES + 1023) / 1024;
  int base = tid * CH;
  int s = 0;
  for (int i = 0; i < CH; i++) { int idx = base + i; if (idx < N_NODES) s += ideg[idx]; }
  part[tid] = s;
  __syncthreads();
  for (int off = 1; off < 1024; off <<= 1) {
    int v = (tid >= off) ? part[tid - off] : 0;
    __syncthreads();
    part[tid] += v;
    __syncthreads();
  }
  int run = (tid == 0) ? 0 : part[tid - 1];
  for (int i = 0; i < CH; i++) { int idx = base + i; if (idx < N_NODES) { rowptr[idx] = run; run += ideg[idx]; } }
  if (tid == 1023) rowptr[N_NODES] = run;
}

__global__ void fill_csr_kernel(const void* ei, const int* __restrict__ flag,
                                const float* __restrict__ dinv, const int* __restrict__ rowptr,
                                int* __restrict__ cnt, int* __restrict__ col, float* __restrict__ wcsr) {
  int e = blockIdx.x * blockDim.x + threadIdx.x;
  if (e < N_EDGES) {
    int m = *flag;
    int s = load_edge(ei, m, e);
    int d = load_edge(ei, m, (long long)N_EDGES + e);
    int pos = rowptr[d] + atomicAdd(&cnt[d], 1);
    col[pos] = s;
    wcsr[pos] = -dinv[s] * dinv[d];
  }
}

// ---------------- weight transpose-convert: W[KF][256] fp32 -> Wt[256][KF] fp16 ----------------
__global__ __launch_bounds__(256) void wt_kernel(const float* __restrict__ W, u16* __restrict__ Wt, int KF) {
  __shared__ float sm[32][36];
  int kf0 = blockIdx.x * 32, n0 = blockIdx.y * 32;
  int r = threadIdx.x >> 3, c4 = (threadIdx.x & 7) * 4;
  float4 v = *(const float4*)(W + (size_t)(kf0 + r) * 256 + n0 + c4);
  sm[r][c4 + 0] = v.x; sm[r][c4 + 1] = v.y; sm[r][c4 + 2] = v.z; sm[r][c4 + 3] = v.w;
  __syncthreads();
  int on = threadIdx.x >> 3, okf4 = (threadIdx.x & 7) * 4;
  ushort4 u;
  u.x = f2h(sm[okf4 + 0][on]);
  u.y = f2h(sm[okf4 + 1][on]);
  u.z = f2h(sm[okf4 + 2][on]);
  u.w = f2h(sm[okf4 + 3][on]);
  *(ushort4*)(Wt + (size_t)(n0 + on) * KF + kf0 + okf4) = u;
}

// ---------------- convert h fp32 -> fp16 into cat slot 0 (T0) ----------------
template <int F>
__global__ void convert_cat_kernel(const float* __restrict__ in, u16* __restrict__ cat) {
  constexpr int F8 = F / 8;
  int i = blockIdx.x * blockDim.x + threadIdx.x;  // over N*F8
  int n = i / F8, f8 = i % F8;
  const float4* p = (const float4*)(in + (size_t)n * F + f8 * 8);
  float4 a = p[0], b = p[1];
  half8 o;
  o[0] = (_Float16)a.x; o[1] = (_Float16)a.y; o[2] = (_Float16)a.z; o[3] = (_Float16)a.w;
  o[4] = (_Float16)b.x; o[5] = (_Float16)b.y; o[6] = (_Float16)b.z; o[7] = (_Float16)b.w;
  *(half8*)(cat + (size_t)n * (5 * F) + f8 * 8) = o;
}

// ---------------- L_hat on cat slots: slot_out = scale * gather(slot_in) - slot_tx0 ----------------
template <int F, bool HAS_TX0>
__global__ void lhat3_kernel(u16* __restrict__ cat,
                             const int* __restrict__ rowptr, const int* __restrict__ col,
                             const float* __restrict__ w, float scale,
                             int inOff, int tx0Off, int outOff) {
  constexpr int L = F / 8;        // lanes per node (16B fp16 per lane)
  constexpr int NPB = 256 / L;    // nodes per block
  constexpr int R = 5 * F;        // cat row stride (halves)
  int node = blockIdx.x * NPB + threadIdx.x / L;
  int ln8 = (threadIdx.x % L) * 8;
  if (node >= N_NODES) return;
  int beg = rowptr[node], end = rowptr[node + 1];
  float a0[8] = {0.f, 0.f, 0.f, 0.f, 0.f, 0.f, 0.f, 0.f};
  float a1[8] = {0.f, 0.f, 0.f, 0.f, 0.f, 0.f, 0.f, 0.f};
  int e = beg;
  for (; e + 1 < end; e += 2) {
    int c0 = col[e], c1 = col[e + 1];
    float w0 = w[e], w1 = w[e + 1];
    half8 v0 = *(const half8*)(cat + (size_t)c0 * R + inOff + ln8);
    half8 v1 = *(const half8*)(cat + (size_t)c1 * R + inOff + ln8);
#pragma unroll
    for (int j = 0; j < 8; j++) {
      a0[j] += w0 * (float)v0[j];
      a1[j] += w1 * (float)v1[j];
    }
  }
  if (e < end) {
    int c0 = col[e];
    float w0 = w[e];
    half8 v0 = *(const half8*)(cat + (size_t)c0 * R + inOff + ln8);
#pragma unroll
    for (int j = 0; j < 8; j++) a0[j] += w0 * (float)v0[j];
  }
  float r[8];
#pragma unroll
  for (int j = 0; j < 8; j++) r[j] = scale * (a0[j] + a1[j]);
  if (HAS_TX0) {
    half8 t = *(const half8*)(cat + (size_t)node * R + tx0Off + ln8);
#pragma unroll
    for (int j = 0; j < 8; j++) r[j] -= (float)t[j];
  }
  half8 o;
#pragma unroll
  for (int j = 0; j < 8; j++) o[j] = (_Float16)r[j];
  *(half8*)(cat + (size_t)node * R + outOff + ln8) = o;
}

// ---------------- f16 MFMA GEMM: C[M][256] (+)= A[M][Kc]f16 @ Wt[256][ldB]^T ----------------
// Tile 64(M) x 128(N) x 64(K); 4 waves, each 32x64 (Mrep=2, Nrep=4).
// Staging: global_load_lds w16, linear LDS dest, inverse-swizzled global src.
__global__ __launch_bounds__(256) void gemm_cat_kernel(
    const u16* __restrict__ A, int ldA, const u16* __restrict__ B, int ldB, int kBase,
    int Kc, float* __restrict__ C, const float* __restrict__ bias, int M,
    int accFlag, int epiFlag, int reluFlag) {
  __shared__ __align__(16) u16 As[64 * 64];    // 8 KB
  __shared__ __align__(16) u16 Bs[128 * 64];   // 16 KB
  int tid = threadIdx.x;
  int lane = tid & 63, wave = tid >> 6;
  int wr = wave >> 1, wc = wave & 1;
  int l15 = lane & 15, l16 = lane >> 4;
  int m0 = blockIdx.x * 64, n0 = blockIdx.y * 128;
  floatx4 acc[2][4];
#pragma unroll
  for (int m = 0; m < 2; m++)
#pragma unroll
    for (int n = 0; n < 4; n++) acc[m][n] = (floatx4){0.f, 0.f, 0.f, 0.f};

  int subrow = lane >> 3;          // 0..7
  int bcol = (lane & 7) * 16;      // byte col within 128B row

  for (int k0 = 0; k0 < Kc; k0 += 64) {
    __syncthreads();  // previous iteration's ds_reads done before overwrite
#pragma unroll
    for (int i = 0; i < 6; i++) {
      int c = wave * 6 + i;        // 0..23 chunk id, 1KB each
      if (c < 8) {
        int row = c * 8 + subrow;
        const char* src = (const char*)A + ((size_t)(m0 + row) * ldA + k0) * 2 +
                          (bcol ^ ((row & 7) << 4));
        gld16(src, (char*)As + c * 1024);
      } else {
        int row = (c - 8) * 8 + subrow;
        const char* src = (const char*)B + ((size_t)(n0 + row) * ldB + kBase + k0) * 2 +
                          (bcol ^ ((row & 7) << 4));
        gld16(src, (char*)Bs + (c - 8) * 1024);
      }
    }
    __syncthreads();  // compiler drains vmcnt before barrier -> LDS valid
#pragma unroll
    for (int kk = 0; kk < 2; kk++) {
      int kb = kk * 64 + l16 * 16;  // byte offset of 16B chunk within row
      half8 a[2];
#pragma unroll
      for (int m = 0; m < 2; m++) {
        int r = wr * 32 + m * 16 + l15;
        a[m] = *(half8*)((char*)As + r * 128 + (kb ^ ((r & 7) << 4)));
      }
#pragma unroll
      for (int n = 0; n < 4; n++) {
        int r = wc * 64 + n * 16 + l15;
        half8 b = *(half8*)((char*)Bs + r * 128 + (kb ^ ((r & 7) << 4)));
        acc[0][n] = __builtin_amdgcn_mfma_f32_16x16x32_f16(a[0], b, acc[0][n], 0, 0, 0);
        acc[1][n] = __builtin_amdgcn_mfma_f32_16x16x32_f16(a[1], b, acc[1][n], 0, 0, 0);
      }
    }
  }
#pragma unroll
  for (int m = 0; m < 2; m++)
#pragma unroll
    for (int n = 0; n < 4; n++)
#pragma unroll
      for (int j = 0; j < 4; j++) {
        int row = m0 + wr * 32 + m * 16 + l16 * 4 + j;
        int colI = n0 + wc * 64 + n * 16 + l15;
        if (row < M) {
          size_t idx = (size_t)row * 256 + colI;
          float v = acc[m][n][j];
          if (accFlag) v += C[idx];
          if (epiFlag) {
            if (bias) v += bias[colI];
            if (reluFlag) v = fmaxf(v, 0.f);
          }
          C[idx] = v;
        }
      }
}

// ---------------- fp32 GEMM for head ----------------
__global__ __launch_bounds__(256) void gemm64_kernel(const float* __restrict__ A, const float* __restrict__ B,
                                                     float* __restrict__ C, int M, int Kd, int Nd,
                                                     int accumulate) {
  __shared__ float As[16][68];
  __shared__ float Bs[16][68];
  int bm = blockIdx.x * 64;
  int bn = blockIdx.y * 64;
  int t = threadIdx.x;
  int tm = t >> 4, tn = t & 15;
  float acc[4][4] = {};
  for (int k0 = 0; k0 < Kd; k0 += 16) {
#pragma unroll
    for (int i = 0; i < 4; i++) {
      int idx = t + i * 256;
      int m = idx >> 4, kk = idx & 15;
      int gm = bm + m;
      As[kk][m] = (gm < M) ? A[(size_t)gm * Kd + k0 + kk] : 0.f;
    }
#pragma unroll
    for (int i = 0; i < 4; i++) {
      int idx = t + i * 256;
      int kk = idx >> 6, n = idx & 63;
      Bs[kk][n] = B[(size_t)(k0 + kk) * Nd + bn + n];
    }
    __syncthreads();
#pragma unroll
    for (int kk = 0; kk < 16; kk++) {
      float a0 = As[kk][tm * 4 + 0], a1 = As[kk][tm * 4 + 1];
      float a2 = As[kk][tm * 4 + 2], a3 = As[kk][tm * 4 + 3];
      float b0 = Bs[kk][tn * 4 + 0], b1 = Bs[kk][tn * 4 + 1];
      float b2 = Bs[kk][tn * 4 + 2], b3 = Bs[kk][tn * 4 + 3];
      acc[0][0] += a0 * b0; acc[0][1] += a0 * b1; acc[0][2] += a0 * b2; acc[0][3] += a0 * b3;
      acc[1][0] += a1 * b0; acc[1][1] += a1 * b1; acc[1][2] += a1 * b2; acc[1][3] += a1 * b3;
      acc[2][0] += a2 * b0; acc[2][1] += a2 * b1; acc[2][2] += a2 * b2; acc[2][3] += a2 * b3;
      acc[3][0] += a3 * b0; acc[3][1] += a3 * b1; acc[3][2] += a3 * b2; acc[3][3] += a3 * b3;
    }
    __syncthreads();
  }
#pragma unroll
  for (int i = 0; i < 4; i++) {
    int gm = bm + tm * 4 + i;
    if (gm < M) {
      float* cp = C + (size_t)gm * Nd + bn + tn * 4;
      if (accumulate) {
        cp[0] += acc[i][0]; cp[1] += acc[i][1]; cp[2] += acc[i][2]; cp[3] += acc[i][3];
      } else {
        cp[0] = acc[i][0]; cp[1] = acc[i][1]; cp[2] = acc[i][2]; cp[3] = acc[i][3];
      }
    }
  }
}

// ---------------- elementwise / BN / head ----------------
__global__ void bias_act_kernel(float* __restrict__ h, const float* __restrict__ bias,
                                int total, int mask, int relu) {
  int i = blockIdx.x * blockDim.x + threadIdx.x;
  if (i < total) {
    float v = h[i];
    if (bias) v += bias[i & mask];
    if (relu) v = fmaxf(v, 0.f);
    h[i] = v;
  }
}

__global__ __launch_bounds__(256) void bn_stats_kernel(const float* __restrict__ h, float* __restrict__ acc,
                                                       int rows, int D) {
  int f = threadIdx.x;
  if (f >= D) return;
  float s = 0.f, q = 0.f;
  for (int r = blockIdx.x; r < rows; r += gridDim.x) {
    float v = h[(size_t)r * D + f];
    s += v;
    q += v * v;
  }
  atomicAdd(&acc[f], s);
  atomicAdd(&acc[256 + f], q);
}

__global__ void bn_apply_kernel(float* __restrict__ h, const float* __restrict__ acc,
                                const float* __restrict__ g, const float* __restrict__ b,
                                int total, int mask, int relu, float invRows) {
  int i = blockIdx.x * blockDim.x + threadIdx.x;
  if (i < total) {
    int f = i & mask;
    float m = acc[f] * invRows;
    float var = acc[256 + f] * invRows - m * m;
    float r = (h[i] - m) * rsqrtf(var + EPSBN) * g[f] + b[f];
    if (relu) r = fmaxf(r, 0.f);
    h[i] = r;
  }
}

__global__ void fc3_kernel(const float* __restrict__ h, const float* __restrict__ w,
                           const float* __restrict__ b, float* __restrict__ out) {
  int node = blockIdx.x * 4 + (threadIdx.x >> 6);
  int lane = threadIdx.x & 63;
  if (node >= N_NODES) return;
  float v = h[(size_t)node * DD3 + lane] * w[lane];
#pragma unroll
  for (int off = 32; off > 0; off >>= 1) v += __shfl_down(v, off);
  if (lane == 0) out[node] = v + b[0];
}

// ---------------- host ----------------
extern "C" void kernel_launch(void* const* d_in, const int* in_sizes, int n_in,
                              void* d_out, int out_size, void* d_ws, size_t ws_size,
                              hipStream_t stream) {
  const float* x = (const float*)d_in[0];
  const void* ei = d_in[1];
  const float* conv1_w = (const float*)d_in[2];
  const float* convs_w = (const float*)d_in[3];
  const float* convs_b = (const float*)d_in[4];
  const float* bn1_g = (const float*)d_in[5];
  const float* bn1_b = (const float*)d_in[6];
  const float* fc1_w = (const float*)d_in[7];
  const float* fc1_b = (const float*)d_in[8];
  const float* bn2_g = (const float*)d_in[9];
  const float* bn2_b = (const float*)d_in[10];
  const float* fc2_w = (const float*)d_in[11];
  const float* fc2_b = (const float*)d_in[12];
  const float* bn3_g = (const float*)d_in[13];
  const float* bn3_b = (const float*)d_in[14];
  const float* fc3_w = (const float*)d_in[15];
  const float* fc3_b = (const float*)d_in[16];
  float* out = (float*)d_out;

  char* ws = (char*)d_ws;
  size_t off = 0;
  auto alloc = [&](size_t bytes) -> void* {
    off = (off + 255) & ~(size_t)255;
    void* p = ws + off;
    off += bytes;
    return p;
  };
  float* f1buf = (float*)alloc((size_t)N_NODES * DD1 * 4);
  float* f2buf = (float*)alloc((size_t)N_NODES * DD1 * 4);
  float* bufA = (float*)alloc((size_t)N_NODES * DD1 * 4);
  float* bufB = (float*)alloc((size_t)N_NODES * DD1 * 4);
  u16* Tcat = (u16*)alloc((size_t)N_NODES * 5 * DD1 * 2);   // 5 fp16 slots (chunked)
  u16* Wt = (u16*)alloc((size_t)(1280 * 256 + 3 * 2560 * 256) * 2);
  int* ideg = (int*)alloc(N_NODES * 4);
  int* rowptr = (int*)alloc((N_NODES + 1) * 4);
  int* cnt = (int*)alloc(N_NODES * 4);
  int* col = (int*)alloc(N_EDGES * 4);
  float* wcsr = (float*)alloc(N_EDGES * 4);
  float* dinv = (float*)alloc(N_NODES * 4);
  float* bnacc = (float*)alloc(512 * 4);
  int* flag = (int*)alloc(4);
  if (off > ws_size) return;

  // ---- one-time weight transpose to fp16 [256][KF] ----
  wt_kernel<<<dim3(1280 / 32, 8), 256, 0, stream>>>(conv1_w, Wt, 1280);
  for (int l = 0; l < 3; l++)
    wt_kernel<<<dim3(2560 / 32, 8), 256, 0, stream>>>(convs_w + (size_t)l * 655360,
                                                      Wt + 327680 + (size_t)l * 655360, 2560);

  // ---- graph structures ----
  hipMemsetAsync(ideg, 0, N_NODES * 4, stream);
  hipMemsetAsync(cnt, 0, N_NODES * 4, stream);
  detect_idx_kernel<<<1, 64, 0, stream>>>(ei, flag);
  deg_kernel<<<(N_EDGES + 255) / 256, 256, 0, stream>>>(ei, flag, ideg);
  dinv_kernel<<<(N_NODES + 255) / 256, 256, 0, stream>>>(ideg, dinv);
  scan_kernel<<<1, 1024, 0, stream>>>(ideg, rowptr);
  fill_csr_kernel<<<(N_EDGES + 255) / 256, 256, 0, stream>>>(ei, flag, dinv, rowptr, cnt, col, wcsr);

  // lhat on cat slots: out = scale * gather(in) - tx0
  auto lhat = [&](int F, float scale, int inS, int tx0S, int outS) {
    if (F == 128) {
      if (tx0S < 0)
        lhat3_kernel<128, false><<<1250, 256, 0, stream>>>(Tcat, rowptr, col, wcsr, scale,
                                                           inS * 128, 0, outS * 128);
      else
        lhat3_kernel<128, true><<<1250, 256, 0, stream>>>(Tcat, rowptr, col, wcsr, scale,
                                                          inS * 128, tx0S * 128, outS * 128);
    } else {
      if (tx0S < 0)
        lhat3_kernel<256, false><<<2500, 256, 0, stream>>>(Tcat, rowptr, col, wcsr, scale,
                                                           inS * 256, 0, outS * 256);
      else
        lhat3_kernel<256, true><<<2500, 256, 0, stream>>>(Tcat, rowptr, col, wcsr, scale,
                                                          inS * 256, tx0S * 256, outS * 256);
    }
  };
  auto gemm_cat = [&](int F, const u16* WtL, float* C, const float* bias, int chunk, int relu) {
    int Kc = 5 * F, KF = 10 * F;
    gemm_cat_kernel<<<dim3((N_NODES + 63) / 64, 2), 256, 0, stream>>>(
        Tcat, Kc, WtL, KF, chunk * Kc, Kc, C, bias, N_NODES, chunk, chunk, relu);
  };
  // per layer: T0..T4 in slots 0..4 -> GEMM chunk0; T5..T9 cycle slots 0..4 -> GEMM chunk1
  auto cheb = [&](const float* hin, int F, const u16* WtL, const float* bias, float* hout, int relu) {
    if (F == 128)
      convert_cat_kernel<128><<<1250, 256, 0, stream>>>(hin, Tcat);
    else
      convert_cat_kernel<256><<<2500, 256, 0, stream>>>(hin, Tcat);
    lhat(F, 1.f, 0, -1, 1);   // T1
    lhat(F, 2.f, 1, 0, 2);    // T2
    lhat(F, 2.f, 2, 1, 3);    // T3
    lhat(F, 2.f, 3, 2, 4);    // T4
    gemm_cat(F, WtL, hout, bias, 0, relu);
    lhat(F, 2.f, 4, 3, 0);    // T5
    lhat(F, 2.f, 0, 4, 1);    // T6
    lhat(F, 2.f, 1, 0, 2);    // T7
    lhat(F, 2.f, 2, 1, 3);    // T8
    lhat(F, 2.f, 3, 2, 4);    // T9
    gemm_cat(F, WtL, hout, bias, 1, relu);
  };

  // ---- conv1: cheb(128->256) + relu ----
  cheb(x, FDIM_IN, Wt, nullptr, bufA, 1);

  // ---- convs 2..4: cheb(256->256)+bias+relu, bn1 ----
  float* h = bufA;
  float* o = bufB;
  for (int l = 0; l < 3; l++) {
    const u16* WtL = Wt + 327680 + (size_t)l * 655360;
    cheb(h, DD1, WtL, convs_b + (size_t)l * DD1, o, 1);
    hipMemsetAsync(bnacc, 0, 512 * 4, stream);
    bn_stats_kernel<<<128, 256, 0, stream>>>(o, bnacc, N_NODES, DD1);
    bn_apply_kernel<<<(N_NODES * DD1 + 255) / 256, 256, 0, stream>>>(o, bnacc, bn1_g, bn1_b,
                                                                     N_NODES * DD1, DD1 - 1, 0,
                                                                     1.f / N_NODES);
    float* t = h; h = o; o = t;
  }

  // ---- fc1 (256->128) + bias, bn2, relu ----
  float* f1 = f1buf;
  gemm64_kernel<<<dim3((N_NODES + 63) / 64, DD2 / 64), 256, 0, stream>>>(h, fc1_w, f1, N_NODES, DD1, DD2, 0);
  bias_act_kernel<<<(N_NODES * DD2 + 255) / 256, 256, 0, stream>>>(f1, fc1_b, N_NODES * DD2, DD2 - 1, 0);
  hipMemsetAsync(bnacc, 0, 512 * 4, stream);
  bn_stats_kernel<<<128, 256, 0, stream>>>(f1, bnacc, N_NODES, DD2);
  bn_apply_kernel<<<(N_NODES * DD2 + 255) / 256, 256, 0, stream>>>(f1, bnacc, bn2_g, bn2_b,
                                                                   N_NODES * DD2, DD2 - 1, 1,
                                                                   1.f / N_NODES);

  // ---- fc2 (128->64) + bias, bn3 ----
  float* f2 = f2buf;
  gemm64_kernel<<<dim3((N_NODES + 63) / 64, 1), 256, 0, stream>>>(f1, fc2_w, f2, N_NODES, DD2, DD3, 0);
  bias_act_kernel<<<(N_NODES * DD3 + 255) / 256, 256, 0, stream>>>(f2, fc2_b, N_NODES * DD3, DD3 - 1, 0);
  hipMemsetAsync(bnacc, 0, 512 * 4, stream);
  bn_stats_kernel<<<128, 256, 0, stream>>>(f2, bnacc, N_NODES, DD3);
  bn_apply_kernel<<<(N_NODES * DD3 + 255) / 256, 256, 0, stream>>>(f2, bnacc, bn3_g, bn3_b,
                                                                   N_NODES * DD3, DD3 - 1, 0,
                                                                   1.f / N_NODES);

  // ---- fc3 (64->1) ----
  fc3_kernel<<<(N_NODES + 3) / 4, 256, 0, stream>>>(f2, fc3_w, fc3_b, out);
}

// Round 6
// 1218.736 us; speedup vs baseline: 3.9544x; 1.2179x over previous
//
#include <hip/hip_runtime.h>
#include <hip/hip_bf16.h>
#include <stdint.h>

// ChebNet: fp16 Chebyshev T-storage in the concat GEMM buffer (gather CSR,
// fp32 accumulate), f16 MFMA GEMM everywhere (convs + fc head), two-pass BN.
// R6: BN rewrite (vectorized partials + reduce, fused convert in apply),
// f16 MFMA fc1/fc2, lhat unroll-4.

#define N_NODES 20000
#define N_EDGES 320000
#define FDIM_IN 128
#define DD1 256
#define DD2 128
#define DD3 64
#define K_CHEB 10
#define EPSBN 1e-5f
#define BN_B 512  // partial blocks for BN pass1

typedef unsigned short u16;
typedef unsigned int u32;
typedef _Float16 half8 __attribute__((ext_vector_type(8)));
typedef __attribute__((ext_vector_type(4))) float floatx4;

__device__ __forceinline__ u16 f2h(float v) {
  _Float16 h = (_Float16)v;
  return *reinterpret_cast<u16*>(&h);
}

__device__ __forceinline__ void gld16(const void* g, void* l) {
  __builtin_amdgcn_global_load_lds((const __attribute__((address_space(1))) u32*)g,
                                   (__attribute__((address_space(3))) u32*)l, 16, 0, 0);
}

// ---------------- graph setup ----------------
__global__ void detect_idx_kernel(const void* ei, int* flag) {
  int t = threadIdx.x;
  const int* p = (const int*)ei;
  int v = p[2 * t + 1];
  unsigned long long b = __ballot(v == 0);
  if (t == 0) *flag = (b == ~0ULL) ? 1 : 0;
}

__device__ __forceinline__ int load_edge(const void* ei, int mode64, long long pos) {
  return mode64 ? (int)((const long long*)ei)[pos] : ((const int*)ei)[pos];
}

__global__ void deg_kernel(const void* ei, const int* __restrict__ flag, int* __restrict__ ideg) {
  int e = blockIdx.x * blockDim.x + threadIdx.x;
  if (e < N_EDGES) {
    int d = load_edge(ei, *flag, (long long)N_EDGES + e);
    atomicAdd(&ideg[d], 1);
  }
}

__global__ void dinv_kernel(const int* __restrict__ ideg, float* __restrict__ dinv) {
  int n = blockIdx.x * blockDim.x + threadIdx.x;
  if (n < N_NODES) {
    int d = ideg[n];
    dinv[n] = d > 0 ? rsqrtf((float)d) : 0.f;
  }
}

__global__ __launch_bounds__(1024) void scan_kernel(const int* __restrict__ ideg, int* __restrict__ rowptr) {
  __shared__ int part[1024];
  int tid = threadIdx.x;
  const int CH = (N_NODES + 1023) / 1024;
  int base = tid * CH;
  int s = 0;
  for (int i = 0; i < CH; i++) { int idx = base + i; if (idx < N_NODES) s += ideg[idx]; }
  part[tid] = s;
  __syncthreads();
  for (int off = 1; off < 1024; off <<= 1) {
    int v = (tid >= off) ? part[tid - off] : 0;
    __syncthreads();
    part[tid] += v;
    __syncthreads();
  }
  int run = (tid == 0) ? 0 : part[tid - 1];
  for (int i = 0; i < CH; i++) { int idx = base + i; if (idx < N_NODES) { rowptr[idx] = run; run += ideg[idx]; } }
  if (tid == 1023) rowptr[N_NODES] = run;
}

__global__ void fill_csr_kernel(const void* ei, const int* __restrict__ flag,
                                const float* __restrict__ dinv, const int* __restrict__ rowptr,
                                int* __restrict__ cnt, int* __restrict__ col, float* __restrict__ wcsr) {
  int e = blockIdx.x * blockDim.x + threadIdx.x;
  if (e < N_EDGES) {
    int m = *flag;
    int s = load_edge(ei, m, e);
    int d = load_edge(ei, m, (long long)N_EDGES + e);
    int pos = rowptr[d] + atomicAdd(&cnt[d], 1);
    col[pos] = s;
    wcsr[pos] = -dinv[s] * dinv[d];
  }
}

// ---------------- weight transpose-convert: W[KF][Nd] fp32 -> Wt[Nd][KF] fp16 ----------------
__global__ __launch_bounds__(256) void wt_kernel(const float* __restrict__ W, u16* __restrict__ Wt,
                                                 int KF, int Nd) {
  __shared__ float sm[32][36];
  int kf0 = blockIdx.x * 32, n0 = blockIdx.y * 32;
  int r = threadIdx.x >> 3, c4 = (threadIdx.x & 7) * 4;
  float4 v = *(const float4*)(W + (size_t)(kf0 + r) * Nd + n0 + c4);
  sm[r][c4 + 0] = v.x; sm[r][c4 + 1] = v.y; sm[r][c4 + 2] = v.z; sm[r][c4 + 3] = v.w;
  __syncthreads();
  int on = threadIdx.x >> 3, okf4 = (threadIdx.x & 7) * 4;
  ushort4 u;
  u.x = f2h(sm[okf4 + 0][on]);
  u.y = f2h(sm[okf4 + 1][on]);
  u.z = f2h(sm[okf4 + 2][on]);
  u.w = f2h(sm[okf4 + 3][on]);
  *(ushort4*)(Wt + (size_t)(n0 + on) * KF + kf0 + okf4) = u;
}

// ---------------- convert h fp32 -> fp16 into cat slot 0 (T0) ----------------
template <int F>
__global__ void convert_cat_kernel(const float* __restrict__ in, u16* __restrict__ cat) {
  constexpr int F8 = F / 8;
  int i = blockIdx.x * blockDim.x + threadIdx.x;  // over N*F8
  int n = i / F8, f8 = i % F8;
  const float4* p = (const float4*)(in + (size_t)n * F + f8 * 8);
  float4 a = p[0], b = p[1];
  half8 o;
  o[0] = (_Float16)a.x; o[1] = (_Float16)a.y; o[2] = (_Float16)a.z; o[3] = (_Float16)a.w;
  o[4] = (_Float16)b.x; o[5] = (_Float16)b.y; o[6] = (_Float16)b.z; o[7] = (_Float16)b.w;
  *(half8*)(cat + (size_t)n * (5 * F) + f8 * 8) = o;
}

// ---------------- L_hat on cat slots: slot_out = scale * gather(slot_in) - slot_tx0 ----------------
template <int F, bool HAS_TX0>
__global__ void lhat3_kernel(u16* __restrict__ cat,
                             const int* __restrict__ rowptr, const int* __restrict__ col,
                             const float* __restrict__ w, float scale,
                             int inOff, int tx0Off, int outOff) {
  constexpr int L = F / 8;        // lanes per node (16B fp16 per lane)
  constexpr int NPB = 256 / L;    // nodes per block
  constexpr int R = 5 * F;        // cat row stride (halves)
  int node = blockIdx.x * NPB + threadIdx.x / L;
  int ln8 = (threadIdx.x % L) * 8;
  if (node >= N_NODES) return;
  int beg = rowptr[node], end = rowptr[node + 1];
  float a0[8] = {0.f, 0.f, 0.f, 0.f, 0.f, 0.f, 0.f, 0.f};
  float a1[8] = {0.f, 0.f, 0.f, 0.f, 0.f, 0.f, 0.f, 0.f};
  float a2[8] = {0.f, 0.f, 0.f, 0.f, 0.f, 0.f, 0.f, 0.f};
  float a3[8] = {0.f, 0.f, 0.f, 0.f, 0.f, 0.f, 0.f, 0.f};
  int e = beg;
  for (; e + 3 < end; e += 4) {
    int c0 = col[e], c1 = col[e + 1], c2 = col[e + 2], c3 = col[e + 3];
    float w0 = w[e], w1 = w[e + 1], w2 = w[e + 2], w3 = w[e + 3];
    half8 v0 = *(const half8*)(cat + (size_t)c0 * R + inOff + ln8);
    half8 v1 = *(const half8*)(cat + (size_t)c1 * R + inOff + ln8);
    half8 v2 = *(const half8*)(cat + (size_t)c2 * R + inOff + ln8);
    half8 v3 = *(const half8*)(cat + (size_t)c3 * R + inOff + ln8);
#pragma unroll
    for (int j = 0; j < 8; j++) {
      a0[j] += w0 * (float)v0[j];
      a1[j] += w1 * (float)v1[j];
      a2[j] += w2 * (float)v2[j];
      a3[j] += w3 * (float)v3[j];
    }
  }
  for (; e < end; e++) {
    int c0 = col[e];
    float w0 = w[e];
    half8 v0 = *(const half8*)(cat + (size_t)c0 * R + inOff + ln8);
#pragma unroll
    for (int j = 0; j < 8; j++) a0[j] += w0 * (float)v0[j];
  }
  float r[8];
#pragma unroll
  for (int j = 0; j < 8; j++) r[j] = scale * ((a0[j] + a1[j]) + (a2[j] + a3[j]));
  if (HAS_TX0) {
    half8 t = *(const half8*)(cat + (size_t)node * R + tx0Off + ln8);
#pragma unroll
    for (int j = 0; j < 8; j++) r[j] -= (float)t[j];
  }
  half8 o;
#pragma unroll
  for (int j = 0; j < 8; j++) o[j] = (_Float16)r[j];
  *(half8*)(cat + (size_t)node * R + outOff + ln8) = o;
}

// ---------------- f16 MFMA GEMM: C[M][ldC] (+)= A[M][ldA]f16(Kc cols) @ B[Nc][ldB]^T ----------------
// Tile 64(M) x 128(N) x 64(K); 4 waves, each 32x64 (Mrep=2, Nrep=4).
// Staging: global_load_lds w16, linear LDS dest, inverse-swizzled global src.
__global__ __launch_bounds__(256) void gemm_cat_kernel(
    const u16* __restrict__ A, int ldA, const u16* __restrict__ B, int ldB, int kBase,
    int Kc, float* __restrict__ C, int ldC, int Nc, const float* __restrict__ bias, int M,
    int accFlag, int reluFlag) {
  __shared__ __align__(16) u16 As[64 * 64];    // 8 KB
  __shared__ __align__(16) u16 Bs[128 * 64];   // 16 KB
  int tid = threadIdx.x;
  int lane = tid & 63, wave = tid >> 6;
  int wr = wave >> 1, wc = wave & 1;
  int l15 = lane & 15, l16 = lane >> 4;
  int m0 = blockIdx.x * 64, n0 = blockIdx.y * 128;
  floatx4 acc[2][4];
#pragma unroll
  for (int m = 0; m < 2; m++)
#pragma unroll
    for (int n = 0; n < 4; n++) acc[m][n] = (floatx4){0.f, 0.f, 0.f, 0.f};

  int subrow = lane >> 3;          // 0..7
  int bcol = (lane & 7) * 16;      // byte col within 128B row

  for (int k0 = 0; k0 < Kc; k0 += 64) {
    __syncthreads();  // previous iteration's ds_reads done before overwrite
#pragma unroll
    for (int i = 0; i < 6; i++) {
      int c = wave * 6 + i;        // 0..23 chunk id, 1KB each
      if (c < 8) {
        int row = c * 8 + subrow;
        const char* src = (const char*)A + ((size_t)(m0 + row) * ldA + k0) * 2 +
                          (bcol ^ ((row & 7) << 4));
        gld16(src, (char*)As + c * 1024);
      } else {
        int row = (c - 8) * 8 + subrow;
        const char* src = (const char*)B + ((size_t)(n0 + row) * ldB + kBase + k0) * 2 +
                          (bcol ^ ((row & 7) << 4));
        gld16(src, (char*)Bs + (c - 8) * 1024);
      }
    }
    __syncthreads();  // compiler drains vmcnt before barrier -> LDS valid
#pragma unroll
    for (int kk = 0; kk < 2; kk++) {
      int kb = kk * 64 + l16 * 16;  // byte offset of 16B chunk within row
      half8 a[2];
#pragma unroll
      for (int m = 0; m < 2; m++) {
        int r = wr * 32 + m * 16 + l15;
        a[m] = *(half8*)((char*)As + r * 128 + (kb ^ ((r & 7) << 4)));
      }
#pragma unroll
      for (int n = 0; n < 4; n++) {
        int r = wc * 64 + n * 16 + l15;
        half8 b = *(half8*)((char*)Bs + r * 128 + (kb ^ ((r & 7) << 4)));
        acc[0][n] = __builtin_amdgcn_mfma_f32_16x16x32_f16(a[0], b, acc[0][n], 0, 0, 0);
        acc[1][n] = __builtin_amdgcn_mfma_f32_16x16x32_f16(a[1], b, acc[1][n], 0, 0, 0);
      }
    }
  }
#pragma unroll
  for (int m = 0; m < 2; m++)
#pragma unroll
    for (int n = 0; n < 4; n++)
#pragma unroll
      for (int j = 0; j < 4; j++) {
        int row = m0 + wr * 32 + m * 16 + l16 * 4 + j;
        int colI = n0 + wc * 64 + n * 16 + l15;
        if (row < M && colI < Nc) {
          size_t idx = (size_t)row * ldC + colI;
          float v = acc[m][n][j];
          if (accFlag) v += C[idx];
          if (bias) v += bias[colI];
          if (reluFlag) v = fmaxf(v, 0.f);
          C[idx] = v;
        }
      }
}

// ---------------- BN: pass1 partials (vectorized), reduce, apply (+fp16 out) ----------------
template <int D>
__global__ __launch_bounds__(256) void bn_part_kernel(const float* __restrict__ h,
                                                      float* __restrict__ part, int rows) {
  constexpr int TPR = D / 4;       // threads per row
  constexpr int RPI = 256 / TPR;   // rows per block-iter
  __shared__ float4 ssum[256], ssq[256];
  int tid = threadIdx.x;
  int g = tid / TPR;
  int fr = tid % TPR;
  float4 s = {0.f, 0.f, 0.f, 0.f}, q = {0.f, 0.f, 0.f, 0.f};
  for (int r = blockIdx.x * RPI + g; r < rows; r += gridDim.x * RPI) {
    float4 v = *(const float4*)(h + (size_t)r * D + fr * 4);
    s.x += v.x; s.y += v.y; s.z += v.z; s.w += v.w;
    q.x += v.x * v.x; q.y += v.y * v.y; q.z += v.z * v.z; q.w += v.w * v.w;
  }
  ssum[tid] = s; ssq[tid] = q;
  __syncthreads();
  if (g == 0) {
#pragma unroll
    for (int gg = 1; gg < RPI; gg++) {
      float4 a = ssum[gg * TPR + fr], b = ssq[gg * TPR + fr];
      s.x += a.x; s.y += a.y; s.z += a.z; s.w += a.w;
      q.x += b.x; q.y += b.y; q.z += b.z; q.w += b.w;
    }
    *(float4*)(part + (size_t)blockIdx.x * (2 * D) + fr * 4) = s;
    *(float4*)(part + (size_t)blockIdx.x * (2 * D) + D + fr * 4) = q;
  }
}

__global__ void bn_reduce_kernel(const float* __restrict__ part, float* __restrict__ acc, int D) {
  int c = blockIdx.x;   // 0..2D-1
  int tid = threadIdx.x;  // 64
  float v = 0.f;
  for (int b = tid; b < BN_B; b += 64) v += part[(size_t)b * (2 * D) + c];
#pragma unroll
  for (int off = 32; off > 0; off >>= 1) v += __shfl_down(v, off);
  if (tid == 0) {
    if (c < D) acc[c] = v;
    else acc[256 + (c - D)] = v;
  }
}

template <int D>
__global__ void bn_apply_kernel(float* __restrict__ h, const float* __restrict__ acc,
                                const float* __restrict__ gam, const float* __restrict__ bet,
                                int rows, int relu, float invRows,
                                u16* __restrict__ dst16, int ld16) {
  constexpr int F4 = D / 4;
  int i = blockIdx.x * blockDim.x + threadIdx.x;
  if (i >= rows * F4) return;
  int row = i / F4;
  int fi = (i % F4) * 4;
  float4 s4 = *(const float4*)(acc + fi);
  float4 q4 = *(const float4*)(acc + 256 + fi);
  float4 g4 = *(const float4*)(gam + fi);
  float4 b4 = *(const float4*)(bet + fi);
  float4 v = *(float4*)(h + (size_t)row * D + fi);
  float4 res;
  {
    float m = s4.x * invRows, var = q4.x * invRows - m * m;
    res.x = (v.x - m) * rsqrtf(var + EPSBN) * g4.x + b4.x;
    m = s4.y * invRows; var = q4.y * invRows - m * m;
    res.y = (v.y - m) * rsqrtf(var + EPSBN) * g4.y + b4.y;
    m = s4.z * invRows; var = q4.z * invRows - m * m;
    res.z = (v.z - m) * rsqrtf(var + EPSBN) * g4.z + b4.z;
    m = s4.w * invRows; var = q4.w * invRows - m * m;
    res.w = (v.w - m) * rsqrtf(var + EPSBN) * g4.w + b4.w;
  }
  if (relu) {
    res.x = fmaxf(res.x, 0.f); res.y = fmaxf(res.y, 0.f);
    res.z = fmaxf(res.z, 0.f); res.w = fmaxf(res.w, 0.f);
  }
  *(float4*)(h + (size_t)row * D + fi) = res;
  if (dst16) {
    ushort4 u;
    u.x = f2h(res.x); u.y = f2h(res.y); u.z = f2h(res.z); u.w = f2h(res.w);
    *(ushort4*)(dst16 + (size_t)row * ld16 + fi) = u;
  }
}

__global__ void fc3_kernel(const float* __restrict__ h, const float* __restrict__ w,
                           const float* __restrict__ b, float* __restrict__ out) {
  int node = blockIdx.x * 4 + (threadIdx.x >> 6);
  int lane = threadIdx.x & 63;
  if (node >= N_NODES) return;
  float v = h[(size_t)node * DD3 + lane] * w[lane];
#pragma unroll
  for (int off = 32; off > 0; off >>= 1) v += __shfl_down(v, off);
  if (lane == 0) out[node] = v + b[0];
}

// ---------------- host ----------------
extern "C" void kernel_launch(void* const* d_in, const int* in_sizes, int n_in,
                              void* d_out, int out_size, void* d_ws, size_t ws_size,
                              hipStream_t stream) {
  const float* x = (const float*)d_in[0];
  const void* ei = d_in[1];
  const float* conv1_w = (const float*)d_in[2];
  const float* convs_w = (const float*)d_in[3];
  const float* convs_b = (const float*)d_in[4];
  const float* bn1_g = (const float*)d_in[5];
  const float* bn1_b = (const float*)d_in[6];
  const float* fc1_w = (const float*)d_in[7];
  const float* fc1_b = (const float*)d_in[8];
  const float* bn2_g = (const float*)d_in[9];
  const float* bn2_b = (const float*)d_in[10];
  const float* fc2_w = (const float*)d_in[11];
  const float* fc2_b = (const float*)d_in[12];
  const float* bn3_g = (const float*)d_in[13];
  const float* bn3_b = (const float*)d_in[14];
  const float* fc3_w = (const float*)d_in[15];
  const float* fc3_b = (const float*)d_in[16];
  float* out = (float*)d_out;

  char* ws = (char*)d_ws;
  size_t off = 0;
  auto alloc = [&](size_t bytes) -> void* {
    off = (off + 255) & ~(size_t)255;
    void* p = ws + off;
    off += bytes;
    return p;
  };
  float* bufA = (float*)alloc((size_t)N_NODES * DD1 * 4);
  float* bufB = (float*)alloc((size_t)N_NODES * DD1 * 4);
  float* f1buf = (float*)alloc((size_t)N_NODES * DD2 * 4);
  float* f2buf = (float*)alloc((size_t)N_NODES * DD3 * 4);
  u16* Tcat = (u16*)alloc((size_t)(N_NODES + 64) * 5 * DD1 * 2);  // 5 fp16 slots + pad rows
  u16* h16 = (u16*)alloc((size_t)(N_NODES + 64) * DD1 * 2);       // fc1 input fp16
  u16* h16b = (u16*)alloc((size_t)(N_NODES + 64) * DD2 * 2);      // fc2 input fp16
  u16* Wt = (u16*)alloc((size_t)(1280 * 256 + 3 * 2560 * 256) * 2);
  u16* Wtf1 = (u16*)alloc((size_t)DD2 * DD1 * 2);                 // [128][256]
  u16* Wtf2 = (u16*)alloc((size_t)128 * DD2 * 2);                 // [64 valid +pad][128]
  float* bnpart = (float*)alloc((size_t)BN_B * 2 * DD1 * 4);
  int* ideg = (int*)alloc(N_NODES * 4);
  int* rowptr = (int*)alloc((N_NODES + 1) * 4);
  int* cnt = (int*)alloc(N_NODES * 4);
  int* col = (int*)alloc(N_EDGES * 4);
  float* wcsr = (float*)alloc(N_EDGES * 4);
  float* dinv = (float*)alloc(N_NODES * 4);
  float* bnacc = (float*)alloc(512 * 4);
  int* flag = (int*)alloc(4);
  if (off > ws_size) return;

  // ---- one-time weight transpose to fp16 ----
  wt_kernel<<<dim3(1280 / 32, 8), 256, 0, stream>>>(conv1_w, Wt, 1280, 256);
  for (int l = 0; l < 3; l++)
    wt_kernel<<<dim3(2560 / 32, 8), 256, 0, stream>>>(convs_w + (size_t)l * 655360,
                                                      Wt + 327680 + (size_t)l * 655360, 2560, 256);
  wt_kernel<<<dim3(256 / 32, 128 / 32), 256, 0, stream>>>(fc1_w, Wtf1, 256, 128);
  wt_kernel<<<dim3(128 / 32, 64 / 32), 256, 0, stream>>>(fc2_w, Wtf2, 128, 64);

  // ---- graph structures ----
  hipMemsetAsync(ideg, 0, N_NODES * 4, stream);
  hipMemsetAsync(cnt, 0, N_NODES * 4, stream);
  detect_idx_kernel<<<1, 64, 0, stream>>>(ei, flag);
  deg_kernel<<<(N_EDGES + 255) / 256, 256, 0, stream>>>(ei, flag, ideg);
  dinv_kernel<<<(N_NODES + 255) / 256, 256, 0, stream>>>(ideg, dinv);
  scan_kernel<<<1, 1024, 0, stream>>>(ideg, rowptr);
  fill_csr_kernel<<<(N_EDGES + 255) / 256, 256, 0, stream>>>(ei, flag, dinv, rowptr, cnt, col, wcsr);

  auto lhat = [&](int F, float scale, int inS, int tx0S, int outS) {
    if (F == 128) {
      if (tx0S < 0)
        lhat3_kernel<128, false><<<1250, 256, 0, stream>>>(Tcat, rowptr, col, wcsr, scale,
                                                           inS * 128, 0, outS * 128);
      else
        lhat3_kernel<128, true><<<1250, 256, 0, stream>>>(Tcat, rowptr, col, wcsr, scale,
                                                          inS * 128, tx0S * 128, outS * 128);
    } else {
      if (tx0S < 0)
        lhat3_kernel<256, false><<<2500, 256, 0, stream>>>(Tcat, rowptr, col, wcsr, scale,
                                                           inS * 256, 0, outS * 256);
      else
        lhat3_kernel<256, true><<<2500, 256, 0, stream>>>(Tcat, rowptr, col, wcsr, scale,
                                                          inS * 256, tx0S * 256, outS * 256);
    }
  };
  auto gemm_cat = [&](int F, const u16* WtL, float* C, const float* bias, int chunk, int relu) {
    int Kc = 5 * F, KF = 10 * F;
    gemm_cat_kernel<<<dim3((N_NODES + 63) / 64, 2), 256, 0, stream>>>(
        Tcat, Kc, WtL, KF, chunk * Kc, Kc, C, 256, 256, bias, N_NODES, chunk, relu);
  };
  // per layer: T0..T4 in slots 0..4 -> GEMM chunk0; T5..T9 cycle slots 0..4 -> GEMM chunk1
  // (convert/bn_apply must have placed T0 into slot 0 beforehand)
  auto cheb = [&](int F, const u16* WtL, const float* bias, float* hout, int relu) {
    lhat(F, 1.f, 0, -1, 1);   // T1
    lhat(F, 2.f, 1, 0, 2);    // T2
    lhat(F, 2.f, 2, 1, 3);    // T3
    lhat(F, 2.f, 3, 2, 4);    // T4
    gemm_cat(F, WtL, hout, nullptr, 0, 0);
    lhat(F, 2.f, 4, 3, 0);    // T5
    lhat(F, 2.f, 0, 4, 1);    // T6
    lhat(F, 2.f, 1, 0, 2);    // T7
    lhat(F, 2.f, 2, 1, 3);    // T8
    lhat(F, 2.f, 3, 2, 4);    // T9
    gemm_cat(F, WtL, hout, bias, 1, relu);
  };
  auto bn = [&](float* h, int D, const float* g, const float* b, int relu, u16* dst16, int ld16) {
    if (D == 256) {
      bn_part_kernel<256><<<BN_B, 256, 0, stream>>>(h, bnpart, N_NODES);
      bn_reduce_kernel<<<2 * 256, 64, 0, stream>>>(bnpart, bnacc, 256);
      bn_apply_kernel<256><<<(N_NODES * 64 + 255) / 256, 256, 0, stream>>>(
          h, bnacc, g, b, N_NODES, relu, 1.f / N_NODES, dst16, ld16);
    } else if (D == 128) {
      bn_part_kernel<128><<<BN_B, 256, 0, stream>>>(h, bnpart, N_NODES);
      bn_reduce_kernel<<<2 * 128, 64, 0, stream>>>(bnpart, bnacc, 128);
      bn_apply_kernel<128><<<(N_NODES * 32 + 255) / 256, 256, 0, stream>>>(
          h, bnacc, g, b, N_NODES, relu, 1.f / N_NODES, dst16, ld16);
    } else {
      bn_part_kernel<64><<<BN_B, 256, 0, stream>>>(h, bnpart, N_NODES);
      bn_reduce_kernel<<<2 * 64, 64, 0, stream>>>(bnpart, bnacc, 64);
      bn_apply_kernel<64><<<(N_NODES * 16 + 255) / 256, 256, 0, stream>>>(
          h, bnacc, g, b, N_NODES, relu, 1.f / N_NODES, dst16, ld16);
    }
  };

  // ---- conv1: T0 = x (fp16 convert), cheb(128->256) + relu -> bufA ----
  convert_cat_kernel<128><<<1250, 256, 0, stream>>>(x, Tcat);
  cheb(FDIM_IN, Wt, nullptr, bufA, 1);

  // ---- conv2: T0 = conv1-out (convert), cheb(256->256)+bias+relu -> bufB, bn1 (writes slot0 for conv3)
  convert_cat_kernel<256><<<2500, 256, 0, stream>>>(bufA, Tcat);
  cheb(DD1, Wt + 327680, convs_b, bufB, 1);
  bn(bufB, DD1, bn1_g, bn1_b, 0, Tcat, 5 * DD1);

  // ---- conv3 ----
  cheb(DD1, Wt + 327680 + 655360, convs_b + DD1, bufA, 1);
  bn(bufA, DD1, bn1_g, bn1_b, 0, Tcat, 5 * DD1);

  // ---- conv4 (bn writes h16 for fc1) ----
  cheb(DD1, Wt + 327680 + 2 * 655360, convs_b + 2 * DD1, bufB, 1);
  bn(bufB, DD1, bn1_g, bn1_b, 0, h16, DD1);

  // ---- fc1 (256->128) + bias, bn2+relu (writes h16b for fc2) ----
  gemm_cat_kernel<<<dim3((N_NODES + 63) / 64, 1), 256, 0, stream>>>(
      h16, DD1, Wtf1, DD1, 0, DD1, f1buf, DD2, DD2, fc1_b, N_NODES, 0, 0);
  bn(f1buf, DD2, bn2_g, bn2_b, 1, h16b, DD2);

  // ---- fc2 (128->64) + bias, bn3 ----
  gemm_cat_kernel<<<dim3((N_NODES + 63) / 64, 1), 256, 0, stream>>>(
      h16b, DD2, Wtf2, DD2, 0, DD2, f2buf, DD3, DD3, fc2_b, N_NODES, 0, 0);
  bn(f2buf, DD3, bn3_g, bn3_b, 0, nullptr, 0);

  // ---- fc3 (64->1) ----
  fc3_kernel<<<(N_NODES + 3) / 4, 256, 0, stream>>>(f2buf, fc3_w, fc3_b, out);
}

// Round 7
// 1168.811 us; speedup vs baseline: 4.1233x; 1.0427x over previous
//
#include <hip/hip_runtime.h>
#include <hip/hip_bf16.h>
#include <stdint.h>

// ChebNet: fp16 Chebyshev T-storage in the concat GEMM buffer (gather CSR,
// fp32 accumulate), f16 MFMA GEMM everywhere (convs + fc head), two-pass BN.
// R7: gemm tile 64x128 -> 64x64 (2x blocks, latency hiding) + XCD-chunked
// swizzle so A-panel sibling blocks share one XCD L2. MFMA K-chain order
// unchanged -> absmax must stay bit-identical (0.0078125).

#define N_NODES 20000
#define N_EDGES 320000
#define FDIM_IN 128
#define DD1 256
#define DD2 128
#define DD3 64
#define K_CHEB 10
#define EPSBN 1e-5f
#define BN_B 512  // partial blocks for BN pass1

typedef unsigned short u16;
typedef unsigned int u32;
typedef _Float16 half8 __attribute__((ext_vector_type(8)));
typedef __attribute__((ext_vector_type(4))) float floatx4;

__device__ __forceinline__ u16 f2h(float v) {
  _Float16 h = (_Float16)v;
  return *reinterpret_cast<u16*>(&h);
}

__device__ __forceinline__ void gld16(const void* g, void* l) {
  __builtin_amdgcn_global_load_lds((const __attribute__((address_space(1))) u32*)g,
                                   (__attribute__((address_space(3))) u32*)l, 16, 0, 0);
}

// ---------------- graph setup ----------------
__global__ void detect_idx_kernel(const void* ei, int* flag) {
  int t = threadIdx.x;
  const int* p = (const int*)ei;
  int v = p[2 * t + 1];
  unsigned long long b = __ballot(v == 0);
  if (t == 0) *flag = (b == ~0ULL) ? 1 : 0;
}

__device__ __forceinline__ int load_edge(const void* ei, int mode64, long long pos) {
  return mode64 ? (int)((const long long*)ei)[pos] : ((const int*)ei)[pos];
}

__global__ void deg_kernel(const void* ei, const int* __restrict__ flag, int* __restrict__ ideg) {
  int e = blockIdx.x * blockDim.x + threadIdx.x;
  if (e < N_EDGES) {
    int d = load_edge(ei, *flag, (long long)N_EDGES + e);
    atomicAdd(&ideg[d], 1);
  }
}

__global__ void dinv_kernel(const int* __restrict__ ideg, float* __restrict__ dinv) {
  int n = blockIdx.x * blockDim.x + threadIdx.x;
  if (n < N_NODES) {
    int d = ideg[n];
    dinv[n] = d > 0 ? rsqrtf((float)d) : 0.f;
  }
}

__global__ __launch_bounds__(1024) void scan_kernel(const int* __restrict__ ideg, int* __restrict__ rowptr) {
  __shared__ int part[1024];
  int tid = threadIdx.x;
  const int CH = (N_NODES + 1023) / 1024;
  int base = tid * CH;
  int s = 0;
  for (int i = 0; i < CH; i++) { int idx = base + i; if (idx < N_NODES) s += ideg[idx]; }
  part[tid] = s;
  __syncthreads();
  for (int off = 1; off < 1024; off <<= 1) {
    int v = (tid >= off) ? part[tid - off] : 0;
    __syncthreads();
    part[tid] += v;
    __syncthreads();
  }
  int run = (tid == 0) ? 0 : part[tid - 1];
  for (int i = 0; i < CH; i++) { int idx = base + i; if (idx < N_NODES) { rowptr[idx] = run; run += ideg[idx]; } }
  if (tid == 1023) rowptr[N_NODES] = run;
}

__global__ void fill_csr_kernel(const void* ei, const int* __restrict__ flag,
                                const float* __restrict__ dinv, const int* __restrict__ rowptr,
                                int* __restrict__ cnt, int* __restrict__ col, float* __restrict__ wcsr) {
  int e = blockIdx.x * blockDim.x + threadIdx.x;
  if (e < N_EDGES) {
    int m = *flag;
    int s = load_edge(ei, m, e);
    int d = load_edge(ei, m, (long long)N_EDGES + e);
    int pos = rowptr[d] + atomicAdd(&cnt[d], 1);
    col[pos] = s;
    wcsr[pos] = -dinv[s] * dinv[d];
  }
}

// ---------------- weight transpose-convert: W[KF][Nd] fp32 -> Wt[Nd][KF] fp16 ----------------
__global__ __launch_bounds__(256) void wt_kernel(const float* __restrict__ W, u16* __restrict__ Wt,
                                                 int KF, int Nd) {
  __shared__ float sm[32][36];
  int kf0 = blockIdx.x * 32, n0 = blockIdx.y * 32;
  int r = threadIdx.x >> 3, c4 = (threadIdx.x & 7) * 4;
  float4 v = *(const float4*)(W + (size_t)(kf0 + r) * Nd + n0 + c4);
  sm[r][c4 + 0] = v.x; sm[r][c4 + 1] = v.y; sm[r][c4 + 2] = v.z; sm[r][c4 + 3] = v.w;
  __syncthreads();
  int on = threadIdx.x >> 3, okf4 = (threadIdx.x & 7) * 4;
  ushort4 u;
  u.x = f2h(sm[okf4 + 0][on]);
  u.y = f2h(sm[okf4 + 1][on]);
  u.z = f2h(sm[okf4 + 2][on]);
  u.w = f2h(sm[okf4 + 3][on]);
  *(ushort4*)(Wt + (size_t)(n0 + on) * KF + kf0 + okf4) = u;
}

// ---------------- convert h fp32 -> fp16 into cat slot 0 (T0) ----------------
template <int F>
__global__ void convert_cat_kernel(const float* __restrict__ in, u16* __restrict__ cat) {
  constexpr int F8 = F / 8;
  int i = blockIdx.x * blockDim.x + threadIdx.x;  // over N*F8
  int n = i / F8, f8 = i % F8;
  const float4* p = (const float4*)(in + (size_t)n * F + f8 * 8);
  float4 a = p[0], b = p[1];
  half8 o;
  o[0] = (_Float16)a.x; o[1] = (_Float16)a.y; o[2] = (_Float16)a.z; o[3] = (_Float16)a.w;
  o[4] = (_Float16)b.x; o[5] = (_Float16)b.y; o[6] = (_Float16)b.z; o[7] = (_Float16)b.w;
  *(half8*)(cat + (size_t)n * (5 * F) + f8 * 8) = o;
}

// ---------------- L_hat on cat slots: slot_out = scale * gather(slot_in) - slot_tx0 ----------------
template <int F, bool HAS_TX0>
__global__ void lhat3_kernel(u16* __restrict__ cat,
                             const int* __restrict__ rowptr, const int* __restrict__ col,
                             const float* __restrict__ w, float scale,
                             int inOff, int tx0Off, int outOff) {
  constexpr int L = F / 8;        // lanes per node (16B fp16 per lane)
  constexpr int NPB = 256 / L;    // nodes per block
  constexpr int R = 5 * F;        // cat row stride (halves)
  int node = blockIdx.x * NPB + threadIdx.x / L;
  int ln8 = (threadIdx.x % L) * 8;
  if (node >= N_NODES) return;
  int beg = rowptr[node], end = rowptr[node + 1];
  float a0[8] = {0.f, 0.f, 0.f, 0.f, 0.f, 0.f, 0.f, 0.f};
  float a1[8] = {0.f, 0.f, 0.f, 0.f, 0.f, 0.f, 0.f, 0.f};
  float a2[8] = {0.f, 0.f, 0.f, 0.f, 0.f, 0.f, 0.f, 0.f};
  float a3[8] = {0.f, 0.f, 0.f, 0.f, 0.f, 0.f, 0.f, 0.f};
  int e = beg;
  for (; e + 3 < end; e += 4) {
    int c0 = col[e], c1 = col[e + 1], c2 = col[e + 2], c3 = col[e + 3];
    float w0 = w[e], w1 = w[e + 1], w2 = w[e + 2], w3 = w[e + 3];
    half8 v0 = *(const half8*)(cat + (size_t)c0 * R + inOff + ln8);
    half8 v1 = *(const half8*)(cat + (size_t)c1 * R + inOff + ln8);
    half8 v2 = *(const half8*)(cat + (size_t)c2 * R + inOff + ln8);
    half8 v3 = *(const half8*)(cat + (size_t)c3 * R + inOff + ln8);
#pragma unroll
    for (int j = 0; j < 8; j++) {
      a0[j] += w0 * (float)v0[j];
      a1[j] += w1 * (float)v1[j];
      a2[j] += w2 * (float)v2[j];
      a3[j] += w3 * (float)v3[j];
    }
  }
  for (; e < end; e++) {
    int c0 = col[e];
    float w0 = w[e];
    half8 v0 = *(const half8*)(cat + (size_t)c0 * R + inOff + ln8);
#pragma unroll
    for (int j = 0; j < 8; j++) a0[j] += w0 * (float)v0[j];
  }
  float r[8];
#pragma unroll
  for (int j = 0; j < 8; j++) r[j] = scale * ((a0[j] + a1[j]) + (a2[j] + a3[j]));
  if (HAS_TX0) {
    half8 t = *(const half8*)(cat + (size_t)node * R + tx0Off + ln8);
#pragma unroll
    for (int j = 0; j < 8; j++) r[j] -= (float)t[j];
  }
  half8 o;
#pragma unroll
  for (int j = 0; j < 8; j++) o[j] = (_Float16)r[j];
  *(half8*)(cat + (size_t)node * R + outOff + ln8) = o;
}

// ---------------- f16 MFMA GEMM: C[M][ldC] (+)= A[M][ldA]f16(Kc cols) @ B[Nc][ldB]^T ----------------
// R7: tile 64(M) x 64(N) x 64(K); 4 waves (2x2), each 32x32. 1-D grid with
// XCD-chunked swizzle: phys = a*8*NY + y*8 + b, x = a*8+b -> NY siblings of an
// A panel land on one XCD. Staging: global_load_lds w16, linear LDS dest,
// inverse-swizzled global src; swizzled ds_read.
__global__ __launch_bounds__(256) void gemm_cat_kernel(
    const u16* __restrict__ A, int ldA, const u16* __restrict__ B, int ldB, int kBase,
    int Kc, float* __restrict__ C, int ldC, int Nc, const float* __restrict__ bias, int M,
    int NX, int NY, int accFlag, int reluFlag) {
  __shared__ __align__(16) u16 As[64 * 64];    // 8 KB
  __shared__ __align__(16) u16 Bs[64 * 64];    // 8 KB
  int pid = blockIdx.x;
  int g8 = 8 * NY;
  int a8 = pid / g8, rem = pid % g8;
  int by = rem >> 3;
  int bx = a8 * 8 + (rem & 7);
  if (bx >= NX) return;
  int tid = threadIdx.x;
  int lane = tid & 63, wave = tid >> 6;
  int wr = wave >> 1, wc = wave & 1;
  int l15 = lane & 15, l16 = lane >> 4;
  int m0 = bx * 64, n0 = by * 64;
  floatx4 acc[2][2];
#pragma unroll
  for (int m = 0; m < 2; m++)
#pragma unroll
    for (int n = 0; n < 2; n++) acc[m][n] = (floatx4){0.f, 0.f, 0.f, 0.f};

  int subrow = lane >> 3;          // 0..7
  int bcol = (lane & 7) * 16;      // byte col within 128B row

  for (int k0 = 0; k0 < Kc; k0 += 64) {
    __syncthreads();  // previous iteration's ds_reads done before overwrite
#pragma unroll
    for (int i = 0; i < 4; i++) {
      int c = wave * 4 + i;        // 0..15 chunk id, 1KB each
      if (c < 8) {
        int row = c * 8 + subrow;
        const char* src = (const char*)A + ((size_t)(m0 + row) * ldA + k0) * 2 +
                          (bcol ^ ((row & 7) << 4));
        gld16(src, (char*)As + c * 1024);
      } else {
        int row = (c - 8) * 8 + subrow;
        const char* src = (const char*)B + ((size_t)(n0 + row) * ldB + kBase + k0) * 2 +
                          (bcol ^ ((row & 7) << 4));
        gld16(src, (char*)Bs + (c - 8) * 1024);
      }
    }
    __syncthreads();  // compiler drains vmcnt before barrier -> LDS valid
#pragma unroll
    for (int kk = 0; kk < 2; kk++) {
      int kb = kk * 64 + l16 * 16;  // byte offset of 16B chunk within row
      half8 a[2];
#pragma unroll
      for (int m = 0; m < 2; m++) {
        int r = wr * 32 + m * 16 + l15;
        a[m] = *(half8*)((char*)As + r * 128 + (kb ^ ((r & 7) << 4)));
      }
#pragma unroll
      for (int n = 0; n < 2; n++) {
        int r = wc * 32 + n * 16 + l15;
        half8 b = *(half8*)((char*)Bs + r * 128 + (kb ^ ((r & 7) << 4)));
        acc[0][n] = __builtin_amdgcn_mfma_f32_16x16x32_f16(a[0], b, acc[0][n], 0, 0, 0);
        acc[1][n] = __builtin_amdgcn_mfma_f32_16x16x32_f16(a[1], b, acc[1][n], 0, 0, 0);
      }
    }
  }
#pragma unroll
  for (int m = 0; m < 2; m++)
#pragma unroll
    for (int n = 0; n < 2; n++)
#pragma unroll
      for (int j = 0; j < 4; j++) {
        int row = m0 + wr * 32 + m * 16 + l16 * 4 + j;
        int colI = n0 + wc * 32 + n * 16 + l15;
        if (row < M && colI < Nc) {
          size_t idx = (size_t)row * ldC + colI;
          float v = acc[m][n][j];
          if (accFlag) v += C[idx];
          if (bias) v += bias[colI];
          if (reluFlag) v = fmaxf(v, 0.f);
          C[idx] = v;
        }
      }
}

// ---------------- BN: pass1 partials (vectorized), reduce, apply (+fp16 out) ----------------
template <int D>
__global__ __launch_bounds__(256) void bn_part_kernel(const float* __restrict__ h,
                                                      float* __restrict__ part, int rows) {
  constexpr int TPR = D / 4;       // threads per row
  constexpr int RPI = 256 / TPR;   // rows per block-iter
  __shared__ float4 ssum[256], ssq[256];
  int tid = threadIdx.x;
  int g = tid / TPR;
  int fr = tid % TPR;
  float4 s = {0.f, 0.f, 0.f, 0.f}, q = {0.f, 0.f, 0.f, 0.f};
  for (int r = blockIdx.x * RPI + g; r < rows; r += gridDim.x * RPI) {
    float4 v = *(const float4*)(h + (size_t)r * D + fr * 4);
    s.x += v.x; s.y += v.y; s.z += v.z; s.w += v.w;
    q.x += v.x * v.x; q.y += v.y * v.y; q.z += v.z * v.z; q.w += v.w * v.w;
  }
  ssum[tid] = s; ssq[tid] = q;
  __syncthreads();
  if (g == 0) {
#pragma unroll
    for (int gg = 1; gg < RPI; gg++) {
      float4 a = ssum[gg * TPR + fr], b = ssq[gg * TPR + fr];
      s.x += a.x; s.y += a.y; s.z += a.z; s.w += a.w;
      q.x += b.x; q.y += b.y; q.z += b.z; q.w += b.w;
    }
    *(float4*)(part + (size_t)blockIdx.x * (2 * D) + fr * 4) = s;
    *(float4*)(part + (size_t)blockIdx.x * (2 * D) + D + fr * 4) = q;
  }
}

__global__ void bn_reduce_kernel(const float* __restrict__ part, float* __restrict__ acc, int D) {
  int c = blockIdx.x;   // 0..2D-1
  int tid = threadIdx.x;  // 64
  float v = 0.f;
  for (int b = tid; b < BN_B; b += 64) v += part[(size_t)b * (2 * D) + c];
#pragma unroll
  for (int off = 32; off > 0; off >>= 1) v += __shfl_down(v, off);
  if (tid == 0) {
    if (c < D) acc[c] = v;
    else acc[256 + (c - D)] = v;
  }
}

template <int D>
__global__ void bn_apply_kernel(float* __restrict__ h, const float* __restrict__ acc,
                                const float* __restrict__ gam, const float* __restrict__ bet,
                                int rows, int relu, float invRows,
                                u16* __restrict__ dst16, int ld16) {
  constexpr int F4 = D / 4;
  int i = blockIdx.x * blockDim.x + threadIdx.x;
  if (i >= rows * F4) return;
  int row = i / F4;
  int fi = (i % F4) * 4;
  float4 s4 = *(const float4*)(acc + fi);
  float4 q4 = *(const float4*)(acc + 256 + fi);
  float4 g4 = *(const float4*)(gam + fi);
  float4 b4 = *(const float4*)(bet + fi);
  float4 v = *(float4*)(h + (size_t)row * D + fi);
  float4 res;
  {
    float m = s4.x * invRows, var = q4.x * invRows - m * m;
    res.x = (v.x - m) * rsqrtf(var + EPSBN) * g4.x + b4.x;
    m = s4.y * invRows; var = q4.y * invRows - m * m;
    res.y = (v.y - m) * rsqrtf(var + EPSBN) * g4.y + b4.y;
    m = s4.z * invRows; var = q4.z * invRows - m * m;
    res.z = (v.z - m) * rsqrtf(var + EPSBN) * g4.z + b4.z;
    m = s4.w * invRows; var = q4.w * invRows - m * m;
    res.w = (v.w - m) * rsqrtf(var + EPSBN) * g4.w + b4.w;
  }
  if (relu) {
    res.x = fmaxf(res.x, 0.f); res.y = fmaxf(res.y, 0.f);
    res.z = fmaxf(res.z, 0.f); res.w = fmaxf(res.w, 0.f);
  }
  *(float4*)(h + (size_t)row * D + fi) = res;
  if (dst16) {
    ushort4 u;
    u.x = f2h(res.x); u.y = f2h(res.y); u.z = f2h(res.z); u.w = f2h(res.w);
    *(ushort4*)(dst16 + (size_t)row * ld16 + fi) = u;
  }
}

__global__ void fc3_kernel(const float* __restrict__ h, const float* __restrict__ w,
                           const float* __restrict__ b, float* __restrict__ out) {
  int node = blockIdx.x * 4 + (threadIdx.x >> 6);
  int lane = threadIdx.x & 63;
  if (node >= N_NODES) return;
  float v = h[(size_t)node * DD3 + lane] * w[lane];
#pragma unroll
  for (int off = 32; off > 0; off >>= 1) v += __shfl_down(v, off);
  if (lane == 0) out[node] = v + b[0];
}

// ---------------- host ----------------
extern "C" void kernel_launch(void* const* d_in, const int* in_sizes, int n_in,
                              void* d_out, int out_size, void* d_ws, size_t ws_size,
                              hipStream_t stream) {
  const float* x = (const float*)d_in[0];
  const void* ei = d_in[1];
  const float* conv1_w = (const float*)d_in[2];
  const float* convs_w = (const float*)d_in[3];
  const float* convs_b = (const float*)d_in[4];
  const float* bn1_g = (const float*)d_in[5];
  const float* bn1_b = (const float*)d_in[6];
  const float* fc1_w = (const float*)d_in[7];
  const float* fc1_b = (const float*)d_in[8];
  const float* bn2_g = (const float*)d_in[9];
  const float* bn2_b = (const float*)d_in[10];
  const float* fc2_w = (const float*)d_in[11];
  const float* fc2_b = (const float*)d_in[12];
  const float* bn3_g = (const float*)d_in[13];
  const float* bn3_b = (const float*)d_in[14];
  const float* fc3_w = (const float*)d_in[15];
  const float* fc3_b = (const float*)d_in[16];
  float* out = (float*)d_out;

  char* ws = (char*)d_ws;
  size_t off = 0;
  auto alloc = [&](size_t bytes) -> void* {
    off = (off + 255) & ~(size_t)255;
    void* p = ws + off;
    off += bytes;
    return p;
  };
  float* bufA = (float*)alloc((size_t)N_NODES * DD1 * 4);
  float* bufB = (float*)alloc((size_t)N_NODES * DD1 * 4);
  float* f1buf = (float*)alloc((size_t)N_NODES * DD2 * 4);
  float* f2buf = (float*)alloc((size_t)N_NODES * DD3 * 4);
  u16* Tcat = (u16*)alloc((size_t)(N_NODES + 64) * 5 * DD1 * 2);  // 5 fp16 slots + pad rows
  u16* h16 = (u16*)alloc((size_t)(N_NODES + 64) * DD1 * 2);       // fc1 input fp16
  u16* h16b = (u16*)alloc((size_t)(N_NODES + 64) * DD2 * 2);      // fc2 input fp16
  u16* Wt = (u16*)alloc((size_t)(1280 * 256 + 3 * 2560 * 256) * 2);
  u16* Wtf1 = (u16*)alloc((size_t)DD2 * DD1 * 2);                 // [128][256]
  u16* Wtf2 = (u16*)alloc((size_t)128 * DD2 * 2);                 // [64 valid +pad][128]
  float* bnpart = (float*)alloc((size_t)BN_B * 2 * DD1 * 4);
  int* ideg = (int*)alloc(N_NODES * 4);
  int* rowptr = (int*)alloc((N_NODES + 1) * 4);
  int* cnt = (int*)alloc(N_NODES * 4);
  int* col = (int*)alloc(N_EDGES * 4);
  float* wcsr = (float*)alloc(N_EDGES * 4);
  float* dinv = (float*)alloc(N_NODES * 4);
  float* bnacc = (float*)alloc(512 * 4);
  int* flag = (int*)alloc(4);
  if (off > ws_size) return;

  // ---- one-time weight transpose to fp16 ----
  wt_kernel<<<dim3(1280 / 32, 8), 256, 0, stream>>>(conv1_w, Wt, 1280, 256);
  for (int l = 0; l < 3; l++)
    wt_kernel<<<dim3(2560 / 32, 8), 256, 0, stream>>>(convs_w + (size_t)l * 655360,
                                                      Wt + 327680 + (size_t)l * 655360, 2560, 256);
  wt_kernel<<<dim3(256 / 32, 128 / 32), 256, 0, stream>>>(fc1_w, Wtf1, 256, 128);
  wt_kernel<<<dim3(128 / 32, 64 / 32), 256, 0, stream>>>(fc2_w, Wtf2, 128, 64);

  // ---- graph structures ----
  hipMemsetAsync(ideg, 0, N_NODES * 4, stream);
  hipMemsetAsync(cnt, 0, N_NODES * 4, stream);
  detect_idx_kernel<<<1, 64, 0, stream>>>(ei, flag);
  deg_kernel<<<(N_EDGES + 255) / 256, 256, 0, stream>>>(ei, flag, ideg);
  dinv_kernel<<<(N_NODES + 255) / 256, 256, 0, stream>>>(ideg, dinv);
  scan_kernel<<<1, 1024, 0, stream>>>(ideg, rowptr);
  fill_csr_kernel<<<(N_EDGES + 255) / 256, 256, 0, stream>>>(ei, flag, dinv, rowptr, cnt, col, wcsr);

  auto lhat = [&](int F, float scale, int inS, int tx0S, int outS) {
    if (F == 128) {
      if (tx0S < 0)
        lhat3_kernel<128, false><<<1250, 256, 0, stream>>>(Tcat, rowptr, col, wcsr, scale,
                                                           inS * 128, 0, outS * 128);
      else
        lhat3_kernel<128, true><<<1250, 256, 0, stream>>>(Tcat, rowptr, col, wcsr, scale,
                                                          inS * 128, tx0S * 128, outS * 128);
    } else {
      if (tx0S < 0)
        lhat3_kernel<256, false><<<2500, 256, 0, stream>>>(Tcat, rowptr, col, wcsr, scale,
                                                           inS * 256, 0, outS * 256);
      else
        lhat3_kernel<256, true><<<2500, 256, 0, stream>>>(Tcat, rowptr, col, wcsr, scale,
                                                          inS * 256, tx0S * 256, outS * 256);
    }
  };
  // generalized f16 MFMA gemm launch (XCD-chunked 1-D grid)
  auto mgemm = [&](const u16* A, int ldA, const u16* B, int ldB, int kBase, int Kc,
                   float* C, int ldC, int Nc, const float* bias, int accFlag, int relu) {
    int NX = (N_NODES + 63) / 64;        // 313
    int NXP = (NX + 7) & ~7;             // 320
    int NY = (Nc + 63) / 64;
    gemm_cat_kernel<<<dim3(NXP * NY), 256, 0, stream>>>(A, ldA, B, ldB, kBase, Kc, C, ldC, Nc,
                                                        bias, N_NODES, NX, NY, accFlag, relu);
  };
  auto gemm_cat = [&](int F, const u16* WtL, float* C, const float* bias, int chunk, int relu) {
    int Kc = 5 * F, KF = 10 * F;
    mgemm(Tcat, Kc, WtL, KF, chunk * Kc, Kc, C, 256, 256, bias, chunk, relu);
  };
  // per layer: T0..T4 in slots 0..4 -> GEMM chunk0; T5..T9 cycle slots 0..4 -> GEMM chunk1
  auto cheb = [&](int F, const u16* WtL, const float* bias, float* hout, int relu) {
    lhat(F, 1.f, 0, -1, 1);   // T1
    lhat(F, 2.f, 1, 0, 2);    // T2
    lhat(F, 2.f, 2, 1, 3);    // T3
    lhat(F, 2.f, 3, 2, 4);    // T4
    gemm_cat(F, WtL, hout, nullptr, 0, 0);
    lhat(F, 2.f, 4, 3, 0);    // T5
    lhat(F, 2.f, 0, 4, 1);    // T6
    lhat(F, 2.f, 1, 0, 2);    // T7
    lhat(F, 2.f, 2, 1, 3);    // T8
    lhat(F, 2.f, 3, 2, 4);    // T9
    gemm_cat(F, WtL, hout, bias, 1, relu);
  };
  auto bn = [&](float* h, int D, const float* g, const float* b, int relu, u16* dst16, int ld16) {
    if (D == 256) {
      bn_part_kernel<256><<<BN_B, 256, 0, stream>>>(h, bnpart, N_NODES);
      bn_reduce_kernel<<<2 * 256, 64, 0, stream>>>(bnpart, bnacc, 256);
      bn_apply_kernel<256><<<(N_NODES * 64 + 255) / 256, 256, 0, stream>>>(
          h, bnacc, g, b, N_NODES, relu, 1.f / N_NODES, dst16, ld16);
    } else if (D == 128) {
      bn_part_kernel<128><<<BN_B, 256, 0, stream>>>(h, bnpart, N_NODES);
      bn_reduce_kernel<<<2 * 128, 64, 0, stream>>>(bnpart, bnacc, 128);
      bn_apply_kernel<128><<<(N_NODES * 32 + 255) / 256, 256, 0, stream>>>(
          h, bnacc, g, b, N_NODES, relu, 1.f / N_NODES, dst16, ld16);
    } else {
      bn_part_kernel<64><<<BN_B, 256, 0, stream>>>(h, bnpart, N_NODES);
      bn_reduce_kernel<<<2 * 64, 64, 0, stream>>>(bnpart, bnacc, 64);
      bn_apply_kernel<64><<<(N_NODES * 16 + 255) / 256, 256, 0, stream>>>(
          h, bnacc, g, b, N_NODES, relu, 1.f / N_NODES, dst16, ld16);
    }
  };

  // ---- conv1: T0 = x (fp16 convert), cheb(128->256) + relu -> bufA ----
  convert_cat_kernel<128><<<1250, 256, 0, stream>>>(x, Tcat);
  cheb(FDIM_IN, Wt, nullptr, bufA, 1);

  // ---- conv2: T0 = conv1-out (convert), cheb(256->256)+bias+relu -> bufB, bn1 (writes slot0 for conv3)
  convert_cat_kernel<256><<<2500, 256, 0, stream>>>(bufA, Tcat);
  cheb(DD1, Wt + 327680, convs_b, bufB, 1);
  bn(bufB, DD1, bn1_g, bn1_b, 0, Tcat, 5 * DD1);

  // ---- conv3 ----
  cheb(DD1, Wt + 327680 + 655360, convs_b + DD1, bufA, 1);
  bn(bufA, DD1, bn1_g, bn1_b, 0, Tcat, 5 * DD1);

  // ---- conv4 (bn writes h16 for fc1) ----
  cheb(DD1, Wt + 327680 + 2 * 655360, convs_b + 2 * DD1, bufB, 1);
  bn(bufB, DD1, bn1_g, bn1_b, 0, h16, DD1);

  // ---- fc1 (256->128) + bias, bn2+relu (writes h16b for fc2) ----
  mgemm(h16, DD1, Wtf1, DD1, 0, DD1, f1buf, DD2, DD2, fc1_b, 0, 0);
  bn(f1buf, DD2, bn2_g, bn2_b, 1, h16b, DD2);

  // ---- fc2 (128->64) + bias, bn3 ----
  mgemm(h16b, DD2, Wtf2, DD2, 0, DD2, f2buf, DD3, DD3, fc2_b, 0, 0);
  bn(f2buf, DD3, bn3_g, bn3_b, 0, nullptr, 0);

  // ---- fc3 (64->1) ----
  fc3_kernel<<<(N_NODES + 3) / 4, 256, 0, stream>>>(f2buf, fc3_w, fc3_b, out);
}

// Round 8
// 1164.160 us; speedup vs baseline: 4.1398x; 1.0040x over previous
//
#include <hip/hip_runtime.h>
#include <hip/hip_bf16.h>
#include <stdint.h>

// ChebNet: fp16 Chebyshev T-storage, 10-slot flat concat buffer (103 MB ws,
// confirmed ws>=256MB), gather CSR with 8-deep load batching, single full-K
// f16 MFMA GEMM per conv layer, two-pass BN, fp16 MFMA head.
// R8: lhat 8-edge load batching (2x loads in flight); full-K GEMM (no C RMW).

#define N_NODES 20000
#define N_EDGES 320000
#define FDIM_IN 128
#define DD1 256
#define DD2 128
#define DD3 64
#define K_CHEB 10
#define EPSBN 1e-5f
#define BN_B 512  // partial blocks for BN pass1

typedef unsigned short u16;
typedef unsigned int u32;
typedef _Float16 half8 __attribute__((ext_vector_type(8)));
typedef __attribute__((ext_vector_type(4))) float floatx4;

__device__ __forceinline__ u16 f2h(float v) {
  _Float16 h = (_Float16)v;
  return *reinterpret_cast<u16*>(&h);
}

__device__ __forceinline__ void gld16(const void* g, void* l) {
  __builtin_amdgcn_global_load_lds((const __attribute__((address_space(1))) u32*)g,
                                   (__attribute__((address_space(3))) u32*)l, 16, 0, 0);
}

// ---------------- graph setup ----------------
__global__ void detect_idx_kernel(const void* ei, int* flag) {
  int t = threadIdx.x;
  const int* p = (const int*)ei;
  int v = p[2 * t + 1];
  unsigned long long b = __ballot(v == 0);
  if (t == 0) *flag = (b == ~0ULL) ? 1 : 0;
}

__device__ __forceinline__ int load_edge(const void* ei, int mode64, long long pos) {
  return mode64 ? (int)((const long long*)ei)[pos] : ((const int*)ei)[pos];
}

__global__ void deg_kernel(const void* ei, const int* __restrict__ flag, int* __restrict__ ideg) {
  int e = blockIdx.x * blockDim.x + threadIdx.x;
  if (e < N_EDGES) {
    int d = load_edge(ei, *flag, (long long)N_EDGES + e);
    atomicAdd(&ideg[d], 1);
  }
}

__global__ void dinv_kernel(const int* __restrict__ ideg, float* __restrict__ dinv) {
  int n = blockIdx.x * blockDim.x + threadIdx.x;
  if (n < N_NODES) {
    int d = ideg[n];
    dinv[n] = d > 0 ? rsqrtf((float)d) : 0.f;
  }
}

__global__ __launch_bounds__(1024) void scan_kernel(const int* __restrict__ ideg, int* __restrict__ rowptr) {
  __shared__ int part[1024];
  int tid = threadIdx.x;
  const int CH = (N_NODES + 1023) / 1024;
  int base = tid * CH;
  int s = 0;
  for (int i = 0; i < CH; i++) { int idx = base + i; if (idx < N_NODES) s += ideg[idx]; }
  part[tid] = s;
  __syncthreads();
  for (int off = 1; off < 1024; off <<= 1) {
    int v = (tid >= off) ? part[tid - off] : 0;
    __syncthreads();
    part[tid] += v;
    __syncthreads();
  }
  int run = (tid == 0) ? 0 : part[tid - 1];
  for (int i = 0; i < CH; i++) { int idx = base + i; if (idx < N_NODES) { rowptr[idx] = run; run += ideg[idx]; } }
  if (tid == 1023) rowptr[N_NODES] = run;
}

__global__ void fill_csr_kernel(const void* ei, const int* __restrict__ flag,
                                const float* __restrict__ dinv, const int* __restrict__ rowptr,
                                int* __restrict__ cnt, int* __restrict__ col, float* __restrict__ wcsr) {
  int e = blockIdx.x * blockDim.x + threadIdx.x;
  if (e < N_EDGES) {
    int m = *flag;
    int s = load_edge(ei, m, e);
    int d = load_edge(ei, m, (long long)N_EDGES + e);
    int pos = rowptr[d] + atomicAdd(&cnt[d], 1);
    col[pos] = s;
    wcsr[pos] = -dinv[s] * dinv[d];
  }
}

// ---------------- weight transpose-convert: W[KF][Nd] fp32 -> Wt[Nd][KF] fp16 ----------------
__global__ __launch_bounds__(256) void wt_kernel(const float* __restrict__ W, u16* __restrict__ Wt,
                                                 int KF, int Nd) {
  __shared__ float sm[32][36];
  int kf0 = blockIdx.x * 32, n0 = blockIdx.y * 32;
  int r = threadIdx.x >> 3, c4 = (threadIdx.x & 7) * 4;
  float4 v = *(const float4*)(W + (size_t)(kf0 + r) * Nd + n0 + c4);
  sm[r][c4 + 0] = v.x; sm[r][c4 + 1] = v.y; sm[r][c4 + 2] = v.z; sm[r][c4 + 3] = v.w;
  __syncthreads();
  int on = threadIdx.x >> 3, okf4 = (threadIdx.x & 7) * 4;
  ushort4 u;
  u.x = f2h(sm[okf4 + 0][on]);
  u.y = f2h(sm[okf4 + 1][on]);
  u.z = f2h(sm[okf4 + 2][on]);
  u.w = f2h(sm[okf4 + 3][on]);
  *(ushort4*)(Wt + (size_t)(n0 + on) * KF + kf0 + okf4) = u;
}

// ---------------- convert h fp32 -> fp16 into cat slot 0 (T0); row stride 10F ----------------
template <int F>
__global__ void convert_cat_kernel(const float* __restrict__ in, u16* __restrict__ cat) {
  constexpr int F8 = F / 8;
  int i = blockIdx.x * blockDim.x + threadIdx.x;  // over N*F8
  int n = i / F8, f8 = i % F8;
  const float4* p = (const float4*)(in + (size_t)n * F + f8 * 8);
  float4 a = p[0], b = p[1];
  half8 o;
  o[0] = (_Float16)a.x; o[1] = (_Float16)a.y; o[2] = (_Float16)a.z; o[3] = (_Float16)a.w;
  o[4] = (_Float16)b.x; o[5] = (_Float16)b.y; o[6] = (_Float16)b.z; o[7] = (_Float16)b.w;
  *(half8*)(cat + (size_t)n * (10 * F) + f8 * 8) = o;
}

// ---------------- L_hat on cat slots: slot_out = scale * gather(slot_in) - slot_tx0 ----------------
// 8-edge batched loads (8 gathers in flight per wave), then FMA block.
template <int F, bool HAS_TX0>
__global__ void lhat4_kernel(u16* __restrict__ cat,
                             const int* __restrict__ rowptr, const int* __restrict__ col,
                             const float* __restrict__ w, float scale,
                             int inOff, int tx0Off, int outOff) {
  constexpr int L = F / 8;        // lanes per node (16B fp16 per lane)
  constexpr int NPB = 256 / L;    // nodes per block
  constexpr int R = 10 * F;       // cat row stride (halves)
  int node = blockIdx.x * NPB + threadIdx.x / L;
  int ln8 = (threadIdx.x % L) * 8;
  if (node >= N_NODES) return;
  int beg = rowptr[node], end = rowptr[node + 1];
  float acc[8] = {0.f, 0.f, 0.f, 0.f, 0.f, 0.f, 0.f, 0.f};
  int e = beg;
  for (; e + 7 < end; e += 8) {
    int c[8];
    float wv[8];
#pragma unroll
    for (int j = 0; j < 8; j++) { c[j] = col[e + j]; wv[j] = w[e + j]; }
    half8 v[8];
#pragma unroll
    for (int j = 0; j < 8; j++) v[j] = *(const half8*)(cat + (size_t)c[j] * R + inOff + ln8);
#pragma unroll
    for (int j = 0; j < 8; j++)
#pragma unroll
      for (int i = 0; i < 8; i++) acc[i] += wv[j] * (float)v[j][i];
  }
  if (e + 3 < end) {
    int c[4];
    float wv[4];
#pragma unroll
    for (int j = 0; j < 4; j++) { c[j] = col[e + j]; wv[j] = w[e + j]; }
    half8 v[4];
#pragma unroll
    for (int j = 0; j < 4; j++) v[j] = *(const half8*)(cat + (size_t)c[j] * R + inOff + ln8);
#pragma unroll
    for (int j = 0; j < 4; j++)
#pragma unroll
      for (int i = 0; i < 8; i++) acc[i] += wv[j] * (float)v[j][i];
    e += 4;
  }
  for (; e < end; e++) {
    int c0 = col[e];
    float w0 = w[e];
    half8 v0 = *(const half8*)(cat + (size_t)c0 * R + inOff + ln8);
#pragma unroll
    for (int i = 0; i < 8; i++) acc[i] += w0 * (float)v0[i];
  }
  float r[8];
#pragma unroll
  for (int i = 0; i < 8; i++) r[i] = scale * acc[i];
  if (HAS_TX0) {
    half8 t = *(const half8*)(cat + (size_t)node * R + tx0Off + ln8);
#pragma unroll
    for (int i = 0; i < 8; i++) r[i] -= (float)t[i];
  }
  half8 o;
#pragma unroll
  for (int i = 0; i < 8; i++) o[i] = (_Float16)r[i];
  *(half8*)(cat + (size_t)node * R + outOff + ln8) = o;
}

// ---------------- f16 MFMA GEMM: C[M][ldC] = A[M][ldA]f16(Kc cols) @ B[Nc][ldB]^T ----------------
// Tile 64(M) x 64(N) x 64(K); 4 waves (2x2), each 32x32. 1-D grid with
// XCD-chunked swizzle. Staging: global_load_lds w16, linear LDS dest,
// inverse-swizzled global src; swizzled ds_read.
__global__ __launch_bounds__(256) void gemm_cat_kernel(
    const u16* __restrict__ A, int ldA, const u16* __restrict__ B, int ldB, int kBase,
    int Kc, float* __restrict__ C, int ldC, int Nc, const float* __restrict__ bias, int M,
    int NX, int NY, int accFlag, int reluFlag) {
  __shared__ __align__(16) u16 As[64 * 64];    // 8 KB
  __shared__ __align__(16) u16 Bs[64 * 64];    // 8 KB
  int pid = blockIdx.x;
  int g8 = 8 * NY;
  int a8 = pid / g8, rem = pid % g8;
  int by = rem >> 3;
  int bx = a8 * 8 + (rem & 7);
  if (bx >= NX) return;
  int tid = threadIdx.x;
  int lane = tid & 63, wave = tid >> 6;
  int wr = wave >> 1, wc = wave & 1;
  int l15 = lane & 15, l16 = lane >> 4;
  int m0 = bx * 64, n0 = by * 64;
  floatx4 acc[2][2];
#pragma unroll
  for (int m = 0; m < 2; m++)
#pragma unroll
    for (int n = 0; n < 2; n++) acc[m][n] = (floatx4){0.f, 0.f, 0.f, 0.f};

  int subrow = lane >> 3;          // 0..7
  int bcol = (lane & 7) * 16;      // byte col within 128B row

  for (int k0 = 0; k0 < Kc; k0 += 64) {
    __syncthreads();  // previous iteration's ds_reads done before overwrite
#pragma unroll
    for (int i = 0; i < 4; i++) {
      int c = wave * 4 + i;        // 0..15 chunk id, 1KB each
      if (c < 8) {
        int row = c * 8 + subrow;
        const char* src = (const char*)A + ((size_t)(m0 + row) * ldA + kBase + k0) * 2 +
                          (bcol ^ ((row & 7) << 4));
        gld16(src, (char*)As + c * 1024);
      } else {
        int row = (c - 8) * 8 + subrow;
        const char* src = (const char*)B + ((size_t)(n0 + row) * ldB + kBase + k0) * 2 +
                          (bcol ^ ((row & 7) << 4));
        gld16(src, (char*)Bs + (c - 8) * 1024);
      }
    }
    __syncthreads();  // compiler drains vmcnt before barrier -> LDS valid
#pragma unroll
    for (int kk = 0; kk < 2; kk++) {
      int kb = kk * 64 + l16 * 16;  // byte offset of 16B chunk within row
      half8 a[2];
#pragma unroll
      for (int m = 0; m < 2; m++) {
        int r = wr * 32 + m * 16 + l15;
        a[m] = *(half8*)((char*)As + r * 128 + (kb ^ ((r & 7) << 4)));
      }
#pragma unroll
      for (int n = 0; n < 2; n++) {
        int r = wc * 32 + n * 16 + l15;
        half8 b = *(half8*)((char*)Bs + r * 128 + (kb ^ ((r & 7) << 4)));
        acc[0][n] = __builtin_amdgcn_mfma_f32_16x16x32_f16(a[0], b, acc[0][n], 0, 0, 0);
        acc[1][n] = __builtin_amdgcn_mfma_f32_16x16x32_f16(a[1], b, acc[1][n], 0, 0, 0);
      }
    }
  }
#pragma unroll
  for (int m = 0; m < 2; m++)
#pragma unroll
    for (int n = 0; n < 2; n++)
#pragma unroll
      for (int j = 0; j < 4; j++) {
        int row = m0 + wr * 32 + m * 16 + l16 * 4 + j;
        int colI = n0 + wc * 32 + n * 16 + l15;
        if (row < M && colI < Nc) {
          size_t idx = (size_t)row * ldC + colI;
          float v = acc[m][n][j];
          if (accFlag) v += C[idx];
          if (bias) v += bias[colI];
          if (reluFlag) v = fmaxf(v, 0.f);
          C[idx] = v;
        }
      }
}

// ---------------- BN: pass1 partials (vectorized), reduce, apply (+fp16 out) ----------------
template <int D>
__global__ __launch_bounds__(256) void bn_part_kernel(const float* __restrict__ h,
                                                      float* __restrict__ part, int rows) {
  constexpr int TPR = D / 4;       // threads per row
  constexpr int RPI = 256 / TPR;   // rows per block-iter
  __shared__ float4 ssum[256], ssq[256];
  int tid = threadIdx.x;
  int g = tid / TPR;
  int fr = tid % TPR;
  float4 s = {0.f, 0.f, 0.f, 0.f}, q = {0.f, 0.f, 0.f, 0.f};
  for (int r = blockIdx.x * RPI + g; r < rows; r += gridDim.x * RPI) {
    float4 v = *(const float4*)(h + (size_t)r * D + fr * 4);
    s.x += v.x; s.y += v.y; s.z += v.z; s.w += v.w;
    q.x += v.x * v.x; q.y += v.y * v.y; q.z += v.z * v.z; q.w += v.w * v.w;
  }
  ssum[tid] = s; ssq[tid] = q;
  __syncthreads();
  if (g == 0) {
#pragma unroll
    for (int gg = 1; gg < RPI; gg++) {
      float4 a = ssum[gg * TPR + fr], b = ssq[gg * TPR + fr];
      s.x += a.x; s.y += a.y; s.z += a.z; s.w += a.w;
      q.x += b.x; q.y += b.y; q.z += b.z; q.w += b.w;
    }
    *(float4*)(part + (size_t)blockIdx.x * (2 * D) + fr * 4) = s;
    *(float4*)(part + (size_t)blockIdx.x * (2 * D) + D + fr * 4) = q;
  }
}

__global__ void bn_reduce_kernel(const float* __restrict__ part, float* __restrict__ acc, int D) {
  int c = blockIdx.x;   // 0..2D-1
  int tid = threadIdx.x;  // 64
  float v = 0.f;
  for (int b = tid; b < BN_B; b += 64) v += part[(size_t)b * (2 * D) + c];
#pragma unroll
  for (int off = 32; off > 0; off >>= 1) v += __shfl_down(v, off);
  if (tid == 0) {
    if (c < D) acc[c] = v;
    else acc[256 + (c - D)] = v;
  }
}

template <int D>
__global__ void bn_apply_kernel(float* __restrict__ h, const float* __restrict__ acc,
                                const float* __restrict__ gam, const float* __restrict__ bet,
                                int rows, int relu, float invRows,
                                u16* __restrict__ dst16, int ld16) {
  constexpr int F4 = D / 4;
  int i = blockIdx.x * blockDim.x + threadIdx.x;
  if (i >= rows * F4) return;
  int row = i / F4;
  int fi = (i % F4) * 4;
  float4 s4 = *(const float4*)(acc + fi);
  float4 q4 = *(const float4*)(acc + 256 + fi);
  float4 g4 = *(const float4*)(gam + fi);
  float4 b4 = *(const float4*)(bet + fi);
  float4 v = *(float4*)(h + (size_t)row * D + fi);
  float4 res;
  {
    float m = s4.x * invRows, var = q4.x * invRows - m * m;
    res.x = (v.x - m) * rsqrtf(var + EPSBN) * g4.x + b4.x;
    m = s4.y * invRows; var = q4.y * invRows - m * m;
    res.y = (v.y - m) * rsqrtf(var + EPSBN) * g4.y + b4.y;
    m = s4.z * invRows; var = q4.z * invRows - m * m;
    res.z = (v.z - m) * rsqrtf(var + EPSBN) * g4.z + b4.z;
    m = s4.w * invRows; var = q4.w * invRows - m * m;
    res.w = (v.w - m) * rsqrtf(var + EPSBN) * g4.w + b4.w;
  }
  if (relu) {
    res.x = fmaxf(res.x, 0.f); res.y = fmaxf(res.y, 0.f);
    res.z = fmaxf(res.z, 0.f); res.w = fmaxf(res.w, 0.f);
  }
  *(float4*)(h + (size_t)row * D + fi) = res;
  if (dst16) {
    ushort4 u;
    u.x = f2h(res.x); u.y = f2h(res.y); u.z = f2h(res.z); u.w = f2h(res.w);
    *(ushort4*)(dst16 + (size_t)row * ld16 + fi) = u;
  }
}

__global__ void fc3_kernel(const float* __restrict__ h, const float* __restrict__ w,
                           const float* __restrict__ b, float* __restrict__ out) {
  int node = blockIdx.x * 4 + (threadIdx.x >> 6);
  int lane = threadIdx.x & 63;
  if (node >= N_NODES) return;
  float v = h[(size_t)node * DD3 + lane] * w[lane];
#pragma unroll
  for (int off = 32; off > 0; off >>= 1) v += __shfl_down(v, off);
  if (lane == 0) out[node] = v + b[0];
}

// ---------------- host ----------------
extern "C" void kernel_launch(void* const* d_in, const int* in_sizes, int n_in,
                              void* d_out, int out_size, void* d_ws, size_t ws_size,
                              hipStream_t stream) {
  const float* x = (const float*)d_in[0];
  const void* ei = d_in[1];
  const float* conv1_w = (const float*)d_in[2];
  const float* convs_w = (const float*)d_in[3];
  const float* convs_b = (const float*)d_in[4];
  const float* bn1_g = (const float*)d_in[5];
  const float* bn1_b = (const float*)d_in[6];
  const float* fc1_w = (const float*)d_in[7];
  const float* fc1_b = (const float*)d_in[8];
  const float* bn2_g = (const float*)d_in[9];
  const float* bn2_b = (const float*)d_in[10];
  const float* fc2_w = (const float*)d_in[11];
  const float* fc2_b = (const float*)d_in[12];
  const float* bn3_g = (const float*)d_in[13];
  const float* bn3_b = (const float*)d_in[14];
  const float* fc3_w = (const float*)d_in[15];
  const float* fc3_b = (const float*)d_in[16];
  float* out = (float*)d_out;

  char* ws = (char*)d_ws;
  size_t off = 0;
  auto alloc = [&](size_t bytes) -> void* {
    off = (off + 255) & ~(size_t)255;
    void* p = ws + off;
    off += bytes;
    return p;
  };
  u16* Tcat = (u16*)alloc((size_t)(N_NODES + 64) * 10 * DD1 * 2);  // 10 fp16 slots, ~103 MB
  float* bufA = (float*)alloc((size_t)N_NODES * DD1 * 4);
  float* bufB = (float*)alloc((size_t)N_NODES * DD1 * 4);
  float* f1buf = (float*)alloc((size_t)N_NODES * DD2 * 4);
  float* f2buf = (float*)alloc((size_t)N_NODES * DD3 * 4);
  u16* h16 = (u16*)alloc((size_t)(N_NODES + 64) * DD1 * 2);       // fc1 input fp16
  u16* h16b = (u16*)alloc((size_t)(N_NODES + 64) * DD2 * 2);      // fc2 input fp16
  u16* Wt = (u16*)alloc((size_t)(1280 * 256 + 3 * 2560 * 256) * 2);
  u16* Wtf1 = (u16*)alloc((size_t)DD2 * DD1 * 2);                 // [128][256]
  u16* Wtf2 = (u16*)alloc((size_t)128 * DD2 * 2);                 // [64 valid +pad][128]
  float* bnpart = (float*)alloc((size_t)BN_B * 2 * DD1 * 4);
  int* ideg = (int*)alloc(N_NODES * 4);
  int* rowptr = (int*)alloc((N_NODES + 1) * 4);
  int* cnt = (int*)alloc(N_NODES * 4);
  int* col = (int*)alloc(N_EDGES * 4);
  float* wcsr = (float*)alloc(N_EDGES * 4);
  float* dinv = (float*)alloc(N_NODES * 4);
  float* bnacc = (float*)alloc(512 * 4);
  int* flag = (int*)alloc(4);
  if (off > ws_size) return;

  // ---- one-time weight transpose to fp16 ----
  wt_kernel<<<dim3(1280 / 32, 8), 256, 0, stream>>>(conv1_w, Wt, 1280, 256);
  for (int l = 0; l < 3; l++)
    wt_kernel<<<dim3(2560 / 32, 8), 256, 0, stream>>>(convs_w + (size_t)l * 655360,
                                                      Wt + 327680 + (size_t)l * 655360, 2560, 256);
  wt_kernel<<<dim3(256 / 32, 128 / 32), 256, 0, stream>>>(fc1_w, Wtf1, 256, 128);
  wt_kernel<<<dim3(128 / 32, 64 / 32), 256, 0, stream>>>(fc2_w, Wtf2, 128, 64);

  // ---- graph structures ----
  hipMemsetAsync(ideg, 0, N_NODES * 4, stream);
  hipMemsetAsync(cnt, 0, N_NODES * 4, stream);
  detect_idx_kernel<<<1, 64, 0, stream>>>(ei, flag);
  deg_kernel<<<(N_EDGES + 255) / 256, 256, 0, stream>>>(ei, flag, ideg);
  dinv_kernel<<<(N_NODES + 255) / 256, 256, 0, stream>>>(ideg, dinv);
  scan_kernel<<<1, 1024, 0, stream>>>(ideg, rowptr);
  fill_csr_kernel<<<(N_EDGES + 255) / 256, 256, 0, stream>>>(ei, flag, dinv, rowptr, cnt, col, wcsr);

  auto lhat = [&](int F, float scale, int inS, int tx0S, int outS) {
    if (F == 128) {
      if (tx0S < 0)
        lhat4_kernel<128, false><<<1250, 256, 0, stream>>>(Tcat, rowptr, col, wcsr, scale,
                                                           inS * 128, 0, outS * 128);
      else
        lhat4_kernel<128, true><<<1250, 256, 0, stream>>>(Tcat, rowptr, col, wcsr, scale,
                                                          inS * 128, tx0S * 128, outS * 128);
    } else {
      if (tx0S < 0)
        lhat4_kernel<256, false><<<2500, 256, 0, stream>>>(Tcat, rowptr, col, wcsr, scale,
                                                           inS * 256, 0, outS * 256);
      else
        lhat4_kernel<256, true><<<2500, 256, 0, stream>>>(Tcat, rowptr, col, wcsr, scale,
                                                          inS * 256, tx0S * 256, outS * 256);
    }
  };
  // generalized f16 MFMA gemm launch (XCD-chunked 1-D grid)
  auto mgemm = [&](const u16* A, int ldA, const u16* B, int ldB, int kBase, int Kc,
                   float* C, int ldC, int Nc, const float* bias, int accFlag, int relu) {
    int NX = (N_NODES + 63) / 64;        // 313
    int NXP = (NX + 7) & ~7;             // 320
    int NY = (Nc + 63) / 64;
    gemm_cat_kernel<<<dim3(NXP * NY), 256, 0, stream>>>(A, ldA, B, ldB, kBase, Kc, C, ldC, Nc,
                                                        bias, N_NODES, NX, NY, accFlag, relu);
  };
  // per layer: T0..T9 in slots 0..9, then ONE full-K GEMM
  auto cheb = [&](int F, const u16* WtL, const float* bias, float* hout, int relu) {
    lhat(F, 1.f, 0, -1, 1);                                // T1
    for (int k = 2; k < K_CHEB; k++) lhat(F, 2.f, k - 1, k - 2, k);  // T2..T9
    mgemm(Tcat, 10 * F, WtL, 10 * F, 0, 10 * F, hout, 256, 256, bias, 0, relu);
  };
  auto bn = [&](float* h, int D, const float* g, const float* b, int relu, u16* dst16, int ld16) {
    if (D == 256) {
      bn_part_kernel<256><<<BN_B, 256, 0, stream>>>(h, bnpart, N_NODES);
      bn_reduce_kernel<<<2 * 256, 64, 0, stream>>>(bnpart, bnacc, 256);
      bn_apply_kernel<256><<<(N_NODES * 64 + 255) / 256, 256, 0, stream>>>(
          h, bnacc, g, b, N_NODES, relu, 1.f / N_NODES, dst16, ld16);
    } else if (D == 128) {
      bn_part_kernel<128><<<BN_B, 256, 0, stream>>>(h, bnpart, N_NODES);
      bn_reduce_kernel<<<2 * 128, 64, 0, stream>>>(bnpart, bnacc, 128);
      bn_apply_kernel<128><<<(N_NODES * 32 + 255) / 256, 256, 0, stream>>>(
          h, bnacc, g, b, N_NODES, relu, 1.f / N_NODES, dst16, ld16);
    } else {
      bn_part_kernel<64><<<BN_B, 256, 0, stream>>>(h, bnpart, N_NODES);
      bn_reduce_kernel<<<2 * 64, 64, 0, stream>>>(bnpart, bnacc, 64);
      bn_apply_kernel<64><<<(N_NODES * 16 + 255) / 256, 256, 0, stream>>>(
          h, bnacc, g, b, N_NODES, relu, 1.f / N_NODES, dst16, ld16);
    }
  };

  // ---- conv1: T0 = x (fp16 convert), cheb(128->256) + relu -> bufA ----
  convert_cat_kernel<128><<<1250, 256, 0, stream>>>(x, Tcat);
  cheb(FDIM_IN, Wt, nullptr, bufA, 1);

  // ---- conv2: T0 = conv1-out (convert), cheb(256->256)+bias+relu -> bufB, bn1 (writes slot0 for conv3)
  convert_cat_kernel<256><<<2500, 256, 0, stream>>>(bufA, Tcat);
  cheb(DD1, Wt + 327680, convs_b, bufB, 1);
  bn(bufB, DD1, bn1_g, bn1_b, 0, Tcat, 10 * DD1);

  // ---- conv3 ----
  cheb(DD1, Wt + 327680 + 655360, convs_b + DD1, bufA, 1);
  bn(bufA, DD1, bn1_g, bn1_b, 0, Tcat, 10 * DD1);

  // ---- conv4 (bn writes h16 for fc1) ----
  cheb(DD1, Wt + 327680 + 2 * 655360, convs_b + 2 * DD1, bufB, 1);
  bn(bufB, DD1, bn1_g, bn1_b, 0, h16, DD1);

  // ---- fc1 (256->128) + bias, bn2+relu (writes h16b for fc2) ----
  mgemm(h16, DD1, Wtf1, DD1, 0, DD1, f1buf, DD2, DD2, fc1_b, 0, 0);
  bn(f1buf, DD2, bn2_g, bn2_b, 1, h16b, DD2);

  // ---- fc2 (128->64) + bias, bn3 ----
  mgemm(h16b, DD2, Wtf2, DD2, 0, DD2, f2buf, DD3, DD3, fc2_b, 0, 0);
  bn(f2buf, DD3, bn3_g, bn3_b, 0, nullptr, 0);

  // ---- fc3 (64->1) ----
  fc3_kernel<<<(N_NODES + 3) / 4, 256, 0, stream>>>(f2buf, fc3_w, fc3_b, out);
}

// Round 10
// 1099.106 us; speedup vs baseline: 4.3848x; 1.0592x over previous
//
#include <hip/hip_runtime.h>
#include <hip/hip_bf16.h>
#include <stdint.h>

// ChebNet: fp16 Chebyshev T-storage, 10-slot flat concat buffer, single full-K
// f16 MFMA GEMM per conv layer, two-pass BN, fp16 MFMA head.
// R10: fix lhat5 NPG formula (N_NODES*SLICES/8; F=128 case was 2x too big ->
// rowptr OOB crash in R9) + hard node<N_NODES guard.

#define N_NODES 20000
#define N_EDGES 320000
#define FDIM_IN 128
#define DD1 256
#define DD2 128
#define DD3 64
#define K_CHEB 10
#define EPSBN 1e-5f
#define BN_B 512  // partial blocks for BN pass1

typedef unsigned short u16;
typedef unsigned int u32;
typedef _Float16 half8 __attribute__((ext_vector_type(8)));
typedef __attribute__((ext_vector_type(4))) float floatx4;

__device__ __forceinline__ u16 f2h(float v) {
  _Float16 h = (_Float16)v;
  return *reinterpret_cast<u16*>(&h);
}

__device__ __forceinline__ void gld16(const void* g, void* l) {
  __builtin_amdgcn_global_load_lds((const __attribute__((address_space(1))) u32*)g,
                                   (__attribute__((address_space(3))) u32*)l, 16, 0, 0);
}

// ---------------- graph setup ----------------
__global__ void detect_idx_kernel(const void* ei, int* flag) {
  int t = threadIdx.x;
  const int* p = (const int*)ei;
  int v = p[2 * t + 1];
  unsigned long long b = __ballot(v == 0);
  if (t == 0) *flag = (b == ~0ULL) ? 1 : 0;
}

__device__ __forceinline__ int load_edge(const void* ei, int mode64, long long pos) {
  return mode64 ? (int)((const long long*)ei)[pos] : ((const int*)ei)[pos];
}

__global__ void deg_kernel(const void* ei, const int* __restrict__ flag, int* __restrict__ ideg) {
  int e = blockIdx.x * blockDim.x + threadIdx.x;
  if (e < N_EDGES) {
    int d = load_edge(ei, *flag, (long long)N_EDGES + e);
    atomicAdd(&ideg[d], 1);
  }
}

__global__ void dinv_kernel(const int* __restrict__ ideg, float* __restrict__ dinv) {
  int n = blockIdx.x * blockDim.x + threadIdx.x;
  if (n < N_NODES) {
    int d = ideg[n];
    dinv[n] = d > 0 ? rsqrtf((float)d) : 0.f;
  }
}

__global__ __launch_bounds__(1024) void scan_kernel(const int* __restrict__ ideg, int* __restrict__ rowptr) {
  __shared__ int part[1024];
  int tid = threadIdx.x;
  const int CH = (N_NODES + 1023) / 1024;
  int base = tid * CH;
  int s = 0;
  for (int i = 0; i < CH; i++) { int idx = base + i; if (idx < N_NODES) s += ideg[idx]; }
  part[tid] = s;
  __syncthreads();
  for (int off = 1; off < 1024; off <<= 1) {
    int v = (tid >= off) ? part[tid - off] : 0;
    __syncthreads();
    part[tid] += v;
    __syncthreads();
  }
  int run = (tid == 0) ? 0 : part[tid - 1];
  for (int i = 0; i < CH; i++) { int idx = base + i; if (idx < N_NODES) { rowptr[idx] = run; run += ideg[idx]; } }
  if (tid == 1023) rowptr[N_NODES] = run;
}

__global__ void fill_csr_kernel(const void* ei, const int* __restrict__ flag,
                                const float* __restrict__ dinv, const int* __restrict__ rowptr,
                                int* __restrict__ cnt, int* __restrict__ col, float* __restrict__ wcsr) {
  int e = blockIdx.x * blockDim.x + threadIdx.x;
  if (e < N_EDGES) {
    int m = *flag;
    int s = load_edge(ei, m, e);
    int d = load_edge(ei, m, (long long)N_EDGES + e);
    int pos = rowptr[d] + atomicAdd(&cnt[d], 1);
    col[pos] = s;
    wcsr[pos] = -dinv[s] * dinv[d];
  }
}

// ---------------- weight transpose-convert: W[KF][Nd] fp32 -> Wt[Nd][KF] fp16 ----------------
__global__ __launch_bounds__(256) void wt_kernel(const float* __restrict__ W, u16* __restrict__ Wt,
                                                 int KF, int Nd) {
  __shared__ float sm[32][36];
  int kf0 = blockIdx.x * 32, n0 = blockIdx.y * 32;
  int r = threadIdx.x >> 3, c4 = (threadIdx.x & 7) * 4;
  float4 v = *(const float4*)(W + (size_t)(kf0 + r) * Nd + n0 + c4);
  sm[r][c4 + 0] = v.x; sm[r][c4 + 1] = v.y; sm[r][c4 + 2] = v.z; sm[r][c4 + 3] = v.w;
  __syncthreads();
  int on = threadIdx.x >> 3, okf4 = (threadIdx.x & 7) * 4;
  ushort4 u;
  u.x = f2h(sm[okf4 + 0][on]);
  u.y = f2h(sm[okf4 + 1][on]);
  u.z = f2h(sm[okf4 + 2][on]);
  u.w = f2h(sm[okf4 + 3][on]);
  *(ushort4*)(Wt + (size_t)(n0 + on) * KF + kf0 + okf4) = u;
}

// ---------------- convert h fp32 -> fp16 into cat slot 0 (T0); row stride 10F ----------------
template <int F>
__global__ void convert_cat_kernel(const float* __restrict__ in, u16* __restrict__ cat) {
  constexpr int F8 = F / 8;
  int i = blockIdx.x * blockDim.x + threadIdx.x;  // over N*F8
  int n = i / F8, f8 = i % F8;
  const float4* p = (const float4*)(in + (size_t)n * F + f8 * 8);
  float4 a = p[0], b = p[1];
  half8 o;
  o[0] = (_Float16)a.x; o[1] = (_Float16)a.y; o[2] = (_Float16)a.z; o[3] = (_Float16)a.w;
  o[4] = (_Float16)b.x; o[5] = (_Float16)b.y; o[6] = (_Float16)b.z; o[7] = (_Float16)b.w;
  *(half8*)(cat + (size_t)n * (10 * F) + f8 * 8) = o;
}

// ---------------- L_hat, XCD-sliced: slot_out = scale * gather(slot_in) - slot_tx0 ----------------
// blockIdx%8 -> XCD (round-robin heuristic). XCD handles feature-slice q (64
// features = 128 B = 1 cache line) of node group grp; slice data is
// L2-resident. NPG = N_NODES*SLICES/8 (8 XCDs = SLICES x groups).
template <int F, bool HAS_TX0>
__global__ void lhat5_kernel(u16* __restrict__ cat,
                             const int* __restrict__ rowptr, const int* __restrict__ col,
                             const float* __restrict__ w, float scale,
                             int inOff, int tx0Off, int outOff) {
  constexpr int R = 10 * F;                  // cat row stride (halves)
  constexpr int SLICES = F / 64;             // 4 (F=256) or 2 (F=128)
  constexpr int NPG = N_NODES * SLICES / 8;  // 10000 (F=256) / 5000 (F=128)
  int xcd = blockIdx.x & 7;
  int lb = blockIdx.x >> 3;
  int q = xcd % SLICES;
  int grp = xcd / SLICES;
  int node0 = grp * NPG;
  int node = node0 + lb * 32 + (threadIdx.x >> 3);
  if (node >= node0 + NPG || node >= N_NODES) return;
  int ln8 = q * 64 + (threadIdx.x & 7) * 8;  // element offset within slot
  int beg = rowptr[node], end = rowptr[node + 1];
  float acc[8] = {0.f, 0.f, 0.f, 0.f, 0.f, 0.f, 0.f, 0.f};
  int e = beg;
  for (; e + 7 < end; e += 8) {
    int c[8];
    float wv[8];
#pragma unroll
    for (int j = 0; j < 8; j++) { c[j] = col[e + j]; wv[j] = w[e + j]; }
    half8 v[8];
#pragma unroll
    for (int j = 0; j < 8; j++) v[j] = *(const half8*)(cat + (size_t)c[j] * R + inOff + ln8);
#pragma unroll
    for (int j = 0; j < 8; j++)
#pragma unroll
      for (int i = 0; i < 8; i++) acc[i] += wv[j] * (float)v[j][i];
  }
  if (e + 3 < end) {
    int c[4];
    float wv[4];
#pragma unroll
    for (int j = 0; j < 4; j++) { c[j] = col[e + j]; wv[j] = w[e + j]; }
    half8 v[4];
#pragma unroll
    for (int j = 0; j < 4; j++) v[j] = *(const half8*)(cat + (size_t)c[j] * R + inOff + ln8);
#pragma unroll
    for (int j = 0; j < 4; j++)
#pragma unroll
      for (int i = 0; i < 8; i++) acc[i] += wv[j] * (float)v[j][i];
    e += 4;
  }
  for (; e < end; e++) {
    int c0 = col[e];
    float w0 = w[e];
    half8 v0 = *(const half8*)(cat + (size_t)c0 * R + inOff + ln8);
#pragma unroll
    for (int i = 0; i < 8; i++) acc[i] += w0 * (float)v0[i];
  }
  float r[8];
#pragma unroll
  for (int i = 0; i < 8; i++) r[i] = scale * acc[i];
  if (HAS_TX0) {
    half8 t = *(const half8*)(cat + (size_t)node * R + tx0Off + ln8);
#pragma unroll
    for (int i = 0; i < 8; i++) r[i] -= (float)t[i];
  }
  half8 o;
#pragma unroll
  for (int i = 0; i < 8; i++) o[i] = (_Float16)r[i];
  *(half8*)(cat + (size_t)node * R + outOff + ln8) = o;
}

// ---------------- f16 MFMA GEMM: C[M][ldC] = A[M][ldA]f16(Kc cols) @ B[Nc][ldB]^T ----------------
// Tile 64(M) x 64(N) x 64(K); 4 waves (2x2), each 32x32. 1-D grid with
// XCD-chunked swizzle. Staging: global_load_lds w16, linear LDS dest,
// inverse-swizzled global src; swizzled ds_read.
__global__ __launch_bounds__(256) void gemm_cat_kernel(
    const u16* __restrict__ A, int ldA, const u16* __restrict__ B, int ldB, int kBase,
    int Kc, float* __restrict__ C, int ldC, int Nc, const float* __restrict__ bias, int M,
    int NX, int NY, int accFlag, int reluFlag) {
  __shared__ __align__(16) u16 As[64 * 64];    // 8 KB
  __shared__ __align__(16) u16 Bs[64 * 64];    // 8 KB
  int pid = blockIdx.x;
  int g8 = 8 * NY;
  int a8 = pid / g8, rem = pid % g8;
  int by = rem >> 3;
  int bx = a8 * 8 + (rem & 7);
  if (bx >= NX) return;
  int tid = threadIdx.x;
  int lane = tid & 63, wave = tid >> 6;
  int wr = wave >> 1, wc = wave & 1;
  int l15 = lane & 15, l16 = lane >> 4;
  int m0 = bx * 64, n0 = by * 64;
  floatx4 acc[2][2];
#pragma unroll
  for (int m = 0; m < 2; m++)
#pragma unroll
    for (int n = 0; n < 2; n++) acc[m][n] = (floatx4){0.f, 0.f, 0.f, 0.f};

  int subrow = lane >> 3;          // 0..7
  int bcol = (lane & 7) * 16;      // byte col within 128B row

  for (int k0 = 0; k0 < Kc; k0 += 64) {
    __syncthreads();  // previous iteration's ds_reads done before overwrite
#pragma unroll
    for (int i = 0; i < 4; i++) {
      int c = wave * 4 + i;        // 0..15 chunk id, 1KB each
      if (c < 8) {
        int row = c * 8 + subrow;
        const char* src = (const char*)A + ((size_t)(m0 + row) * ldA + kBase + k0) * 2 +
                          (bcol ^ ((row & 7) << 4));
        gld16(src, (char*)As + c * 1024);
      } else {
        int row = (c - 8) * 8 + subrow;
        const char* src = (const char*)B + ((size_t)(n0 + row) * ldB + kBase + k0) * 2 +
                          (bcol ^ ((row & 7) << 4));
        gld16(src, (char*)Bs + (c - 8) * 1024);
      }
    }
    __syncthreads();  // compiler drains vmcnt before barrier -> LDS valid
#pragma unroll
    for (int kk = 0; kk < 2; kk++) {
      int kb = kk * 64 + l16 * 16;  // byte offset of 16B chunk within row
      half8 a[2];
#pragma unroll
      for (int m = 0; m < 2; m++) {
        int r = wr * 32 + m * 16 + l15;
        a[m] = *(half8*)((char*)As + r * 128 + (kb ^ ((r & 7) << 4)));
      }
#pragma unroll
      for (int n = 0; n < 2; n++) {
        int r = wc * 32 + n * 16 + l15;
        half8 b = *(half8*)((char*)Bs + r * 128 + (kb ^ ((r & 7) << 4)));
        acc[0][n] = __builtin_amdgcn_mfma_f32_16x16x32_f16(a[0], b, acc[0][n], 0, 0, 0);
        acc[1][n] = __builtin_amdgcn_mfma_f32_16x16x32_f16(a[1], b, acc[1][n], 0, 0, 0);
      }
    }
  }
#pragma unroll
  for (int m = 0; m < 2; m++)
#pragma unroll
    for (int n = 0; n < 2; n++)
#pragma unroll
      for (int j = 0; j < 4; j++) {
        int row = m0 + wr * 32 + m * 16 + l16 * 4 + j;
        int colI = n0 + wc * 32 + n * 16 + l15;
        if (row < M && colI < Nc) {
          size_t idx = (size_t)row * ldC + colI;
          float v = acc[m][n][j];
          if (accFlag) v += C[idx];
          if (bias) v += bias[colI];
          if (reluFlag) v = fmaxf(v, 0.f);
          C[idx] = v;
        }
      }
}

// ---------------- BN: pass1 partials (vectorized), reduce, apply (+fp16 out) ----------------
template <int D>
__global__ __launch_bounds__(256) void bn_part_kernel(const float* __restrict__ h,
                                                      float* __restrict__ part, int rows) {
  constexpr int TPR = D / 4;       // threads per row
  constexpr int RPI = 256 / TPR;   // rows per block-iter
  __shared__ float4 ssum[256], ssq[256];
  int tid = threadIdx.x;
  int g = tid / TPR;
  int fr = tid % TPR;
  float4 s = {0.f, 0.f, 0.f, 0.f}, q = {0.f, 0.f, 0.f, 0.f};
  for (int r = blockIdx.x * RPI + g; r < rows; r += gridDim.x * RPI) {
    float4 v = *(const float4*)(h + (size_t)r * D + fr * 4);
    s.x += v.x; s.y += v.y; s.z += v.z; s.w += v.w;
    q.x += v.x * v.x; q.y += v.y * v.y; q.z += v.z * v.z; q.w += v.w * v.w;
  }
  ssum[tid] = s; ssq[tid] = q;
  __syncthreads();
  if (g == 0) {
#pragma unroll
    for (int gg = 1; gg < RPI; gg++) {
      float4 a = ssum[gg * TPR + fr], b = ssq[gg * TPR + fr];
      s.x += a.x; s.y += a.y; s.z += a.z; s.w += a.w;
      q.x += b.x; q.y += b.y; q.z += b.z; q.w += b.w;
    }
    *(float4*)(part + (size_t)blockIdx.x * (2 * D) + fr * 4) = s;
    *(float4*)(part + (size_t)blockIdx.x * (2 * D) + D + fr * 4) = q;
  }
}

__global__ void bn_reduce_kernel(const float* __restrict__ part, float* __restrict__ acc, int D) {
  int c = blockIdx.x;   // 0..2D-1
  int tid = threadIdx.x;  // 64
  float v = 0.f;
  for (int b = tid; b < BN_B; b += 64) v += part[(size_t)b * (2 * D) + c];
#pragma unroll
  for (int off = 32; off > 0; off >>= 1) v += __shfl_down(v, off);
  if (tid == 0) {
    if (c < D) acc[c] = v;
    else acc[256 + (c - D)] = v;
  }
}

template <int D>
__global__ void bn_apply_kernel(float* __restrict__ h, const float* __restrict__ acc,
                                const float* __restrict__ gam, const float* __restrict__ bet,
                                int rows, int relu, float invRows,
                                u16* __restrict__ dst16, int ld16) {
  constexpr int F4 = D / 4;
  int i = blockIdx.x * blockDim.x + threadIdx.x;
  if (i >= rows * F4) return;
  int row = i / F4;
  int fi = (i % F4) * 4;
  float4 s4 = *(const float4*)(acc + fi);
  float4 q4 = *(const float4*)(acc + 256 + fi);
  float4 g4 = *(const float4*)(gam + fi);
  float4 b4 = *(const float4*)(bet + fi);
  float4 v = *(float4*)(h + (size_t)row * D + fi);
  float4 res;
  {
    float m = s4.x * invRows, var = q4.x * invRows - m * m;
    res.x = (v.x - m) * rsqrtf(var + EPSBN) * g4.x + b4.x;
    m = s4.y * invRows; var = q4.y * invRows - m * m;
    res.y = (v.y - m) * rsqrtf(var + EPSBN) * g4.y + b4.y;
    m = s4.z * invRows; var = q4.z * invRows - m * m;
    res.z = (v.z - m) * rsqrtf(var + EPSBN) * g4.z + b4.z;
    m = s4.w * invRows; var = q4.w * invRows - m * m;
    res.w = (v.w - m) * rsqrtf(var + EPSBN) * g4.w + b4.w;
  }
  if (relu) {
    res.x = fmaxf(res.x, 0.f); res.y = fmaxf(res.y, 0.f);
    res.z = fmaxf(res.z, 0.f); res.w = fmaxf(res.w, 0.f);
  }
  *(float4*)(h + (size_t)row * D + fi) = res;
  if (dst16) {
    ushort4 u;
    u.x = f2h(res.x); u.y = f2h(res.y); u.z = f2h(res.z); u.w = f2h(res.w);
    *(ushort4*)(dst16 + (size_t)row * ld16 + fi) = u;
  }
}

__global__ void fc3_kernel(const float* __restrict__ h, const float* __restrict__ w,
                           const float* __restrict__ b, float* __restrict__ out) {
  int node = blockIdx.x * 4 + (threadIdx.x >> 6);
  int lane = threadIdx.x & 63;
  if (node >= N_NODES) return;
  float v = h[(size_t)node * DD3 + lane] * w[lane];
#pragma unroll
  for (int off = 32; off > 0; off >>= 1) v += __shfl_down(v, off);
  if (lane == 0) out[node] = v + b[0];
}

// ---------------- host ----------------
extern "C" void kernel_launch(void* const* d_in, const int* in_sizes, int n_in,
                              void* d_out, int out_size, void* d_ws, size_t ws_size,
                              hipStream_t stream) {
  const float* x = (const float*)d_in[0];
  const void* ei = d_in[1];
  const float* conv1_w = (const float*)d_in[2];
  const float* convs_w = (const float*)d_in[3];
  const float* convs_b = (const float*)d_in[4];
  const float* bn1_g = (const float*)d_in[5];
  const float* bn1_b = (const float*)d_in[6];
  const float* fc1_w = (const float*)d_in[7];
  const float* fc1_b = (const float*)d_in[8];
  const float* bn2_g = (const float*)d_in[9];
  const float* bn2_b = (const float*)d_in[10];
  const float* fc2_w = (const float*)d_in[11];
  const float* fc2_b = (const float*)d_in[12];
  const float* bn3_g = (const float*)d_in[13];
  const float* bn3_b = (const float*)d_in[14];
  const float* fc3_w = (const float*)d_in[15];
  const float* fc3_b = (const float*)d_in[16];
  float* out = (float*)d_out;

  char* ws = (char*)d_ws;
  size_t off = 0;
  auto alloc = [&](size_t bytes) -> void* {
    off = (off + 255) & ~(size_t)255;
    void* p = ws + off;
    off += bytes;
    return p;
  };
  u16* Tcat = (u16*)alloc((size_t)(N_NODES + 64) * 10 * DD1 * 2);  // 10 fp16 slots, ~103 MB
  float* bufA = (float*)alloc((size_t)N_NODES * DD1 * 4);
  float* bufB = (float*)alloc((size_t)N_NODES * DD1 * 4);
  float* f1buf = (float*)alloc((size_t)N_NODES * DD2 * 4);
  float* f2buf = (float*)alloc((size_t)N_NODES * DD3 * 4);
  u16* h16 = (u16*)alloc((size_t)(N_NODES + 64) * DD1 * 2);       // fc1 input fp16
  u16* h16b = (u16*)alloc((size_t)(N_NODES + 64) * DD2 * 2);      // fc2 input fp16
  u16* Wt = (u16*)alloc((size_t)(1280 * 256 + 3 * 2560 * 256) * 2);
  u16* Wtf1 = (u16*)alloc((size_t)DD2 * DD1 * 2);                 // [128][256]
  u16* Wtf2 = (u16*)alloc((size_t)128 * DD2 * 2);                 // [64 valid +pad][128]
  float* bnpart = (float*)alloc((size_t)BN_B * 2 * DD1 * 4);
  int* ideg = (int*)alloc(N_NODES * 4);
  int* rowptr = (int*)alloc((N_NODES + 1) * 4);
  int* cnt = (int*)alloc(N_NODES * 4);
  int* col = (int*)alloc(N_EDGES * 4);
  float* wcsr = (float*)alloc(N_EDGES * 4);
  float* dinv = (float*)alloc(N_NODES * 4);
  float* bnacc = (float*)alloc(512 * 4);
  int* flag = (int*)alloc(4);
  if (off > ws_size) return;

  // ---- one-time weight transpose to fp16 ----
  wt_kernel<<<dim3(1280 / 32, 8), 256, 0, stream>>>(conv1_w, Wt, 1280, 256);
  for (int l = 0; l < 3; l++)
    wt_kernel<<<dim3(2560 / 32, 8), 256, 0, stream>>>(convs_w + (size_t)l * 655360,
                                                      Wt + 327680 + (size_t)l * 655360, 2560, 256);
  wt_kernel<<<dim3(256 / 32, 128 / 32), 256, 0, stream>>>(fc1_w, Wtf1, 256, 128);
  wt_kernel<<<dim3(128 / 32, 64 / 32), 256, 0, stream>>>(fc2_w, Wtf2, 128, 64);

  // ---- graph structures ----
  hipMemsetAsync(ideg, 0, N_NODES * 4, stream);
  hipMemsetAsync(cnt, 0, N_NODES * 4, stream);
  detect_idx_kernel<<<1, 64, 0, stream>>>(ei, flag);
  deg_kernel<<<(N_EDGES + 255) / 256, 256, 0, stream>>>(ei, flag, ideg);
  dinv_kernel<<<(N_NODES + 255) / 256, 256, 0, stream>>>(ideg, dinv);
  scan_kernel<<<1, 1024, 0, stream>>>(ideg, rowptr);
  fill_csr_kernel<<<(N_EDGES + 255) / 256, 256, 0, stream>>>(ei, flag, dinv, rowptr, cnt, col, wcsr);

  auto lhat = [&](int F, float scale, int inS, int tx0S, int outS) {
    if (F == 128) {
      // SLICES=2, NPG=5000, blocks/XCD=ceil(5000/32)=157
      if (tx0S < 0)
        lhat5_kernel<128, false><<<8 * 157, 256, 0, stream>>>(Tcat, rowptr, col, wcsr, scale,
                                                              inS * 128, 0, outS * 128);
      else
        lhat5_kernel<128, true><<<8 * 157, 256, 0, stream>>>(Tcat, rowptr, col, wcsr, scale,
                                                             inS * 128, tx0S * 128, outS * 128);
    } else {
      // SLICES=4, NPG=10000, blocks/XCD=ceil(10000/32)=313
      if (tx0S < 0)
        lhat5_kernel<256, false><<<8 * 313, 256, 0, stream>>>(Tcat, rowptr, col, wcsr, scale,
                                                              inS * 256, 0, outS * 256);
      else
        lhat5_kernel<256, true><<<8 * 313, 256, 0, stream>>>(Tcat, rowptr, col, wcsr, scale,
                                                             inS * 256, tx0S * 256, outS * 256);
    }
  };
  // generalized f16 MFMA gemm launch (XCD-chunked 1-D grid)
  auto mgemm = [&](const u16* A, int ldA, const u16* B, int ldB, int kBase, int Kc,
                   float* C, int ldC, int Nc, const float* bias, int accFlag, int relu) {
    int NX = (N_NODES + 63) / 64;        // 313
    int NXP = (NX + 7) & ~7;             // 320
    int NY = (Nc + 63) / 64;
    gemm_cat_kernel<<<dim3(NXP * NY), 256, 0, stream>>>(A, ldA, B, ldB, kBase, Kc, C, ldC, Nc,
                                                        bias, N_NODES, NX, NY, accFlag, relu);
  };
  // per layer: T0..T9 in slots 0..9, then ONE full-K GEMM
  auto cheb = [&](int F, const u16* WtL, const float* bias, float* hout, int relu) {
    lhat(F, 1.f, 0, -1, 1);                                          // T1
    for (int k = 2; k < K_CHEB; k++) lhat(F, 2.f, k - 1, k - 2, k);  // T2..T9
    mgemm(Tcat, 10 * F, WtL, 10 * F, 0, 10 * F, hout, 256, 256, bias, 0, relu);
  };
  auto bn = [&](float* h, int D, const float* g, const float* b, int relu, u16* dst16, int ld16) {
    if (D == 256) {
      bn_part_kernel<256><<<BN_B, 256, 0, stream>>>(h, bnpart, N_NODES);
      bn_reduce_kernel<<<2 * 256, 64, 0, stream>>>(bnpart, bnacc, 256);
      bn_apply_kernel<256><<<(N_NODES * 64 + 255) / 256, 256, 0, stream>>>(
          h, bnacc, g, b, N_NODES, relu, 1.f / N_NODES, dst16, ld16);
    } else if (D == 128) {
      bn_part_kernel<128><<<BN_B, 256, 0, stream>>>(h, bnpart, N_NODES);
      bn_reduce_kernel<<<2 * 128, 64, 0, stream>>>(bnpart, bnacc, 128);
      bn_apply_kernel<128><<<(N_NODES * 32 + 255) / 256, 256, 0, stream>>>(
          h, bnacc, g, b, N_NODES, relu, 1.f / N_NODES, dst16, ld16);
    } else {
      bn_part_kernel<64><<<BN_B, 256, 0, stream>>>(h, bnpart, N_NODES);
      bn_reduce_kernel<<<2 * 64, 64, 0, stream>>>(bnpart, bnacc, 64);
      bn_apply_kernel<64><<<(N_NODES * 16 + 255) / 256, 256, 0, stream>>>(
          h, bnacc, g, b, N_NODES, relu, 1.f / N_NODES, dst16, ld16);
    }
  };

  // ---- conv1: T0 = x (fp16 convert), cheb(128->256) + relu -> bufA ----
  convert_cat_kernel<128><<<1250, 256, 0, stream>>>(x, Tcat);
  cheb(FDIM_IN, Wt, nullptr, bufA, 1);

  // ---- conv2: T0 = conv1-out (convert), cheb(256->256)+bias+relu -> bufB, bn1 (writes slot0 for conv3)
  convert_cat_kernel<256><<<2500, 256, 0, stream>>>(bufA, Tcat);
  cheb(DD1, Wt + 327680, convs_b, bufB, 1);
  bn(bufB, DD1, bn1_g, bn1_b, 0, Tcat, 10 * DD1);

  // ---- conv3 ----
  cheb(DD1, Wt + 327680 + 655360, convs_b + DD1, bufA, 1);
  bn(bufA, DD1, bn1_g, bn1_b, 0, Tcat, 10 * DD1);

  // ---- conv4 (bn writes h16 for fc1) ----
  cheb(DD1, Wt + 327680 + 2 * 655360, convs_b + 2 * DD1, bufB, 1);
  bn(bufB, DD1, bn1_g, bn1_b, 0, h16, DD1);

  // ---- fc1 (256->128) + bias, bn2+relu (writes h16b for fc2) ----
  mgemm(h16, DD1, Wtf1, DD1, 0, DD1, f1buf, DD2, DD2, fc1_b, 0, 0);
  bn(f1buf, DD2, bn2_g, bn2_b, 1, h16b, DD2);

  // ---- fc2 (128->64) + bias, bn3 ----
  mgemm(h16b, DD2, Wtf2, DD2, 0, DD2, f2buf, DD3, DD3, fc2_b, 0, 0);
  bn(f2buf, DD3, bn3_g, bn3_b, 0, nullptr, 0);

  // ---- fc3 (64->1) ----
  fc3_kernel<<<(N_NODES + 3) / 4, 256, 0, stream>>>(f2buf, fc3_w, fc3_b, out);
}